// Round 2
// baseline (3806.491 us; speedup 1.0000x reference)
//
#include <hip/hip_runtime.h>
#include <hip/hip_bf16.h>
#include <cstddef>
#include <cstdint>

typedef __hip_bfloat16 bf16;
static __device__ __forceinline__ float b2f(bf16 v) { return __bfloat162float(v); }

#define NCONV 35

struct ConvArgs {
    const void* src[NCONV];
    float*      dst[NCONV];
    int         n[NCONV];
};

// ---------------- dtype detection ----------------
// mode: 0 = all-zero, 1 = bf16-stored, 2 = fp32-stored
__device__ int detect_mode(const unsigned short* w, int n) {
    __shared__ int cz, cbad, cevz, codz;
    if (threadIdx.x == 0) { cz = 0; cbad = 0; cevz = 0; codz = 0; }
    __syncthreads();
    int K = n < 2048 ? n : 2048;
    int z = 0, bad = 0, evz = 0, odz = 0;
    for (int i = threadIdx.x; i < K; i += blockDim.x) {
        unsigned short v = w[i];
        int e = (v >> 7) & 0xFF;
        bool isz = (v & 0x7FFF) == 0;
        if (isz) { z++; if (i & 1) odz++; else evz++; }
        else if (e < 91 || e > 140) bad++;
    }
    atomicAdd(&cz, z); atomicAdd(&cbad, bad);
    atomicAdd(&cevz, evz); atomicAdd(&codz, odz);
    __syncthreads();
    int Z = cz, Bc = cbad, EZ = cevz, OZ = codz;
    if (Z >= K) return 0;                          // all zero
    if (Bc * 16 > K) return 2;                     // many garbage exponents -> fp32
    if (EZ * 4 > K && OZ * 16 < K) return 2;       // [0, X] repeating -> fp32 constants
    return 1;                                      // clean bf16
}

__global__ __launch_bounds__(256) void convert_all(ConvArgs a, int* __restrict__ modes) {
    int b = blockIdx.y;
    int n = a.n[b];
    const unsigned short* w = (const unsigned short*)a.src[b];
    int mode = detect_mode(w, n);
    if (blockIdx.x == 0 && threadIdx.x == 0) modes[b] = mode;
    float* dst = a.dst[b];
    const float* f = (const float*)a.src[b];
    const bf16*  h = (const bf16*)a.src[b];
    int i0 = blockIdx.x * 1024 + threadIdx.x;
    #pragma unroll
    for (int k = 0; k < 4; ++k) {
        int i = i0 + k * 256;
        if (i < n) {
            float v;
            if (mode == 0)      v = 0.f;
            else if (mode == 1) v = b2f(h[i]);
            else                v = f[i];
            dst[i] = v;
        }
    }
}

// ---------------- feature build: out[i] = concat(emb[ids[i]](64), feats[i](nf)) ----------------
__global__ void build_feat(const float* __restrict__ emb, const int* __restrict__ ids,
                           const float* __restrict__ feats, float* __restrict__ out,
                           int nf) {
    int i = blockIdx.x;
    int d = threadIdx.x;           // blockDim = 128
    int W = 64 + nf;
    if (d < 64)      out[(size_t)i * W + d] = emb[ids[i] * 64 + d];
    else if (d < W)  out[(size_t)i * W + d] = feats[(size_t)i * nf + (d - 64)];
}

// ---------------- edge scatter: agg[dst] += x[src], width W ----------------
__global__ void scatter_add(const float* __restrict__ x, const int* __restrict__ src,
                            const int* __restrict__ dst, float* __restrict__ agg, int W) {
    int e = blockIdx.x;
    int s = src[e], t = dst[e];
    const float* xs = x + (size_t)s * W;
    float* ad = agg + (size_t)t * W;
    for (int d = threadIdx.x; d < W; d += blockDim.x)
        atomicAdd(&ad[d], xs[d]);
}

// ---------------- GIN combine: h = (1+eps)*x + h ----------------
__global__ void gin_combine(float* __restrict__ h, const float* __restrict__ x,
                            const float* __restrict__ eps, size_t n) {
    size_t i = (size_t)blockIdx.x * blockDim.x + threadIdx.x;
    if (i < n) h[i] = (1.0f + eps[0]) * x[i] + h[i];
}

// ---------------- fp32 tiled GEMM: C[M,N] = A[M,K] @ W[K,N] (+bias) ----------------
#define BMg 64
#define BNg 64
#define BKg 16
__global__ __launch_bounds__(256) void gemm_f32(const float* __restrict__ A,
                                                const float* __restrict__ W,
                                                const float* __restrict__ bias,
                                                float* __restrict__ C,
                                                int M, int N, int K) {
    __shared__ float As[BMg][BKg + 1];
    __shared__ float Bs[BKg][BNg];
    int tid = threadIdx.x;
    int tx = tid & 15, ty = tid >> 4;
    int bm = blockIdx.y * BMg, bn = blockIdx.x * BNg;
    float acc[4][4] = {};
    for (int k0 = 0; k0 < K; k0 += BKg) {
        #pragma unroll
        for (int t = tid; t < BMg * BKg; t += 256) {
            int m = t >> 4, k = t & 15;
            int row = bm + m, kk = k0 + k;
            As[m][k] = (row < M && kk < K) ? A[(size_t)row * K + kk] : 0.f;
        }
        #pragma unroll
        for (int t = tid; t < BKg * BNg; t += 256) {
            int k = t >> 6, n = t & 63;
            int kk = k0 + k;
            Bs[k][n] = (kk < K) ? W[(size_t)kk * N + bn + n] : 0.f;
        }
        __syncthreads();
        #pragma unroll
        for (int kk = 0; kk < BKg; ++kk) {
            float a[4];
            #pragma unroll
            for (int i = 0; i < 4; ++i) a[i] = As[ty * 4 + i][kk];
            float4 bv = *(const float4*)&Bs[kk][tx * 4];
            float b[4] = {bv.x, bv.y, bv.z, bv.w};
            #pragma unroll
            for (int i = 0; i < 4; ++i)
                #pragma unroll
                for (int j = 0; j < 4; ++j)
                    acc[i][j] += a[i] * b[j];
        }
        __syncthreads();
    }
    #pragma unroll
    for (int i = 0; i < 4; ++i) {
        int row = bm + ty * 4 + i;
        if (row >= M) continue;
        int col = bn + tx * 4;
        float4 o;
        o.x = acc[i][0]; o.y = acc[i][1]; o.z = acc[i][2]; o.w = acc[i][3];
        if (bias) {
            o.x += bias[col + 0]; o.y += bias[col + 1];
            o.z += bias[col + 2]; o.w += bias[col + 3];
        }
        *(float4*)&C[(size_t)row * N + col] = o;
    }
}

// ---------------- BatchNorm: stats -> finalize -> apply ----------------
__global__ void bn_stats(const float* __restrict__ X, float* __restrict__ stats,
                         int M, int C, int rows) {
    int c = threadIdx.x;                 // blockDim == C
    int r0 = blockIdx.x * rows;
    int r1 = min(r0 + rows, M);
    float s = 0.f, s2 = 0.f;
    for (int r = r0; r < r1; ++r) {
        float v = X[(size_t)r * C + c];
        s += v; s2 += v * v;
    }
    atomicAdd(&stats[c], s);
    atomicAdd(&stats[C + c], s2);
}

__global__ void bn_finalize(float* __restrict__ stats, const float* __restrict__ g,
                            const float* __restrict__ b, int C, float invM) {
    int c = threadIdx.x;
    if (c < C) {
        float mean = stats[c] * invM;
        float var  = fmaxf(stats[C + c] * invM - mean * mean, 0.f);
        float sc   = g[c] * rsqrtf(var + 1e-5f);
        stats[2 * C + c] = sc;
        stats[3 * C + c] = b[c] - mean * sc;
    }
}

__global__ void bn_apply(float* __restrict__ X, const float* __restrict__ stats,
                         size_t total, int cmask, int C, int relu) {
    size_t i = (size_t)blockIdx.x * blockDim.x + threadIdx.x;
    if (i >= total) return;
    int c = (int)(i & (size_t)cmask);
    float v = X[i] * stats[2 * C + c] + stats[3 * C + c];
    X[i] = relu ? fmaxf(v, 0.f) : v;
}

// ---------------- GCN helpers ----------------
__global__ void deg_scatter(const float* __restrict__ ew, const int* __restrict__ col,
                            float* __restrict__ deg, int nE) {
    int e = blockIdx.x * blockDim.x + threadIdx.x;
    if (e < nE) atomicAdd(&deg[col[e]], ew[e]);
}

__global__ void dinv_fin(float* __restrict__ deg, int n) {
    int i = blockIdx.x * blockDim.x + threadIdx.x;
    if (i < n) {
        float d = deg[i] + 1.0f;   // self-loop weight 1
        deg[i] = d > 0.f ? rsqrtf(d) : 0.f;
    }
}

__global__ void gcn_scatter(const float* __restrict__ xw, const int* __restrict__ row,
                            const int* __restrict__ col, const float* __restrict__ ew,
                            const float* __restrict__ dinv, float* __restrict__ out, int C) {
    int e = blockIdx.x;
    int r = row[e], c = col[e];
    float nrm = dinv[r] * ew[e] * dinv[c];
    const float* xr = xw + (size_t)r * C;
    float* oc = out + (size_t)c * C;
    for (int d = threadIdx.x; d < C; d += blockDim.x)
        atomicAdd(&oc[d], nrm * xr[d]);
}

// out += xw * dinv^2 + bias  (self-loop contribution + conv bias), C==256
__global__ void gcn_self_bias(float* __restrict__ out, const float* __restrict__ xw,
                              const float* __restrict__ dinv, const float* __restrict__ bias,
                              size_t total) {
    size_t i = (size_t)blockIdx.x * blockDim.x + threadIdx.x;
    if (i >= total) return;
    int node = (int)(i >> 8);
    int c = (int)(i & 255);
    float dv = dinv[node];
    out[i] += xw[i] * dv * dv + bias[c];
}

// ---------------- pooling ----------------
__global__ void count_nodes(const int* __restrict__ batch, float* __restrict__ cnt, int n) {
    int i = blockIdx.x * blockDim.x + threadIdx.x;
    if (i < n) atomicAdd(&cnt[batch[i]], 1.0f);
}

__global__ void node_pool(const float* __restrict__ xn, const int* __restrict__ batch,
                          float* __restrict__ xg) {
    int i = blockIdx.x;
    int d = threadIdx.x;   // 128
    atomicAdd(&xg[(size_t)batch[i] * 128 + d], xn[(size_t)i * 128 + d]);
}

__global__ void pool_div(float* __restrict__ xg, const float* __restrict__ cnt) {
    int i = blockIdx.x * blockDim.x + threadIdx.x;   // B*128 total
    int g = i >> 7;
    xg[i] /= fmaxf(cnt[g], 1.0f);
}

// svc slots: row i belongs to slot i%50, exactly 1024 rows per slot
__global__ void svc_pool(const float* __restrict__ xsl, float* __restrict__ xsg) {
    int o = blockIdx.x;    // 50
    int d = threadIdx.x;   // 128
    float s = 0.f;
    for (int r = 0; r < 1024; ++r)
        s += xsl[((size_t)(r * 50 + o)) * 128 + d];
    xsg[o * 128 + d] = s * (1.0f / 1024.0f);
}

// ---------------- final: out[g][o] = sigmoid(dot(xg[g], xsg[o])) ----------------
__global__ void final_out(const float* __restrict__ xg, const float* __restrict__ xsg,
                          const int* __restrict__ modes, void* __restrict__ out) {
    __shared__ float xrow[128];
    int g = blockIdx.x;
    for (int d = threadIdx.x; d < 128; d += 64) xrow[d] = xg[(size_t)g * 128 + d];
    __syncthreads();
    int o = threadIdx.x;
    if (o < 50) {
        const float* xs = xsg + o * 128;
        float s = 0.f;
        #pragma unroll 4
        for (int d = 0; d < 128; ++d) s += xrow[d] * xs[d];
        float sg = 1.0f / (1.0f + __expf(-s));
        if (modes[0] == 1) ((bf16*)out)[(size_t)g * 50 + o] = __float2bfloat16(sg);
        else               ((float*)out)[(size_t)g * 50 + o] = sg;
    }
}

extern "C" void kernel_launch(void* const* d_in, const int* in_sizes, int n_in,
                              void* d_out, int out_size, void* d_ws, size_t ws_size,
                              hipStream_t stream) {
    const int  nN  = 100000, nE = 800000, nS = 51200, nES = 409600;
    const int  Bg  = 1024;

    const int*  node_ids   = (const int*)d_in[0];
    const int*  ei         = (const int*)d_in[2];   // [2, nE]
    const int*  svc_ids    = (const int*)d_in[3];
    const int*  eis        = (const int*)d_in[5];   // [2, nES]
    const int*  batch      = (const int*)d_in[7];

    // workspace layout (floats)
    float* ws    = (float*)d_ws;
    float* conv  = ws;                              // cap 1,600,000
    int*   modes = (int*)(ws + 1600000);            // 64 slots
    float* stats = ws + 1600064;                    // 1,024
    float* dinv  = stats + 1024;                    // 51,200
    float* xg    = dinv + 51200;                    // 131,072
    float* cnt   = xg + 131072;                     // 1,024 (contiguous after xg)
    float* xsg   = cnt + 1024;                      // 6,400
    float* buf0  = xsg + 6400;                      // 13,107,200
    float* buf1  = buf0 + 13107200;                 // 13,107,200
    float* buf2  = buf1 + 13107200;                 // 25,600,000
    size_t need  = (size_t)(buf2 + 25600000 - ws) * sizeof(float);
    if (ws_size < need) return;
    float* xn = buf2;                               // alias: free when node_lin runs

    // ---------------- dtype-detect + convert all float inputs to fp32 ----------------
    static const int conv_idx[NCONV] = {1, 4, 6, 10, 11,
        12, 13, 14, 15, 16, 17, 18, 19, 20,
        21, 22, 23, 24, 25, 26, 27, 28, 29,
        30, 31, 32, 33, 34, 35, 36, 37, 38, 39, 40, 41};
    ConvArgs ca;
    float* cv[NCONV];
    {
        float* c = conv;
        int maxn = 0;
        for (int b = 0; b < NCONV; ++b) {
            int di = conv_idx[b];
            ca.src[b] = d_in[di];
            ca.n[b]   = in_sizes[di];
            ca.dst[b] = c;
            cv[b] = c;
            c += in_sizes[di];
            if (in_sizes[di] > maxn) maxn = in_sizes[di];
        }
        int gx = (maxn + 1023) / 1024;
        convert_all<<<dim3(gx, NCONV), 256, 0, stream>>>(ca, modes);
    }
    float *c_node_feats = cv[0], *c_svc_feats = cv[1], *c_ew = cv[2];
    float *c_emb_node = cv[3], *c_emb_svc = cv[4];
    float *c_g0_W1 = cv[5], *c_g0_b1 = cv[6], *c_g0_bng = cv[7], *c_g0_bnb = cv[8];
    float *c_g0_W2 = cv[9], *c_g0_b2 = cv[10], *c_g0_eps = cv[11];
    float *c_bn0_g = cv[12], *c_bn0_b = cv[13];
    float *c_g1_W1 = cv[14], *c_g1_b1 = cv[15], *c_g1_bng = cv[16], *c_g1_bnb = cv[17];
    float *c_g1_W2 = cv[18], *c_g1_b2 = cv[19], *c_g1_eps = cv[20];
    float *c_bn1_g = cv[21], *c_bn1_b = cv[22];
    float *c_nl_W = cv[23], *c_nl_b = cv[24];
    float *c_c0_W = cv[25], *c_c0_b = cv[26], *c_cbn0_g = cv[27], *c_cbn0_b = cv[28];
    float *c_c1_W = cv[29], *c_c1_b = cv[30], *c_cbn1_g = cv[31], *c_cbn1_b = cv[32];
    float *c_sl_W = cv[33], *c_sl_b = cv[34];

    auto gemm = [&](const float* A, const float* W, const float* bias, float* C,
                    int M, int N, int K) {
        dim3 grid(N / 64, (M + 63) / 64);
        gemm_f32<<<grid, 256, 0, stream>>>(A, W, bias, C, M, N, K);
    };
    auto bn = [&](float* X, const float* g, const float* b, int M, int C, int relu) {
        hipMemsetAsync(stats, 0, 2 * C * sizeof(float), stream);
        int rows = 512, nb = (M + rows - 1) / rows;
        bn_stats<<<nb, C, 0, stream>>>(X, stats, M, C, rows);
        bn_finalize<<<1, C, 0, stream>>>(stats, g, b, C, 1.0f / M);
        size_t total = (size_t)M * C;
        bn_apply<<<(total + 255) / 256, 256, 0, stream>>>(X, stats, total, C - 1, C, relu);
    };

    // ---------------- node branch ----------------
    build_feat<<<nN, 128, 0, stream>>>(c_emb_node, node_ids, c_node_feats, buf0, 6);
    hipMemsetAsync(buf1, 0, (size_t)nN * 70 * sizeof(float), stream);
    scatter_add<<<nE, 64, 0, stream>>>(buf0, ei, ei + nE, buf1, 70);
    { size_t t = (size_t)nN * 70;
      gin_combine<<<(t + 255) / 256, 256, 0, stream>>>(buf1, buf0, c_g0_eps, t); }
    gemm(buf1, c_g0_W1, c_g0_b1, buf2, nN, 256, 70);
    bn(buf2, c_g0_bng, c_g0_bnb, nN, 256, 1);
    gemm(buf2, c_g0_W2, c_g0_b2, buf0, nN, 128, 256);
    bn(buf0, c_bn0_g, c_bn0_b, nN, 128, 1);

    hipMemsetAsync(buf1, 0, (size_t)nN * 128 * sizeof(float), stream);
    scatter_add<<<nE, 64, 0, stream>>>(buf0, ei, ei + nE, buf1, 128);
    { size_t t = (size_t)nN * 128;
      gin_combine<<<(t + 255) / 256, 256, 0, stream>>>(buf1, buf0, c_g1_eps, t); }
    gemm(buf1, c_g1_W1, c_g1_b1, buf2, nN, 256, 128);
    bn(buf2, c_g1_bng, c_g1_bnb, nN, 256, 1);
    gemm(buf2, c_g1_W2, c_g1_b2, buf0, nN, 128, 256);
    bn(buf0, c_bn1_g, c_bn1_b, nN, 128, 1);
    gemm(buf0, c_nl_W, c_nl_b, xn, nN, 128, 128);

    // node pooling
    hipMemsetAsync(xg, 0, (131072 + 1024) * sizeof(float), stream);  // xg + cnt
    count_nodes<<<(nN + 255) / 256, 256, 0, stream>>>(batch, cnt, nN);
    node_pool<<<nN, 128, 0, stream>>>(xn, batch, xg);
    pool_div<<<(Bg * 128) / 256, 256, 0, stream>>>(xg, cnt);

    // ---------------- service branch ----------------
    build_feat<<<nS, 128, 0, stream>>>(c_emb_svc, svc_ids, c_svc_feats, buf2, 4);
    hipMemsetAsync(dinv, 0, nS * sizeof(float), stream);
    deg_scatter<<<(nES + 255) / 256, 256, 0, stream>>>(c_ew, eis + nES, dinv, nES);
    dinv_fin<<<(nS + 255) / 256, 256, 0, stream>>>(dinv, nS);

    gemm(buf2, c_c0_W, nullptr, buf0, nS, 256, 68);
    hipMemsetAsync(buf1, 0, (size_t)nS * 256 * sizeof(float), stream);
    gcn_scatter<<<nES, 256, 0, stream>>>(buf0, eis, eis + nES, c_ew, dinv, buf1, 256);
    gcn_self_bias<<<((size_t)nS * 256) / 256, 256, 0, stream>>>(buf1, buf0, dinv, c_c0_b,
                                                               (size_t)nS * 256);
    bn(buf1, c_cbn0_g, c_cbn0_b, nS, 256, 1);

    gemm(buf1, c_c1_W, nullptr, buf0, nS, 256, 256);
    hipMemsetAsync(buf2, 0, (size_t)nS * 256 * sizeof(float), stream);
    gcn_scatter<<<nES, 256, 0, stream>>>(buf0, eis, eis + nES, c_ew, dinv, buf2, 256);
    gcn_self_bias<<<((size_t)nS * 256) / 256, 256, 0, stream>>>(buf2, buf0, dinv, c_c1_b,
                                                               (size_t)nS * 256);
    bn(buf2, c_cbn1_g, c_cbn1_b, nS, 256, 1);

    gemm(buf2, c_sl_W, c_sl_b, buf0, nS, 128, 256);
    svc_pool<<<50, 128, 0, stream>>>(buf0, xsg);

    // ---------------- output ----------------
    final_out<<<Bg, 64, 0, stream>>>(xg, xsg, modes, d_out);
}

// Round 3
// 2876.059 us; speedup vs baseline: 1.3235x; 1.3235x over previous
//
#include <hip/hip_runtime.h>
#include <hip/hip_bf16.h>
#include <cstddef>
#include <cstdint>

typedef __hip_bfloat16 bf16;
static __device__ __forceinline__ float b2f(bf16 v) { return __bfloat162float(v); }

#define NCONV 35

struct ConvArgs {
    const void* src[NCONV];
    float*      dst[NCONV];
    int         n[NCONV];
};

// ---------------- dtype detection ----------------
// mode: 0 = all-zero, 1 = bf16-stored, 2 = fp32-stored
__device__ int detect_mode(const unsigned short* w, int n) {
    __shared__ int cz, cbad, cevz, codz;
    if (threadIdx.x == 0) { cz = 0; cbad = 0; cevz = 0; codz = 0; }
    __syncthreads();
    int K = n < 2048 ? n : 2048;
    int z = 0, bad = 0, evz = 0, odz = 0;
    for (int i = threadIdx.x; i < K; i += blockDim.x) {
        unsigned short v = w[i];
        int e = (v >> 7) & 0xFF;
        bool isz = (v & 0x7FFF) == 0;
        if (isz) { z++; if (i & 1) odz++; else evz++; }
        else if (e < 91 || e > 140) bad++;
    }
    atomicAdd(&cz, z); atomicAdd(&cbad, bad);
    atomicAdd(&cevz, evz); atomicAdd(&codz, odz);
    __syncthreads();
    int Z = cz, Bc = cbad, EZ = cevz, OZ = codz;
    if (Z >= K) return 0;
    if (Bc * 16 > K) return 2;
    if (EZ * 4 > K && OZ * 16 < K) return 2;
    return 1;
}

__global__ __launch_bounds__(256) void convert_all(ConvArgs a, int* __restrict__ modes) {
    int b = blockIdx.y;
    int n = a.n[b];
    const unsigned short* w = (const unsigned short*)a.src[b];
    int mode = detect_mode(w, n);
    if (blockIdx.x == 0 && threadIdx.x == 0) modes[b] = mode;
    float* dst = a.dst[b];
    const float* f = (const float*)a.src[b];
    const bf16*  h = (const bf16*)a.src[b];
    int i0 = blockIdx.x * 1024 + threadIdx.x;
    #pragma unroll
    for (int k = 0; k < 4; ++k) {
        int i = i0 + k * 256;
        if (i < n) {
            float v;
            if (mode == 0)      v = 0.f;
            else if (mode == 1) v = b2f(h[i]);
            else                v = f[i];
            dst[i] = v;
        }
    }
}

// ---------------- feature build (padded stride) ----------------
// out[i] = concat(emb[ids[i]](64), feats[i](nf), zeros) with row stride Ws
__global__ void build_feat(const float* __restrict__ emb, const int* __restrict__ ids,
                           const float* __restrict__ feats, float* __restrict__ out,
                           int nf, int Ws) {
    int i = blockIdx.x;
    int d = threadIdx.x;           // blockDim = 128
    if (d >= Ws) return;
    float v;
    if (d < 64)           v = emb[ids[i] * 64 + d];
    else if (d < 64 + nf) v = feats[(size_t)i * nf + (d - 64)];
    else                  v = 0.f;
    out[(size_t)i * Ws + d] = v;
}

// ---------------- CSR build ----------------
__global__ void csr_count(const int* __restrict__ dst, int nE, int* __restrict__ cnt) {
    int e = blockIdx.x * blockDim.x + threadIdx.x;
    if (e < nE) atomicAdd(&cnt[dst[e]], 1);
}

// single-block exclusive scan (n up to ~100k)
__global__ __launch_bounds__(1024) void scan_excl(const int* __restrict__ cnt,
                                                  int* __restrict__ rowptr, int n) {
    __shared__ int ssum[1024];
    int T = 1024, t = threadIdx.x;
    int chunk = (n + T - 1) / T;
    int lo = t * chunk, hi = min(lo + chunk, n);
    int s = 0;
    for (int i = lo; i < hi; ++i) s += cnt[i];
    ssum[t] = s;
    __syncthreads();
    for (int off = 1; off < T; off <<= 1) {
        int v = (t >= off) ? ssum[t - off] : 0;
        __syncthreads();
        ssum[t] += v;
        __syncthreads();
    }
    int run = t ? ssum[t - 1] : 0;
    for (int i = lo; i < hi; ++i) { rowptr[i] = run; run += cnt[i]; }
    if (t == T - 1) rowptr[n] = run;
}

__global__ void copy_int(const int* __restrict__ a, int* __restrict__ b, int n) {
    int i = blockIdx.x * blockDim.x + threadIdx.x;
    if (i < n) b[i] = a[i];
}

__global__ void csr_fill(const int* __restrict__ src, const int* __restrict__ dst,
                         const float* __restrict__ w, int nE, int* __restrict__ cursor,
                         int* __restrict__ adj, float* __restrict__ adjw) {
    int e = blockIdx.x * blockDim.x + threadIdx.x;
    if (e < nE) {
        int pos = atomicAdd(&cursor[dst[e]], 1);
        adj[pos] = src[e];
        if (adjw) adjw[pos] = w[e];
    }
}

// ---------------- GIN gather (fused combine): out = (1+eps)*x + sum_{src->i} x[src] ----------------
__global__ void gin_gather(const float* __restrict__ x, const int* __restrict__ rowptr,
                           const int* __restrict__ adj, const float* __restrict__ eps,
                           float* __restrict__ out, int Ws) {
    int i = blockIdx.x;
    int d = threadIdx.x;   // blockDim 128
    if (d >= Ws) return;
    int lo = rowptr[i], hi = rowptr[i + 1];
    float acc = 0.f;
    for (int p = lo; p < hi; ++p)
        acc += x[(size_t)adj[p] * Ws + d];
    out[(size_t)i * Ws + d] = acc + (1.0f + eps[0]) * x[(size_t)i * Ws + d];
}

// ---------------- GCN gather (fused self-loop + bias), C=256 ----------------
__global__ void gcn_gather(const float* __restrict__ xw, const int* __restrict__ rowptr,
                           const int* __restrict__ adj, const float* __restrict__ adjw,
                           const float* __restrict__ dinv, const float* __restrict__ bias,
                           float* __restrict__ out) {
    int i = blockIdx.x;
    int d = threadIdx.x;   // 256
    float di = dinv[i];
    float acc = xw[(size_t)i * 256 + d] * di * di + bias[d];
    int lo = rowptr[i], hi = rowptr[i + 1];
    for (int p = lo; p < hi; ++p) {
        int s = adj[p];
        acc += di * dinv[s] * adjw[p] * xw[(size_t)s * 256 + d];
    }
    out[(size_t)i * 256 + d] = acc;
}

// ---------------- fp32 GEMM v2: 128x128 tile, 8x8/thread ----------------
// A: M x lda (pad cols zeroed, Klog <= lda, Klog % 16 == 0)
// W: KW x ldw (rows k >= KW treated as zero); C: M x ldw
__global__ __launch_bounds__(256) void gemm_f32_v2(const float* __restrict__ A, int lda, int Klog,
                                                   const float* __restrict__ W, int ldw, int KW,
                                                   const float* __restrict__ bias,
                                                   float* __restrict__ C, int M) {
    __shared__ float As[16][132];
    __shared__ float Bs[16][132];
    int tid = threadIdx.x;
    int tx = tid & 15, ty = tid >> 4;
    int bn = blockIdx.x * 128, bm = blockIdx.y * 128;
    float acc[8][8] = {};
    for (int k0 = 0; k0 < Klog; k0 += 16) {
        // stage A (transposed): As[k][m] = A[bm+m][k0+k]
        #pragma unroll
        for (int s = tid; s < 512; s += 256) {
            int m = s >> 2, kq = s & 3;
            int row = bm + m;
            float4 v = {0.f, 0.f, 0.f, 0.f};
            if (row < M) v = *(const float4*)&A[(size_t)row * lda + k0 + kq * 4];
            As[kq * 4 + 0][m] = v.x;
            As[kq * 4 + 1][m] = v.y;
            As[kq * 4 + 2][m] = v.z;
            As[kq * 4 + 3][m] = v.w;
        }
        // stage B: Bs[k][n] = W[k0+k][bn+n]
        #pragma unroll
        for (int s = tid; s < 512; s += 256) {
            int kR = s >> 5, n4 = s & 31;
            int kk = k0 + kR;
            float4 v = {0.f, 0.f, 0.f, 0.f};
            if (kk < KW) v = *(const float4*)&W[(size_t)kk * ldw + bn + n4 * 4];
            *(float4*)&Bs[kR][n4 * 4] = v;
        }
        __syncthreads();
        #pragma unroll
        for (int kk = 0; kk < 16; ++kk) {
            float4 a0 = *(const float4*)&As[kk][ty * 4];
            float4 a1 = *(const float4*)&As[kk][64 + ty * 4];
            float4 b0 = *(const float4*)&Bs[kk][tx * 4];
            float4 b1 = *(const float4*)&Bs[kk][64 + tx * 4];
            float a[8] = {a0.x, a0.y, a0.z, a0.w, a1.x, a1.y, a1.z, a1.w};
            float b[8] = {b0.x, b0.y, b0.z, b0.w, b1.x, b1.y, b1.z, b1.w};
            #pragma unroll
            for (int i = 0; i < 8; ++i)
                #pragma unroll
                for (int j = 0; j < 8; ++j)
                    acc[i][j] += a[i] * b[j];
        }
        __syncthreads();
    }
    #pragma unroll
    for (int i = 0; i < 8; ++i) {
        int row = bm + ((i >> 2) << 6) + ty * 4 + (i & 3);
        if (row >= M) continue;
        #pragma unroll
        for (int h = 0; h < 2; ++h) {
            int col = bn + (h << 6) + tx * 4;
            float4 o = {acc[i][h * 4 + 0], acc[i][h * 4 + 1],
                        acc[i][h * 4 + 2], acc[i][h * 4 + 3]};
            if (bias) {
                o.x += bias[col + 0]; o.y += bias[col + 1];
                o.z += bias[col + 2]; o.w += bias[col + 3];
            }
            *(float4*)&C[(size_t)row * ldw + col] = o;
        }
    }
}

// ---------------- BatchNorm ----------------
__global__ void bn_stats(const float* __restrict__ X, float* __restrict__ stats,
                         int M, int C, int rows) {
    int c = threadIdx.x;                 // blockDim == C
    int r0 = blockIdx.x * rows;
    int r1 = min(r0 + rows, M);
    float s = 0.f, s2 = 0.f;
    for (int r = r0; r < r1; ++r) {
        float v = X[(size_t)r * C + c];
        s += v; s2 += v * v;
    }
    atomicAdd(&stats[c], s);
    atomicAdd(&stats[C + c], s2);
}

__global__ void bn_finalize(float* __restrict__ stats, const float* __restrict__ g,
                            const float* __restrict__ b, int C, float invM) {
    int c = threadIdx.x;
    if (c < C) {
        float mean = stats[c] * invM;
        float var  = fmaxf(stats[C + c] * invM - mean * mean, 0.f);
        float sc   = g[c] * rsqrtf(var + 1e-5f);
        stats[2 * C + c] = sc;
        stats[3 * C + c] = b[c] - mean * sc;
    }
}

__global__ void bn_apply4(float* __restrict__ X, const float* __restrict__ stats,
                          size_t total4, int cmask, int C) {
    size_t i = (size_t)blockIdx.x * blockDim.x + threadIdx.x;
    if (i >= total4) return;
    int c = (int)((i * 4) & (size_t)cmask);
    float4 v = ((float4*)X)[i];
    const float* sc = stats + 2 * C;
    const float* sh = stats + 3 * C;
    v.x = fmaxf(v.x * sc[c + 0] + sh[c + 0], 0.f);
    v.y = fmaxf(v.y * sc[c + 1] + sh[c + 1], 0.f);
    v.z = fmaxf(v.z * sc[c + 2] + sh[c + 2], 0.f);
    v.w = fmaxf(v.w * sc[c + 3] + sh[c + 3], 0.f);
    ((float4*)X)[i] = v;
}

// ---------------- GCN degree ----------------
__global__ void deg_scatter(const float* __restrict__ ew, const int* __restrict__ col,
                            float* __restrict__ deg, int nE) {
    int e = blockIdx.x * blockDim.x + threadIdx.x;
    if (e < nE) atomicAdd(&deg[col[e]], ew[e]);
}

__global__ void dinv_fin(float* __restrict__ deg, int n) {
    int i = blockIdx.x * blockDim.x + threadIdx.x;
    if (i < n) {
        float d = deg[i] + 1.0f;   // self-loop weight 1
        deg[i] = d > 0.f ? rsqrtf(d) : 0.f;
    }
}

// ---------------- pooling: batch is sorted -> segmented reduction via binary search ----------------
__global__ void pool_sorted(const float* __restrict__ xn, const int* __restrict__ batch,
                            float* __restrict__ xg, int nN) {
    int g = blockIdx.x;
    int lo = 0, hi = nN;
    while (lo < hi) { int mid = (lo + hi) >> 1; if (batch[mid] < g) lo = mid + 1; else hi = mid; }
    int lo2 = lo, hi2 = nN;
    while (lo2 < hi2) { int mid = (lo2 + hi2) >> 1; if (batch[mid] < g + 1) lo2 = mid + 1; else hi2 = mid; }
    int d = threadIdx.x;   // 128
    float s = 0.f;
    for (int r = lo; r < lo2; ++r) s += xn[(size_t)r * 128 + d];
    float c = (float)(lo2 - lo);
    xg[(size_t)g * 128 + d] = s / fmaxf(c, 1.0f);
}

// svc pooling two-stage: slot o = row % 50, 1024 rows per slot
__global__ void svc_pool1(const float* __restrict__ xsl, float* __restrict__ partial) {
    int o = blockIdx.x;    // 50
    int c = blockIdx.y;    // 16
    int d = threadIdx.x;   // 128
    float s = 0.f;
    int r0 = c * 64;
    for (int r = r0; r < r0 + 64; ++r)
        s += xsl[((size_t)(r * 50 + o)) * 128 + d];
    partial[((size_t)(o * 16 + c)) * 128 + d] = s;
}

__global__ void svc_pool2(const float* __restrict__ partial, float* __restrict__ xsg) {
    int o = blockIdx.x;    // 50
    int d = threadIdx.x;   // 128
    float s = 0.f;
    #pragma unroll
    for (int c = 0; c < 16; ++c)
        s += partial[((size_t)(o * 16 + c)) * 128 + d];
    xsg[o * 128 + d] = s * (1.0f / 1024.0f);
}

// ---------------- final ----------------
__global__ void final_out(const float* __restrict__ xg, const float* __restrict__ xsg,
                          const int* __restrict__ modes, void* __restrict__ out) {
    __shared__ float xrow[128];
    int g = blockIdx.x;
    for (int d = threadIdx.x; d < 128; d += 64) xrow[d] = xg[(size_t)g * 128 + d];
    __syncthreads();
    int o = threadIdx.x;
    if (o < 50) {
        const float* xs = xsg + o * 128;
        float s = 0.f;
        #pragma unroll 4
        for (int d = 0; d < 128; ++d) s += xrow[d] * xs[d];
        float sg = 1.0f / (1.0f + __expf(-s));
        if (modes[0] == 1) ((bf16*)out)[(size_t)g * 50 + o] = __float2bfloat16(sg);
        else               ((float*)out)[(size_t)g * 50 + o] = sg;
    }
}

extern "C" void kernel_launch(void* const* d_in, const int* in_sizes, int n_in,
                              void* d_out, int out_size, void* d_ws, size_t ws_size,
                              hipStream_t stream) {
    const int nN = 100000, nE = 800000, nS = 51200, nES = 409600;
    const int Bg = 1024;

    const int* node_ids = (const int*)d_in[0];
    const int* ei       = (const int*)d_in[2];   // [2, nE]
    const int* svc_ids  = (const int*)d_in[3];
    const int* eis      = (const int*)d_in[5];   // [2, nES]
    const int* batch    = (const int*)d_in[7];

    // workspace layout (4-byte words)
    float* ws    = (float*)d_ws;
    float* conv  = ws;                              // 1,600,000 cap
    int*   modes = (int*)(ws + 1600000);            // 64
    float* stats = ws + 1600064;                    // 1,024
    float* dinv  = stats + 1024;                    // 51,200
    float* xg    = dinv + 51200;                    // 131,072
    float* xsg   = xg + 131072;                     // 6,400
    float* part  = xsg + 6400;                      // 102,400
    int*   rp_n  = (int*)(part + 102400);           // 100,001
    int*   cur_n = rp_n + 100001;                   // 100,000
    int*   adj_n = cur_n + 100000;                  // 800,000
    int*   rp_s  = adj_n + 800000;                  // 51,201
    int*   cur_s = rp_s + 51201;                    // 51,200
    int*   adj_s = cur_s + 51200;                   // 409,600
    float* adw_s = (float*)(adj_s + 409600);        // 409,600
    float* buf0  = adw_s + 409600;                  // 13,107,200
    float* buf1  = buf0 + 13107200;                 // 13,107,200
    float* buf2  = buf1 + 13107200;                 // 25,600,000
    size_t need  = (size_t)((char*)(buf2 + 25600000) - (char*)ws);
    if (ws_size < need) return;
    float* xn = buf2;                               // alias (free until pooling)

    // ---------------- dtype-detect + convert ----------------
    static const int conv_idx[NCONV] = {1, 4, 6, 10, 11,
        12, 13, 14, 15, 16, 17, 18, 19, 20,
        21, 22, 23, 24, 25, 26, 27, 28, 29,
        30, 31, 32, 33, 34, 35, 36, 37, 38, 39, 40, 41};
    ConvArgs ca;
    float* cv[NCONV];
    {
        float* c = conv;
        int maxn = 0;
        for (int b = 0; b < NCONV; ++b) {
            int di = conv_idx[b];
            ca.src[b] = d_in[di];
            ca.n[b]   = in_sizes[di];
            ca.dst[b] = c;
            cv[b] = c;
            c += in_sizes[di];
            if (in_sizes[di] > maxn) maxn = in_sizes[di];
        }
        int gx = (maxn + 1023) / 1024;
        convert_all<<<dim3(gx, NCONV), 256, 0, stream>>>(ca, modes);
    }
    float *c_node_feats = cv[0], *c_svc_feats = cv[1], *c_ew = cv[2];
    float *c_emb_node = cv[3], *c_emb_svc = cv[4];
    float *c_g0_W1 = cv[5], *c_g0_b1 = cv[6], *c_g0_bng = cv[7], *c_g0_bnb = cv[8];
    float *c_g0_W2 = cv[9], *c_g0_b2 = cv[10], *c_g0_eps = cv[11];
    float *c_bn0_g = cv[12], *c_bn0_b = cv[13];
    float *c_g1_W1 = cv[14], *c_g1_b1 = cv[15], *c_g1_bng = cv[16], *c_g1_bnb = cv[17];
    float *c_g1_W2 = cv[18], *c_g1_b2 = cv[19], *c_g1_eps = cv[20];
    float *c_bn1_g = cv[21], *c_bn1_b = cv[22];
    float *c_nl_W = cv[23], *c_nl_b = cv[24];
    float *c_c0_W = cv[25], *c_c0_b = cv[26], *c_cbn0_g = cv[27], *c_cbn0_b = cv[28];
    float *c_c1_W = cv[29], *c_c1_b = cv[30], *c_cbn1_g = cv[31], *c_cbn1_b = cv[32];
    float *c_sl_W = cv[33], *c_sl_b = cv[34];

    auto gemm = [&](const float* A, int lda, int Klog, const float* W, int ldw, int KW,
                    const float* bias, float* C, int M) {
        dim3 grid(ldw / 128, (M + 127) / 128);
        gemm_f32_v2<<<grid, 256, 0, stream>>>(A, lda, Klog, W, ldw, KW, bias, C, M);
    };
    auto bn = [&](float* X, const float* g, const float* b, int M, int C) {
        hipMemsetAsync(stats, 0, 2 * C * sizeof(float), stream);
        int rows = 512, nb = (M + rows - 1) / rows;
        bn_stats<<<nb, C, 0, stream>>>(X, stats, M, C, rows);
        bn_finalize<<<1, C, 0, stream>>>(stats, g, b, C, 1.0f / M);
        size_t total4 = (size_t)M * C / 4;
        bn_apply4<<<(total4 + 255) / 256, 256, 0, stream>>>(X, stats, total4, C - 1, C);
    };

    // ---------------- CSR builds ----------------
    hipMemsetAsync(cur_n, 0, nN * sizeof(int), stream);   // cur_n as counts first
    csr_count<<<(nE + 255) / 256, 256, 0, stream>>>(ei + nE, nE, cur_n);
    scan_excl<<<1, 1024, 0, stream>>>(cur_n, rp_n, nN);
    copy_int<<<(nN + 255) / 256, 256, 0, stream>>>(rp_n, cur_n, nN);
    csr_fill<<<(nE + 255) / 256, 256, 0, stream>>>(ei, ei + nE, nullptr, nE, cur_n, adj_n, nullptr);

    hipMemsetAsync(cur_s, 0, nS * sizeof(int), stream);
    csr_count<<<(nES + 255) / 256, 256, 0, stream>>>(eis + nES, nES, cur_s);
    scan_excl<<<1, 1024, 0, stream>>>(cur_s, rp_s, nS);
    copy_int<<<(nS + 255) / 256, 256, 0, stream>>>(rp_s, cur_s, nS);
    csr_fill<<<(nES + 255) / 256, 256, 0, stream>>>(eis, eis + nES, c_ew, nES, cur_s, adj_s, adw_s);

    // ---------------- node branch ----------------
    build_feat<<<nN, 128, 0, stream>>>(c_emb_node, node_ids, c_node_feats, buf0, 6, 80);
    gin_gather<<<nN, 128, 0, stream>>>(buf0, rp_n, adj_n, c_g0_eps, buf1, 80);
    gemm(buf1, 80, 80, c_g0_W1, 256, 70, c_g0_b1, buf2, nN);
    bn(buf2, c_g0_bng, c_g0_bnb, nN, 256);
    gemm(buf2, 256, 256, c_g0_W2, 128, 256, c_g0_b2, buf0, nN);
    bn(buf0, c_bn0_g, c_bn0_b, nN, 128);

    gin_gather<<<nN, 128, 0, stream>>>(buf0, rp_n, adj_n, c_g1_eps, buf1, 128);
    gemm(buf1, 128, 128, c_g1_W1, 256, 128, c_g1_b1, buf2, nN);
    bn(buf2, c_g1_bng, c_g1_bnb, nN, 256);
    gemm(buf2, 256, 256, c_g1_W2, 128, 256, c_g1_b2, buf0, nN);
    bn(buf0, c_bn1_g, c_bn1_b, nN, 128);
    gemm(buf0, 128, 128, c_nl_W, 128, 128, c_nl_b, xn, nN);

    // node pooling (batch sorted)
    pool_sorted<<<Bg, 128, 0, stream>>>(xn, batch, xg, nN);

    // ---------------- service branch ----------------
    build_feat<<<nS, 128, 0, stream>>>(c_emb_svc, svc_ids, c_svc_feats, buf2, 4, 80);
    hipMemsetAsync(dinv, 0, nS * sizeof(float), stream);
    deg_scatter<<<(nES + 255) / 256, 256, 0, stream>>>(c_ew, eis + nES, dinv, nES);
    dinv_fin<<<(nS + 255) / 256, 256, 0, stream>>>(dinv, nS);

    gemm(buf2, 80, 80, c_c0_W, 256, 68, nullptr, buf0, nS);
    gcn_gather<<<nS, 256, 0, stream>>>(buf0, rp_s, adj_s, adw_s, dinv, c_c0_b, buf1);
    bn(buf1, c_cbn0_g, c_cbn0_b, nS, 256);

    gemm(buf1, 256, 256, c_c1_W, 256, 256, nullptr, buf0, nS);
    gcn_gather<<<nS, 256, 0, stream>>>(buf0, rp_s, adj_s, adw_s, dinv, c_c1_b, buf2);
    bn(buf2, c_cbn1_g, c_cbn1_b, nS, 256);

    gemm(buf2, 256, 256, c_sl_W, 128, 256, c_sl_b, buf0, nS);
    svc_pool1<<<dim3(50, 16), 128, 0, stream>>>(buf0, part);
    svc_pool2<<<50, 128, 0, stream>>>(part, xsg);

    // ---------------- output ----------------
    final_out<<<Bg, 64, 0, stream>>>(xg, xsg, modes, d_out);
}

// Round 4
// 2002.396 us; speedup vs baseline: 1.9010x; 1.4363x over previous
//
#include <hip/hip_runtime.h>
#include <hip/hip_bf16.h>
#include <cstddef>
#include <cstdint>

typedef __hip_bfloat16 bf16;
typedef __attribute__((ext_vector_type(8))) short short8;   // 8 bf16 (4 VGPRs)
typedef __attribute__((ext_vector_type(4))) float floatx4;  // MFMA acc

static __device__ __forceinline__ float b2f(bf16 v) { return __bfloat162float(v); }

static __device__ __forceinline__ short f2bf(float f) {
    unsigned u = __float_as_uint(f);
    unsigned r = u + 0x7FFF + ((u >> 16) & 1);
    return (short)(r >> 16);
}
static __device__ __forceinline__ float bf2f(short h) {
    return __uint_as_float(((unsigned)(unsigned short)h) << 16);
}
static __device__ __forceinline__ void splitf(float f, short& hi, short& lo) {
    hi = f2bf(f);
    lo = f2bf(f - bf2f(hi));
}
// mode: 0=zero, 1=bf16-stored, 2=fp32-stored
static __device__ __forceinline__ float loadf(const void* p, int mode, size_t i) {
    if (mode == 1) return b2f(((const bf16*)p)[i]);
    if (mode == 2) return ((const float*)p)[i];
    return 0.f;
}

#define NCONV 35
struct DetArgs { const void* src[NCONV]; int n[NCONV]; };

// ---------------- dtype detection (one block per buffer) ----------------
__global__ void detect_all(DetArgs a, int* __restrict__ modes) {
    int b = blockIdx.x;
    int n = a.n[b];
    const unsigned short* w = (const unsigned short*)a.src[b];
    __shared__ int cz, cbad, cevz, codz;
    if (threadIdx.x == 0) { cz = 0; cbad = 0; cevz = 0; codz = 0; }
    __syncthreads();
    int K = n < 2048 ? n : 2048;
    int z = 0, bad = 0, evz = 0, odz = 0;
    for (int i = threadIdx.x; i < K; i += blockDim.x) {
        unsigned short v = w[i];
        int e = (v >> 7) & 0xFF;
        bool isz = (v & 0x7FFF) == 0;
        if (isz) { z++; if (i & 1) odz++; else evz++; }
        else if (e < 91 || e > 140) bad++;
    }
    atomicAdd(&cz, z); atomicAdd(&cbad, bad);
    atomicAdd(&cevz, evz); atomicAdd(&codz, odz);
    __syncthreads();
    if (threadIdx.x == 0) {
        int mode;
        if (cz >= K) mode = 0;
        else if (cbad * 16 > K) mode = 2;
        else if (cevz * 4 > K && codz * 16 < K) mode = 2;
        else mode = 1;
        modes[b] = mode;
    }
}

// ---------------- weight transpose -> bf16 Wt[n][Kpad] ----------------
__global__ void wt_build(const void* __restrict__ W, const int* __restrict__ modes, int midx,
                         int KW, int ldw, short* __restrict__ wt, int Kpad) {
    int n = blockIdx.x;
    int k = threadIdx.x;          // block 256
    if (k >= Kpad) return;
    int mode = modes[midx];
    float v = (k < KW) ? loadf(W, mode, (size_t)k * ldw + n) : 0.f;
    wt[(size_t)n * Kpad + k] = f2bf(v);
}

// ---------------- feature build -> pair planes ----------------
__global__ void build_feat_pair(const void* __restrict__ emb, const int* __restrict__ ids,
                                const void* __restrict__ feats, const int* __restrict__ modes,
                                int eidx, int fidx, short* __restrict__ H, short* __restrict__ L,
                                int nf, int Ws) {
    int i = blockIdx.x;
    int d = threadIdx.x;          // 128
    if (d >= Ws) return;
    float v;
    if (d < 64)           v = loadf(emb, modes[eidx], (size_t)ids[i] * 64 + d);
    else if (d < 64 + nf) v = loadf(feats, modes[fidx], (size_t)i * nf + (d - 64));
    else                  v = 0.f;
    short hh, ll; splitf(v, hh, ll);
    size_t o = (size_t)i * Ws + d;
    H[o] = hh; L[o] = ll;
}

// ---------------- CSR build ----------------
__global__ void csr_count(const int* __restrict__ dst, int nE, int* __restrict__ cnt) {
    int e = blockIdx.x * blockDim.x + threadIdx.x;
    if (e < nE) atomicAdd(&cnt[dst[e]], 1);
}

__global__ __launch_bounds__(1024) void scan_excl(const int* __restrict__ cnt,
                                                  int* __restrict__ rowptr, int n) {
    __shared__ int ssum[1024];
    int T = 1024, t = threadIdx.x;
    int chunk = (n + T - 1) / T;
    int lo = t * chunk, hi = min(lo + chunk, n);
    int s = 0;
    for (int i = lo; i < hi; ++i) s += cnt[i];
    ssum[t] = s;
    __syncthreads();
    for (int off = 1; off < T; off <<= 1) {
        int v = (t >= off) ? ssum[t - off] : 0;
        __syncthreads();
        ssum[t] += v;
        __syncthreads();
    }
    int run = t ? ssum[t - 1] : 0;
    for (int i = lo; i < hi; ++i) { rowptr[i] = run; run += cnt[i]; }
    if (t == T - 1) rowptr[n] = run;
}

__global__ void copy_int(const int* __restrict__ a, int* __restrict__ b, int n) {
    int i = blockIdx.x * blockDim.x + threadIdx.x;
    if (i < n) b[i] = a[i];
}

__global__ void csr_fill(const int* __restrict__ src, const int* __restrict__ dst,
                         const void* __restrict__ w, const int* __restrict__ modes, int widx,
                         int nE, int* __restrict__ cursor,
                         int* __restrict__ adj, short* __restrict__ adjw) {
    int e = blockIdx.x * blockDim.x + threadIdx.x;
    if (e < nE) {
        int pos = atomicAdd(&cursor[dst[e]], 1);
        adj[pos] = src[e];
        if (adjw) adjw[pos] = f2bf(loadf(w, modes[widx], e));
    }
}

// ---------------- GIN gather on pairs (fused (1+eps)x) ----------------
__global__ void gin_gather_pair(const short* __restrict__ H, const short* __restrict__ L,
                                const int* __restrict__ rowptr, const int* __restrict__ adj,
                                const void* __restrict__ eps, const int* __restrict__ modes,
                                int eidx, short* __restrict__ Ho, short* __restrict__ Lo, int Ws) {
    int i = blockIdx.x;
    int d = threadIdx.x;          // 128
    if (d >= Ws) return;
    float epsv = 1.0f + loadf(eps, modes[eidx], 0);
    int lo = rowptr[i], hi = rowptr[i + 1];
    float acc = 0.f;
    for (int p = lo; p < hi; ++p) {
        size_t o = (size_t)adj[p] * Ws + d;
        acc += bf2f(H[o]) + bf2f(L[o]);
    }
    size_t o = (size_t)i * Ws + d;
    acc += epsv * (bf2f(H[o]) + bf2f(L[o]));
    short hh, ll; splitf(acc, hh, ll);
    Ho[o] = hh; Lo[o] = ll;
}

// ---------------- GCN gather (fused self-loop + bias), C=256, fp32 in/out ----------------
__global__ void gcn_gather(const float* __restrict__ xw, const int* __restrict__ rowptr,
                           const int* __restrict__ adj, const short* __restrict__ adjw,
                           const float* __restrict__ dinv, const void* __restrict__ bias,
                           const int* __restrict__ modes, int bidx, float* __restrict__ out) {
    int i = blockIdx.x;
    int d = threadIdx.x;          // 256
    float di = dinv[i];
    float acc = xw[(size_t)i * 256 + d] * di * di + loadf(bias, modes[bidx], d);
    int lo = rowptr[i], hi = rowptr[i + 1];
    for (int p = lo; p < hi; ++p) {
        int s = adj[p];
        acc += di * dinv[s] * bf2f(adjw[p]) * xw[(size_t)s * 256 + d];
    }
    out[(size_t)i * 256 + d] = acc;
}

// ---------------- MFMA GEMM: out[M,N] = A(hi+lo)[M,ldk] @ Wt^T ----------------
// pair_out=1: write split pair + column (sum,sumsq) atomics into stats
// pair_out=0: write fp32 (+bias)
__global__ __launch_bounds__(256) void gemm_mfma(
        const short* __restrict__ Ah, const short* __restrict__ Al, int ldk,
        const short* __restrict__ Wt,
        const void* __restrict__ bias, const int* __restrict__ modes, int bias_midx,
        float* __restrict__ outF, short* __restrict__ oH, short* __restrict__ oL,
        float* __restrict__ stats, int M, int N, int ksteps, int pair_out) {
    int tid  = threadIdx.x;
    int wv   = tid >> 6, lane = tid & 63;
    int m16  = lane & 15, q = lane >> 4;
    int bm   = blockIdx.y * 128 + wv * 32;
    int n0   = blockIdx.x * 128;
    int r0 = min(bm + m16, M - 1);
    int r1 = min(bm + 16 + m16, M - 1);
    const short8* pa0h = (const short8*)(Ah + (size_t)r0 * ldk + q * 8);
    const short8* pa0l = (const short8*)(Al + (size_t)r0 * ldk + q * 8);
    const short8* pa1h = (const short8*)(Ah + (size_t)r1 * ldk + q * 8);
    const short8* pa1l = (const short8*)(Al + (size_t)r1 * ldk + q * 8);
    const short8* pb[8];
    #pragma unroll
    for (int nt = 0; nt < 8; ++nt)
        pb[nt] = (const short8*)(Wt + (size_t)(n0 + nt * 16 + m16) * ldk + q * 8);

    floatx4 acc[2][8];
    #pragma unroll
    for (int mt = 0; mt < 2; ++mt)
        #pragma unroll
        for (int nt = 0; nt < 8; ++nt)
            acc[mt][nt] = (floatx4){0.f, 0.f, 0.f, 0.f};

    for (int ks = 0; ks < ksteps; ++ks) {
        int idx = ks * 4;                 // in short8 units (32 shorts / k-step)
        short8 a0h = pa0h[idx], a0l = pa0l[idx];
        short8 a1h = pa1h[idx], a1l = pa1l[idx];
        #pragma unroll
        for (int nt = 0; nt < 8; ++nt) {
            short8 b = pb[nt][idx];
            acc[0][nt] = __builtin_amdgcn_mfma_f32_16x16x32_bf16(a0h, b, acc[0][nt], 0, 0, 0);
            acc[0][nt] = __builtin_amdgcn_mfma_f32_16x16x32_bf16(a0l, b, acc[0][nt], 0, 0, 0);
            acc[1][nt] = __builtin_amdgcn_mfma_f32_16x16x32_bf16(a1h, b, acc[1][nt], 0, 0, 0);
            acc[1][nt] = __builtin_amdgcn_mfma_f32_16x16x32_bf16(a1l, b, acc[1][nt], 0, 0, 0);
        }
    }

    float bv[8];
    int bmode = bias ? modes[bias_midx] : 0;
    #pragma unroll
    for (int nt = 0; nt < 8; ++nt)
        bv[nt] = bias ? loadf(bias, bmode, n0 + nt * 16 + m16) : 0.f;

    if (pair_out) {
        float sA[8], qA[8];
        #pragma unroll
        for (int nt = 0; nt < 8; ++nt) { sA[nt] = 0.f; qA[nt] = 0.f; }
        #pragma unroll
        for (int mt = 0; mt < 2; ++mt)
            #pragma unroll
            for (int r = 0; r < 4; ++r) {
                int row = bm + mt * 16 + q * 4 + r;
                bool ok = row < M;
                #pragma unroll
                for (int nt = 0; nt < 8; ++nt) {
                    float v = acc[mt][nt][r] + bv[nt];
                    if (ok) {
                        size_t o = (size_t)row * N + n0 + nt * 16 + m16;
                        short hh, ll; splitf(v, hh, ll);
                        oH[o] = hh; oL[o] = ll;
                        sA[nt] += v; qA[nt] += v * v;
                    }
                }
            }
        #pragma unroll
        for (int nt = 0; nt < 8; ++nt) {
            sA[nt] += __shfl_xor(sA[nt], 16); sA[nt] += __shfl_xor(sA[nt], 32);
            qA[nt] += __shfl_xor(qA[nt], 16); qA[nt] += __shfl_xor(qA[nt], 32);
        }
        __shared__ float redS[4][128], redQ[4][128];
        if (q == 0) {
            #pragma unroll
            for (int nt = 0; nt < 8; ++nt) {
                redS[wv][nt * 16 + m16] = sA[nt];
                redQ[wv][nt * 16 + m16] = qA[nt];
            }
        }
        __syncthreads();
        if (tid < 128) {
            float s = 0.f, qq = 0.f;
            #pragma unroll
            for (int w = 0; w < 4; ++w) { s += redS[w][tid]; qq += redQ[w][tid]; }
            atomicAdd(&stats[n0 + tid], s);
            atomicAdd(&stats[N + n0 + tid], qq);
        }
    } else {
        #pragma unroll
        for (int mt = 0; mt < 2; ++mt)
            #pragma unroll
            for (int r = 0; r < 4; ++r) {
                int row = bm + mt * 16 + q * 4 + r;
                if (row >= M) continue;
                #pragma unroll
                for (int nt = 0; nt < 8; ++nt)
                    outF[(size_t)row * N + n0 + nt * 16 + m16] = acc[mt][nt][r] + bv[nt];
            }
    }
}

// ---------------- BatchNorm ----------------
__global__ void bn_finalize(float* __restrict__ stats, const void* __restrict__ g,
                            const void* __restrict__ b, const int* __restrict__ modes,
                            int gidx, int bidx, int C, float invM) {
    int c = threadIdx.x;
    if (c < C) {
        float mean = stats[c] * invM;
        float var  = fmaxf(stats[C + c] * invM - mean * mean, 0.f);
        float sc   = loadf(g, modes[gidx], c) * rsqrtf(var + 1e-5f);
        stats[2 * C + c] = sc;
        stats[3 * C + c] = loadf(b, modes[bidx], c) - mean * sc;
    }
}

// in-place BN+ReLU on split pair (elementwise -> race-free)
__global__ void bn_pair_inplace(short* __restrict__ H, short* __restrict__ L,
                                const float* __restrict__ stats, size_t total4, int cmask, int C) {
    size_t i = (size_t)blockIdx.x * blockDim.x + threadIdx.x;
    if (i >= total4) return;
    size_t e = i * 4;
    int c = (int)(e & (size_t)cmask);
    short4 h = *(short4*)(H + e);
    short4 l = *(short4*)(L + e);
    const float* sc = stats + 2 * C;
    const float* sh = stats + 3 * C;
    float v0 = fmaxf((bf2f(h.x) + bf2f(l.x)) * sc[c + 0] + sh[c + 0], 0.f);
    float v1 = fmaxf((bf2f(h.y) + bf2f(l.y)) * sc[c + 1] + sh[c + 1], 0.f);
    float v2 = fmaxf((bf2f(h.z) + bf2f(l.z)) * sc[c + 2] + sh[c + 2], 0.f);
    float v3 = fmaxf((bf2f(h.w) + bf2f(l.w)) * sc[c + 3] + sh[c + 3], 0.f);
    splitf(v0, h.x, l.x); splitf(v1, h.y, l.y);
    splitf(v2, h.z, l.z); splitf(v3, h.w, l.w);
    *(short4*)(H + e) = h;
    *(short4*)(L + e) = l;
}

__global__ void bn_stats_f32(const float* __restrict__ X, float* __restrict__ stats,
                             int M, int C, int rows) {
    int c = threadIdx.x;          // blockDim == C
    int r0 = blockIdx.x * rows;
    int r1 = min(r0 + rows, M);
    float s = 0.f, s2 = 0.f;
    for (int r = r0; r < r1; ++r) {
        float v = X[(size_t)r * C + c];
        s += v; s2 += v * v;
    }
    atomicAdd(&stats[c], s);
    atomicAdd(&stats[C + c], s2);
}

__global__ void bn_f32_to_pair(const float* __restrict__ X, const float* __restrict__ stats,
                               short* __restrict__ H, short* __restrict__ L,
                               size_t total, int cmask, int C) {
    size_t i = (size_t)blockIdx.x * blockDim.x + threadIdx.x;
    if (i >= total) return;
    int c = (int)(i & (size_t)cmask);
    float v = fmaxf(X[i] * stats[2 * C + c] + stats[3 * C + c], 0.f);
    short hh, ll; splitf(v, hh, ll);
    H[i] = hh; L[i] = ll;
}

// ---------------- GCN degree ----------------
__global__ void deg_scatter(const void* __restrict__ ew, const int* __restrict__ modes, int eidx,
                            const int* __restrict__ col, float* __restrict__ deg, int nE) {
    int e = blockIdx.x * blockDim.x + threadIdx.x;
    if (e < nE) atomicAdd(&deg[col[e]], loadf(ew, modes[eidx], e));
}

__global__ void dinv_fin(float* __restrict__ deg, int n) {
    int i = blockIdx.x * blockDim.x + threadIdx.x;
    if (i < n) {
        float d = deg[i] + 1.0f;
        deg[i] = d > 0.f ? rsqrtf(d) : 0.f;
    }
}

// ---------------- pooling ----------------
__global__ void pool_sorted(const float* __restrict__ xn, const int* __restrict__ batch,
                            float* __restrict__ xg, int nN) {
    int g = blockIdx.x;
    int lo = 0, hi = nN;
    while (lo < hi) { int mid = (lo + hi) >> 1; if (batch[mid] < g) lo = mid + 1; else hi = mid; }
    int lo2 = lo, hi2 = nN;
    while (lo2 < hi2) { int mid = (lo2 + hi2) >> 1; if (batch[mid] < g + 1) lo2 = mid + 1; else hi2 = mid; }
    int d = threadIdx.x;          // 128
    float s = 0.f;
    for (int r = lo; r < lo2; ++r) s += xn[(size_t)r * 128 + d];
    xg[(size_t)g * 128 + d] = s / fmaxf((float)(lo2 - lo), 1.0f);
}

__global__ void svc_pool1(const float* __restrict__ xsl, float* __restrict__ partial) {
    int o = blockIdx.x;           // 50
    int c = blockIdx.y;           // 8
    int d = threadIdx.x;          // 128
    float s = 0.f;
    int r0 = c * 128;
    for (int r = r0; r < r0 + 128; ++r)
        s += xsl[((size_t)(r * 50 + o)) * 128 + d];
    partial[((size_t)(o * 8 + c)) * 128 + d] = s;
}

__global__ void svc_pool2(const float* __restrict__ partial, float* __restrict__ xsg) {
    int o = blockIdx.x;           // 50
    int d = threadIdx.x;          // 128
    float s = 0.f;
    #pragma unroll
    for (int c = 0; c < 8; ++c)
        s += partial[((size_t)(o * 8 + c)) * 128 + d];
    xsg[o * 128 + d] = s * (1.0f / 1024.0f);
}

// ---------------- final ----------------
__global__ void final_out(const float* __restrict__ xg, const float* __restrict__ xsg,
                          const int* __restrict__ modes, void* __restrict__ out) {
    __shared__ float xrow[128];
    int g = blockIdx.x;
    for (int d = threadIdx.x; d < 128; d += 64) xrow[d] = xg[(size_t)g * 128 + d];
    __syncthreads();
    int o = threadIdx.x;
    if (o < 50) {
        const float* xs = xsg + o * 128;
        float s = 0.f;
        #pragma unroll 4
        for (int d = 0; d < 128; ++d) s += xrow[d] * xs[d];
        float sg = 1.0f / (1.0f + __expf(-s));
        if (modes[0] == 1) ((bf16*)out)[(size_t)g * 50 + o] = __float2bfloat16(sg);
        else               ((float*)out)[(size_t)g * 50 + o] = sg;
    }
}

extern "C" void kernel_launch(void* const* d_in, const int* in_sizes, int n_in,
                              void* d_out, int out_size, void* d_ws, size_t ws_size,
                              hipStream_t stream) {
    const int nN = 100000, nE = 800000, nS = 51200, nES = 409600;
    const int Bg = 1024;

    const int* node_ids = (const int*)d_in[0];
    const int* ei       = (const int*)d_in[2];
    const int* svc_ids  = (const int*)d_in[3];
    const int* eis      = (const int*)d_in[5];
    const int* batch    = (const int*)d_in[7];

    // ---------------- workspace layout (float words, 16B-aligned blocks) ----------------
    float* ws    = (float*)d_ws;
    int*   modes = (int*)ws;                        // 64
    float* stats = ws + 64;                         // 1024
    float* dinv  = ws + 1088;                       // 51200
    float* xsg   = ws + 52288;                      // 6400
    int*   rp_n  = (int*)(ws + 58688);              // 100001
    int*   adj_n = (int*)(ws + 158692);             // 800000
    int*   rp_s  = (int*)(ws + 958692);             // 51201
    int*   adj_s = (int*)(ws + 1009896);            // 409600
    short* adw_s = (short*)(ws + 1419496);          // 409600 shorts
    short* wtb   = (short*)(ws + 1624296);          // 262144 shorts
    float* xg    = ws + 1755368;                    // 131072 (also cur_n early)
    float* part  = ws + 1886440;                    // 51200  (also cur_s early)
    float* A25   = ws + 1937640;                    // 25,600,000
    float* B13   = ws + 27537640;                   // 13,107,200
    float* C13   = ws + 40644840;                   // 13,107,200
    size_t need  = (size_t)53752040 * 4;
    if (ws_size < need) return;
    int* cur_n = (int*)xg;
    int* cur_s = (int*)part;

    short* A25H = (short*)A25;  short* A25L = (short*)(A25 + 12800000);
    short* B13H = (short*)B13;  short* B13L = (short*)(B13 + 6553600);
    short* C13H = (short*)C13;  short* C13L = (short*)(C13 + 6553600);
    float* B13F = B13;  float* A25F = A25;

    // wt sub-buffers (shorts)
    short* wt0 = wtb;               // g0_W1  256 x 96
    short* wt1 = wt0 + 24576;       // g0_W2  128 x 256
    short* wt2 = wt1 + 32768;       // g1_W1  256 x 128
    short* wt3 = wt2 + 32768;       // g1_W2  128 x 256
    short* wt4 = wt3 + 32768;       // nl_W   128 x 128
    short* wt5 = wt4 + 16384;       // c0_W   256 x 96
    short* wt6 = wt5 + 24576;       // c1_W   256 x 256
    short* wt7 = wt6 + 65536;       // sl_W   128 x 256

    // ---------------- detect dtypes (once, 35 blocks) ----------------
    static const int conv_idx[NCONV] = {1, 4, 6, 10, 11,
        12, 13, 14, 15, 16, 17, 18, 19, 20,
        21, 22, 23, 24, 25, 26, 27, 28, 29,
        30, 31, 32, 33, 34, 35, 36, 37, 38, 39, 40, 41};
    DetArgs da;
    for (int b = 0; b < NCONV; ++b) { da.src[b] = d_in[conv_idx[b]]; da.n[b] = in_sizes[conv_idx[b]]; }
    detect_all<<<NCONV, 256, 0, stream>>>(da, modes);

    // ---------------- weight transposes (bf16) ----------------
    wt_build<<<256, 256, 0, stream>>>(d_in[12], modes, 5, 70, 256, wt0, 96);
    wt_build<<<128, 256, 0, stream>>>(d_in[16], modes, 9, 256, 128, wt1, 256);
    wt_build<<<256, 256, 0, stream>>>(d_in[21], modes, 14, 128, 256, wt2, 128);
    wt_build<<<128, 256, 0, stream>>>(d_in[25], modes, 18, 256, 128, wt3, 256);
    wt_build<<<128, 256, 0, stream>>>(d_in[30], modes, 23, 128, 128, wt4, 128);
    wt_build<<<256, 256, 0, stream>>>(d_in[32], modes, 25, 68, 256, wt5, 96);
    wt_build<<<256, 256, 0, stream>>>(d_in[36], modes, 29, 256, 256, wt6, 256);
    wt_build<<<128, 256, 0, stream>>>(d_in[40], modes, 33, 256, 128, wt7, 256);

    // ---------------- CSR builds (cursors alias xg/part: disjoint lifetimes) ----------------
    hipMemsetAsync(cur_n, 0, nN * sizeof(int), stream);
    csr_count<<<(nE + 255) / 256, 256, 0, stream>>>(ei + nE, nE, cur_n);
    scan_excl<<<1, 1024, 0, stream>>>(cur_n, rp_n, nN);
    copy_int<<<(nN + 255) / 256, 256, 0, stream>>>(rp_n, cur_n, nN);
    csr_fill<<<(nE + 255) / 256, 256, 0, stream>>>(ei, ei + nE, nullptr, modes, 2, nE,
                                                   cur_n, adj_n, nullptr);
    hipMemsetAsync(cur_s, 0, nS * sizeof(int), stream);
    csr_count<<<(nES + 255) / 256, 256, 0, stream>>>(eis + nES, nES, cur_s);
    scan_excl<<<1, 1024, 0, stream>>>(cur_s, rp_s, nS);
    copy_int<<<(nS + 255) / 256, 256, 0, stream>>>(rp_s, cur_s, nS);
    csr_fill<<<(nES + 255) / 256, 256, 0, stream>>>(eis, eis + nES, d_in[6], modes, 2, nES,
                                                    cur_s, adj_s, adw_s);
    hipMemsetAsync(dinv, 0, nS * sizeof(float), stream);
    deg_scatter<<<(nES + 255) / 256, 256, 0, stream>>>(d_in[6], modes, 2, eis + nES, dinv, nES);
    dinv_fin<<<(nS + 255) / 256, 256, 0, stream>>>(dinv, nS);

    auto gemm = [&](const short* Ah, const short* Al, int ldk, const short* Wt,
                    const void* bias, int bidx, float* outF, short* oH, short* oL,
                    int M, int N, int pair) {
        if (pair) hipMemsetAsync(stats, 0, 2 * N * sizeof(float), stream);
        dim3 grid(N / 128, (M + 127) / 128);
        gemm_mfma<<<grid, 256, 0, stream>>>(Ah, Al, ldk, Wt, bias, modes, bidx,
                                            outF, oH, oL, stats, M, N, ldk / 32, pair);
    };
    auto bnfin = [&](int gidx, int bidx, const void* g, const void* b, int C, int M) {
        bn_finalize<<<1, C, 0, stream>>>(stats, g, b, modes, gidx, bidx, C, 1.0f / M);
    };
    auto bninp = [&](short* H, short* L, int M, int C) {
        size_t t4 = (size_t)M * C / 4;
        bn_pair_inplace<<<(t4 + 255) / 256, 256, 0, stream>>>(H, L, stats, t4, C - 1, C);
    };

    // ---------------- node branch ----------------
    build_feat_pair<<<nN, 128, 0, stream>>>(d_in[10], node_ids, d_in[1], modes, 3, 0,
                                            C13H, C13L, 6, 96);
    gin_gather_pair<<<nN, 128, 0, stream>>>(C13H, C13L, rp_n, adj_n, d_in[18], modes, 11,
                                            B13H, B13L, 96);
    gemm(B13H, B13L, 96, wt0, d_in[13], 6, nullptr, A25H, A25L, nN, 256, 1);
    bnfin(7, 8, d_in[14], d_in[15], 256, nN);
    bninp(A25H, A25L, nN, 256);
    gemm(A25H, A25L, 256, wt1, d_in[17], 10, nullptr, C13H, C13L, nN, 128, 1);
    bnfin(12, 13, d_in[19], d_in[20], 128, nN);
    bninp(C13H, C13L, nN, 128);

    gin_gather_pair<<<nN, 128, 0, stream>>>(C13H, C13L, rp_n, adj_n, d_in[27], modes, 20,
                                            B13H, B13L, 128);
    gemm(B13H, B13L, 128, wt2, d_in[22], 15, nullptr, A25H, A25L, nN, 256, 1);
    bnfin(16, 17, d_in[23], d_in[24], 256, nN);
    bninp(A25H, A25L, nN, 256);
    gemm(A25H, A25L, 256, wt3, d_in[26], 19, nullptr, C13H, C13L, nN, 128, 1);
    bnfin(21, 22, d_in[28], d_in[29], 128, nN);
    bninp(C13H, C13L, nN, 128);

    gemm(C13H, C13L, 128, wt4, d_in[31], 24, B13F, nullptr, nullptr, nN, 128, 0);
    pool_sorted<<<Bg, 128, 0, stream>>>(B13F, batch, xg, nN);

    // ---------------- service branch ----------------
    build_feat_pair<<<nS, 128, 0, stream>>>(d_in[11], svc_ids, d_in[4], modes, 4, 1,
                                            C13H, C13L, 4, 96);
    gemm(C13H, C13L, 96, wt5, nullptr, 0, B13F, nullptr, nullptr, nS, 256, 0);
    gcn_gather<<<nS, 256, 0, stream>>>(B13F, rp_s, adj_s, adw_s, dinv, d_in[33], modes, 26, A25F);
    hipMemsetAsync(stats, 0, 2 * 256 * sizeof(float), stream);
    bn_stats_f32<<<(nS + 511) / 512, 256, 0, stream>>>(A25F, stats, nS, 256, 512);
    bnfin(27, 28, d_in[34], d_in[35], 256, nS);
    { size_t t = (size_t)nS * 256;
      bn_f32_to_pair<<<(t + 255) / 256, 256, 0, stream>>>(A25F, stats, C13H, C13L, t, 255, 256); }

    gemm(C13H, C13L, 256, wt6, nullptr, 0, B13F, nullptr, nullptr, nS, 256, 0);
    gcn_gather<<<nS, 256, 0, stream>>>(B13F, rp_s, adj_s, adw_s, dinv, d_in[37], modes, 30, A25F);
    hipMemsetAsync(stats, 0, 2 * 256 * sizeof(float), stream);
    bn_stats_f32<<<(nS + 511) / 512, 256, 0, stream>>>(A25F, stats, nS, 256, 512);
    bnfin(31, 32, d_in[38], d_in[39], 256, nS);
    { size_t t = (size_t)nS * 256;
      bn_f32_to_pair<<<(t + 255) / 256, 256, 0, stream>>>(A25F, stats, C13H, C13L, t, 255, 256); }

    gemm(C13H, C13L, 256, wt7, d_in[41], 34, B13F, nullptr, nullptr, nS, 128, 0);
    svc_pool1<<<dim3(50, 8), 128, 0, stream>>>(B13F, part);
    svc_pool2<<<50, 128, 0, stream>>>(part, xsg);

    // ---------------- output ----------------
    final_out<<<Bg, 64, 0, stream>>>(xg, xsg, modes, d_out);
}

// Round 5
// 1761.818 us; speedup vs baseline: 2.1605x; 1.1366x over previous
//
#include <hip/hip_runtime.h>
#include <hip/hip_bf16.h>
#include <cstddef>
#include <cstdint>

typedef __hip_bfloat16 bf16;
typedef __attribute__((ext_vector_type(8))) short short8;   // 8 bf16 (4 VGPRs)
typedef __attribute__((ext_vector_type(4))) float floatx4;  // MFMA acc

static __device__ __forceinline__ float b2f(bf16 v) { return __bfloat162float(v); }

static __device__ __forceinline__ short f2bf(float f) {
    unsigned u = __float_as_uint(f);
    unsigned r = u + 0x7FFF + ((u >> 16) & 1);
    return (short)(r >> 16);
}
static __device__ __forceinline__ float bf2f(short h) {
    return __uint_as_float(((unsigned)(unsigned short)h) << 16);
}
static __device__ __forceinline__ void splitf(float f, short& hi, short& lo) {
    hi = f2bf(f);
    lo = f2bf(f - bf2f(hi));
}
// mode: 0=zero, 1=bf16-stored, 2=fp32-stored
static __device__ __forceinline__ float loadf(const void* p, int mode, size_t i) {
    if (mode == 1) return b2f(((const bf16*)p)[i]);
    if (mode == 2) return ((const float*)p)[i];
    return 0.f;
}

#define NCONV 35
struct DetArgs { const void* src[NCONV]; int n[NCONV]; };

// ---------------- dtype detection (one block per buffer) ----------------
__global__ void detect_all(DetArgs a, int* __restrict__ modes) {
    int b = blockIdx.x;
    int n = a.n[b];
    const unsigned short* w = (const unsigned short*)a.src[b];
    __shared__ int cz, cbad, cevz, codz;
    if (threadIdx.x == 0) { cz = 0; cbad = 0; cevz = 0; codz = 0; }
    __syncthreads();
    int K = n < 2048 ? n : 2048;
    int z = 0, bad = 0, evz = 0, odz = 0;
    for (int i = threadIdx.x; i < K; i += blockDim.x) {
        unsigned short v = w[i];
        int e = (v >> 7) & 0xFF;
        bool isz = (v & 0x7FFF) == 0;
        if (isz) { z++; if (i & 1) odz++; else evz++; }
        else if (e < 91 || e > 140) bad++;
    }
    atomicAdd(&cz, z); atomicAdd(&cbad, bad);
    atomicAdd(&cevz, evz); atomicAdd(&codz, odz);
    __syncthreads();
    if (threadIdx.x == 0) {
        int mode;
        if (cz >= K) mode = 0;
        else if (cbad * 16 > K) mode = 2;
        else if (cevz * 4 > K && codz * 16 < K) mode = 2;
        else mode = 1;
        modes[b] = mode;
    }
}

// ---------------- batched weight transpose -> bf16 Wt[n][Kpad] ----------------
struct WtArgs {
    const void* W[8]; short* wt[8];
    int midx[8]; int KW[8]; int ldw[8]; int Kpad[8]; int N[8];
};
__global__ void wt_build_all(WtArgs a, const int* __restrict__ modes) {
    int e = blockIdx.y;
    int n = blockIdx.x; if (n >= a.N[e]) return;
    int k = threadIdx.x; if (k >= a.Kpad[e]) return;
    float v = (k < a.KW[e]) ? loadf(a.W[e], modes[a.midx[e]], (size_t)k * a.ldw[e] + n) : 0.f;
    a.wt[e][(size_t)n * a.Kpad[e] + k] = f2bf(v);
}

// ---------------- feature build -> pair planes ----------------
__global__ void build_feat_pair(const void* __restrict__ emb, const int* __restrict__ ids,
                                const void* __restrict__ feats, const int* __restrict__ modes,
                                int eidx, int fidx, short* __restrict__ H, short* __restrict__ L,
                                int nf, int Ws) {
    int i = blockIdx.x;
    int d = threadIdx.x;          // 128
    if (d >= Ws) return;
    float v;
    if (d < 64)           v = loadf(emb, modes[eidx], (size_t)ids[i] * 64 + d);
    else if (d < 64 + nf) v = loadf(feats, modes[fidx], (size_t)i * nf + (d - 64));
    else                  v = 0.f;
    short hh, ll; splitf(v, hh, ll);
    size_t o = (size_t)i * Ws + d;
    H[o] = hh; L[o] = ll;
}

// ---------------- CSR build ----------------
__global__ void csr_count(const int* __restrict__ dst, int nE, int* __restrict__ cnt) {
    int e = blockIdx.x * blockDim.x + threadIdx.x;
    if (e < nE) atomicAdd(&cnt[dst[e]], 1);
}

// hierarchical scan: part sums -> mid scan -> final scan (+cursor copy)
__global__ __launch_bounds__(256) void scan_part(const int* __restrict__ cnt, int n,
                                                 int* __restrict__ bsum) {
    __shared__ int red[256];
    int blk = blockIdx.x, t = threadIdx.x;
    int base = blk * 1024 + t * 4;
    int s = 0;
    #pragma unroll
    for (int k = 0; k < 4; ++k) { int i = base + k; if (i < n) s += cnt[i]; }
    red[t] = s;
    __syncthreads();
    for (int off = 128; off > 0; off >>= 1) {
        if (t < off) red[t] += red[t + off];
        __syncthreads();
    }
    if (t == 0) bsum[blk] = red[0];
}

__global__ __launch_bounds__(128) void scan_mid(int* __restrict__ bsum, int nb,
                                                int* __restrict__ rowptr, int n) {
    __shared__ int sh[128];
    int t = threadIdx.x;
    int v = (t < nb) ? bsum[t] : 0;
    sh[t] = v;
    __syncthreads();
    for (int off = 1; off < 128; off <<= 1) {
        int u = (t >= off) ? sh[t - off] : 0;
        __syncthreads();
        sh[t] += u;
        __syncthreads();
    }
    if (t < nb) bsum[t] = sh[t] - v;        // exclusive
    if (t == 127) rowptr[n] = sh[127];      // total
}

__global__ __launch_bounds__(256) void scan_fin(const int* __restrict__ cnt, int n,
                                                const int* __restrict__ bsum,
                                                int* __restrict__ rowptr, int* __restrict__ cursor) {
    __shared__ int sh[256];
    int blk = blockIdx.x, t = threadIdx.x;
    int base = blk * 1024 + t * 4;
    int v[4], s = 0;
    #pragma unroll
    for (int k = 0; k < 4; ++k) { int i = base + k; v[k] = (i < n) ? cnt[i] : 0; s += v[k]; }
    sh[t] = s;
    __syncthreads();
    for (int off = 1; off < 256; off <<= 1) {
        int u = (t >= off) ? sh[t - off] : 0;
        __syncthreads();
        sh[t] += u;
        __syncthreads();
    }
    int run = sh[t] - s + bsum[blk];
    #pragma unroll
    for (int k = 0; k < 4; ++k) {
        int i = base + k;
        if (i < n) { rowptr[i] = run; cursor[i] = run; run += v[k]; }
    }
}

// fill; for weighted graphs stores bf16(dinv[src]*w) (dinv computed beforehand)
__global__ void csr_fill(const int* __restrict__ src, const int* __restrict__ dst,
                         const void* __restrict__ w, const int* __restrict__ modes, int widx,
                         const float* __restrict__ dinv, int nE, int* __restrict__ cursor,
                         int* __restrict__ adj, short* __restrict__ adjw) {
    int e = blockIdx.x * blockDim.x + threadIdx.x;
    if (e < nE) {
        int s = src[e];
        int pos = atomicAdd(&cursor[dst[e]], 1);
        adj[pos] = s;
        if (adjw) adjw[pos] = f2bf(dinv[s] * loadf(w, modes[widx], e));
    }
}

// ---------------- GIN gather on pairs (fused (1+eps)x) ----------------
__global__ void gin_gather_pair(const short* __restrict__ H, const short* __restrict__ L,
                                const int* __restrict__ rowptr, const int* __restrict__ adj,
                                const void* __restrict__ eps, const int* __restrict__ modes,
                                int eidx, short* __restrict__ Ho, short* __restrict__ Lo, int Ws) {
    int i = blockIdx.x;
    int d = threadIdx.x;          // 128
    if (d >= Ws) return;
    float epsv = 1.0f + loadf(eps, modes[eidx], 0);
    int lo = rowptr[i], hi = rowptr[i + 1];
    float acc = 0.f;
    for (int p = lo; p < hi; ++p) {
        size_t o = (size_t)adj[p] * Ws + d;
        acc += bf2f(H[o]) + bf2f(L[o]);
    }
    size_t o = (size_t)i * Ws + d;
    acc += epsv * (bf2f(H[o]) + bf2f(L[o]));
    short hh, ll; splitf(acc, hh, ll);
    Ho[o] = hh; Lo[o] = ll;
}

// ---------------- GCN gather (fused self-loop + bias), C=256, fp32 in/out ----------------
// adjw already folded with dinv[src]
__global__ void gcn_gather(const float* __restrict__ xw, const int* __restrict__ rowptr,
                           const int* __restrict__ adj, const short* __restrict__ adjw,
                           const float* __restrict__ dinv, const void* __restrict__ bias,
                           const int* __restrict__ modes, int bidx, float* __restrict__ out) {
    int i = blockIdx.x;
    int d = threadIdx.x;          // 256
    float di = dinv[i];
    float acc = xw[(size_t)i * 256 + d] * di * di + loadf(bias, modes[bidx], d);
    int lo = rowptr[i], hi = rowptr[i + 1];
    for (int p = lo; p < hi; ++p) {
        int s = adj[p];
        acc += di * bf2f(adjw[p]) * xw[(size_t)s * 256 + d];
    }
    out[(size_t)i * 256 + d] = acc;
}

// ---------------- MFMA GEMM: out[M,N] = A(hi+lo)[M,ldk] @ Wt^T ----------------
__global__ __launch_bounds__(256) void gemm_mfma(
        const short* __restrict__ Ah, const short* __restrict__ Al, int ldk,
        const short* __restrict__ Wt,
        const void* __restrict__ bias, const int* __restrict__ modes, int bias_midx,
        float* __restrict__ outF, short* __restrict__ oH, short* __restrict__ oL,
        float* __restrict__ stats, int M, int N, int ksteps, int pair_out) {
    int tid  = threadIdx.x;
    int wv   = tid >> 6, lane = tid & 63;
    int m16  = lane & 15, q = lane >> 4;
    int bm   = blockIdx.y * 128 + wv * 32;
    int n0   = blockIdx.x * 128;
    int r0 = min(bm + m16, M - 1);
    int r1 = min(bm + 16 + m16, M - 1);
    const short8* pa0h = (const short8*)(Ah + (size_t)r0 * ldk + q * 8);
    const short8* pa0l = (const short8*)(Al + (size_t)r0 * ldk + q * 8);
    const short8* pa1h = (const short8*)(Ah + (size_t)r1 * ldk + q * 8);
    const short8* pa1l = (const short8*)(Al + (size_t)r1 * ldk + q * 8);
    const short8* pb[8];
    #pragma unroll
    for (int nt = 0; nt < 8; ++nt)
        pb[nt] = (const short8*)(Wt + (size_t)(n0 + nt * 16 + m16) * ldk + q * 8);

    floatx4 acc[2][8];
    #pragma unroll
    for (int mt = 0; mt < 2; ++mt)
        #pragma unroll
        for (int nt = 0; nt < 8; ++nt)
            acc[mt][nt] = (floatx4){0.f, 0.f, 0.f, 0.f};

    for (int ks = 0; ks < ksteps; ++ks) {
        int idx = ks * 4;                 // short8 units (32 shorts / k-step)
        short8 a0h = pa0h[idx], a0l = pa0l[idx];
        short8 a1h = pa1h[idx], a1l = pa1l[idx];
        #pragma unroll
        for (int nt = 0; nt < 8; ++nt) {
            short8 b = pb[nt][idx];
            acc[0][nt] = __builtin_amdgcn_mfma_f32_16x16x32_bf16(a0h, b, acc[0][nt], 0, 0, 0);
            acc[0][nt] = __builtin_amdgcn_mfma_f32_16x16x32_bf16(a0l, b, acc[0][nt], 0, 0, 0);
            acc[1][nt] = __builtin_amdgcn_mfma_f32_16x16x32_bf16(a1h, b, acc[1][nt], 0, 0, 0);
            acc[1][nt] = __builtin_amdgcn_mfma_f32_16x16x32_bf16(a1l, b, acc[1][nt], 0, 0, 0);
        }
    }

    float bv[8];
    int bmode = bias ? modes[bias_midx] : 0;
    #pragma unroll
    for (int nt = 0; nt < 8; ++nt)
        bv[nt] = bias ? loadf(bias, bmode, n0 + nt * 16 + m16) : 0.f;

    if (pair_out) {
        float sA[8], qA[8];
        #pragma unroll
        for (int nt = 0; nt < 8; ++nt) { sA[nt] = 0.f; qA[nt] = 0.f; }
        #pragma unroll
        for (int mt = 0; mt < 2; ++mt)
            #pragma unroll
            for (int r = 0; r < 4; ++r) {
                int row = bm + mt * 16 + q * 4 + r;
                bool ok = row < M;
                #pragma unroll
                for (int nt = 0; nt < 8; ++nt) {
                    float v = acc[mt][nt][r] + bv[nt];
                    if (ok) {
                        size_t o = (size_t)row * N + n0 + nt * 16 + m16;
                        short hh, ll; splitf(v, hh, ll);
                        oH[o] = hh; oL[o] = ll;
                        sA[nt] += v; qA[nt] += v * v;
                    }
                }
            }
        #pragma unroll
        for (int nt = 0; nt < 8; ++nt) {
            sA[nt] += __shfl_xor(sA[nt], 16); sA[nt] += __shfl_xor(sA[nt], 32);
            qA[nt] += __shfl_xor(qA[nt], 16); qA[nt] += __shfl_xor(qA[nt], 32);
        }
        __shared__ float redS[4][128], redQ[4][128];
        if (q == 0) {
            #pragma unroll
            for (int nt = 0; nt < 8; ++nt) {
                redS[wv][nt * 16 + m16] = sA[nt];
                redQ[wv][nt * 16 + m16] = qA[nt];
            }
        }
        __syncthreads();
        if (tid < 128) {
            float s = 0.f, qq = 0.f;
            #pragma unroll
            for (int w = 0; w < 4; ++w) { s += redS[w][tid]; qq += redQ[w][tid]; }
            atomicAdd(&stats[n0 + tid], s);
            atomicAdd(&stats[N + n0 + tid], qq);
        }
    } else {
        #pragma unroll
        for (int mt = 0; mt < 2; ++mt)
            #pragma unroll
            for (int r = 0; r < 4; ++r) {
                int row = bm + mt * 16 + q * 4 + r;
                if (row >= M) continue;
                #pragma unroll
                for (int nt = 0; nt < 8; ++nt)
                    outF[(size_t)row * N + n0 + nt * 16 + m16] = acc[mt][nt][r] + bv[nt];
            }
    }
}

// ---------------- BatchNorm ----------------
__global__ void bn_finalize(float* __restrict__ stats, const void* __restrict__ g,
                            const void* __restrict__ b, const int* __restrict__ modes,
                            int gidx, int bidx, int C, float invM) {
    int c = threadIdx.x;
    if (c < C) {
        float mean = stats[c] * invM;
        float var  = fmaxf(stats[C + c] * invM - mean * mean, 0.f);
        float sc   = loadf(g, modes[gidx], c) * rsqrtf(var + 1e-5f);
        stats[2 * C + c] = sc;
        stats[3 * C + c] = loadf(b, modes[bidx], c) - mean * sc;
    }
}

__global__ void bn_pair_inplace(short* __restrict__ H, short* __restrict__ L,
                                const float* __restrict__ stats, size_t total4, int cmask, int C) {
    size_t i = (size_t)blockIdx.x * blockDim.x + threadIdx.x;
    if (i >= total4) return;
    size_t e = i * 4;
    int c = (int)(e & (size_t)cmask);
    short4 h = *(short4*)(H + e);
    short4 l = *(short4*)(L + e);
    const float* sc = stats + 2 * C;
    const float* sh = stats + 3 * C;
    float v0 = fmaxf((bf2f(h.x) + bf2f(l.x)) * sc[c + 0] + sh[c + 0], 0.f);
    float v1 = fmaxf((bf2f(h.y) + bf2f(l.y)) * sc[c + 1] + sh[c + 1], 0.f);
    float v2 = fmaxf((bf2f(h.z) + bf2f(l.z)) * sc[c + 2] + sh[c + 2], 0.f);
    float v3 = fmaxf((bf2f(h.w) + bf2f(l.w)) * sc[c + 3] + sh[c + 3], 0.f);
    splitf(v0, h.x, l.x); splitf(v1, h.y, l.y);
    splitf(v2, h.z, l.z); splitf(v3, h.w, l.w);
    *(short4*)(H + e) = h;
    *(short4*)(L + e) = l;
}

__global__ void bn_stats_f32(const float* __restrict__ X, float* __restrict__ stats,
                             int M, int C, int rows) {
    int c = threadIdx.x;          // blockDim == C
    int r0 = blockIdx.x * rows;
    int r1 = min(r0 + rows, M);
    float s = 0.f, s2 = 0.f;
    for (int r = r0; r < r1; ++r) {
        float v = X[(size_t)r * C + c];
        s += v; s2 += v * v;
    }
    atomicAdd(&stats[c], s);
    atomicAdd(&stats[C + c], s2);
}

__global__ void bn_f32_to_pair(const float* __restrict__ X, const float* __restrict__ stats,
                               short* __restrict__ H, short* __restrict__ L,
                               size_t total, int cmask, int C) {
    size_t i = (size_t)blockIdx.x * blockDim.x + threadIdx.x;
    if (i >= total) return;
    int c = (int)(i & (size_t)cmask);
    float v = fmaxf(X[i] * stats[2 * C + c] + stats[3 * C + c], 0.f);
    short hh, ll; splitf(v, hh, ll);
    H[i] = hh; L[i] = ll;
}

// ---------------- GCN degree ----------------
__global__ void deg_scatter(const void* __restrict__ ew, const int* __restrict__ modes, int eidx,
                            const int* __restrict__ col, float* __restrict__ deg, int nE) {
    int e = blockIdx.x * blockDim.x + threadIdx.x;
    if (e < nE) atomicAdd(&deg[col[e]], loadf(ew, modes[eidx], e));
}

__global__ void dinv_fin(float* __restrict__ deg, int n) {
    int i = blockIdx.x * blockDim.x + threadIdx.x;
    if (i < n) {
        float d = deg[i] + 1.0f;
        deg[i] = d > 0.f ? rsqrtf(d) : 0.f;
    }
}

// ---------------- pooling ----------------
__global__ void pool_sorted(const float* __restrict__ xn, const int* __restrict__ batch,
                            float* __restrict__ xg, int nN) {
    int g = blockIdx.x;
    int lo = 0, hi = nN;
    while (lo < hi) { int mid = (lo + hi) >> 1; if (batch[mid] < g) lo = mid + 1; else hi = mid; }
    int lo2 = lo, hi2 = nN;
    while (lo2 < hi2) { int mid = (lo2 + hi2) >> 1; if (batch[mid] < g + 1) lo2 = mid + 1; else hi2 = mid; }
    int d = threadIdx.x;          // 128
    float s = 0.f;
    for (int r = lo; r < lo2; ++r) s += xn[(size_t)r * 128 + d];
    xg[(size_t)g * 128 + d] = s / fmaxf((float)(lo2 - lo), 1.0f);
}

__global__ void svc_pool1(const float* __restrict__ xsl, float* __restrict__ partial) {
    int o = blockIdx.x;           // 50
    int c = blockIdx.y;           // 8
    int d = threadIdx.x;          // 128
    float s = 0.f;
    int r0 = c * 128;
    for (int r = r0; r < r0 + 128; ++r)
        s += xsl[((size_t)(r * 50 + o)) * 128 + d];
    partial[((size_t)(o * 8 + c)) * 128 + d] = s;
}

__global__ void svc_pool2(const float* __restrict__ partial, float* __restrict__ xsg) {
    int o = blockIdx.x;           // 50
    int d = threadIdx.x;          // 128
    float s = 0.f;
    #pragma unroll
    for (int c = 0; c < 8; ++c)
        s += partial[((size_t)(o * 8 + c)) * 128 + d];
    xsg[o * 128 + d] = s * (1.0f / 1024.0f);
}

// ---------------- final ----------------
__global__ void final_out(const float* __restrict__ xg, const float* __restrict__ xsg,
                          const int* __restrict__ modes, void* __restrict__ out) {
    __shared__ float xrow[128];
    int g = blockIdx.x;
    for (int d = threadIdx.x; d < 128; d += 64) xrow[d] = xg[(size_t)g * 128 + d];
    __syncthreads();
    int o = threadIdx.x;
    if (o < 50) {
        const float* xs = xsg + o * 128;
        float s = 0.f;
        #pragma unroll 4
        for (int d = 0; d < 128; ++d) s += xrow[d] * xs[d];
        float sg = 1.0f / (1.0f + __expf(-s));
        if (modes[0] == 1) ((bf16*)out)[(size_t)g * 50 + o] = __float2bfloat16(sg);
        else               ((float*)out)[(size_t)g * 50 + o] = sg;
    }
}

extern "C" void kernel_launch(void* const* d_in, const int* in_sizes, int n_in,
                              void* d_out, int out_size, void* d_ws, size_t ws_size,
                              hipStream_t stream) {
    const int nN = 100000, nE = 800000, nS = 51200, nES = 409600;
    const int Bg = 1024;

    const int* node_ids = (const int*)d_in[0];
    const int* ei       = (const int*)d_in[2];
    const int* svc_ids  = (const int*)d_in[3];
    const int* eis      = (const int*)d_in[5];
    const int* batch    = (const int*)d_in[7];

    // ---------------- workspace layout (float words, 16B-aligned blocks) ----------------
    float* ws    = (float*)d_ws;
    int*   modes = (int*)ws;                        // 64
    float* stats = ws + 64;                         // 1024
    float* dinv  = ws + 1088;                       // 51200
    float* xsg   = ws + 52288;                      // 6400
    int*   bsum  = (int*)(ws + 58688);              // 256 (two scan partial arrays)
    int*   rp_n  = (int*)(ws + 58944);              // 100001
    int*   adj_n = (int*)(ws + 158948);             // 800000
    int*   rp_s  = (int*)(ws + 958948);             // 51201
    int*   adj_s = (int*)(ws + 1010152);            // 409600
    short* adw_s = (short*)(ws + 1419752);          // 409600 shorts
    short* wtb   = (short*)(ws + 1624552);          // 262144 shorts
    float* xg    = ws + 1755624;                    // 131072 (also cur_n early)
    float* part  = ws + 1886696;                    // 51200  (also cur_s early)
    float* A25   = ws + 1937896;                    // 25,600,000
    float* B13   = ws + 27537896;                   // 13,107,200
    float* C13   = ws + 40645096;                   // 13,107,200
    size_t need  = (size_t)53752296 * 4;
    if (ws_size < need) return;
    int* cur_n = (int*)xg;
    int* cur_s = (int*)part;
    int* bsum_n = bsum;
    int* bsum_s = bsum + 128;

    short* A25H = (short*)A25;  short* A25L = (short*)(A25 + 12800000);
    short* B13H = (short*)B13;  short* B13L = (short*)(B13 + 6553600);
    short* C13H = (short*)C13;  short* C13L = (short*)(C13 + 6553600);
    float* B13F = B13;  float* A25F = A25;

    short* wt0 = wtb;               // g0_W1  256 x 96
    short* wt1 = wt0 + 24576;       // g0_W2  128 x 256
    short* wt2 = wt1 + 32768;       // g1_W1  256 x 128
    short* wt3 = wt2 + 32768;       // g1_W2  128 x 256
    short* wt4 = wt3 + 32768;       // nl_W   128 x 128
    short* wt5 = wt4 + 16384;       // c0_W   256 x 96
    short* wt6 = wt5 + 24576;       // c1_W   256 x 256
    short* wt7 = wt6 + 65536;       // sl_W   128 x 256

    // ---------------- detect dtypes (once, 35 blocks) ----------------
    static const int conv_idx[NCONV] = {1, 4, 6, 10, 11,
        12, 13, 14, 15, 16, 17, 18, 19, 20,
        21, 22, 23, 24, 25, 26, 27, 28, 29,
        30, 31, 32, 33, 34, 35, 36, 37, 38, 39, 40, 41};
    DetArgs da;
    for (int b = 0; b < NCONV; ++b) { da.src[b] = d_in[conv_idx[b]]; da.n[b] = in_sizes[conv_idx[b]]; }
    detect_all<<<NCONV, 256, 0, stream>>>(da, modes);

    // ---------------- weight transposes (batched) ----------------
    {
        WtArgs wa;
        const int din_i[8]  = {12, 16, 21, 25, 30, 32, 36, 40};
        const int midx_i[8] = {5, 9, 14, 18, 23, 25, 29, 33};
        const int KW_i[8]   = {70, 256, 128, 256, 128, 68, 256, 256};
        const int ldw_i[8]  = {256, 128, 256, 128, 128, 256, 256, 128};
        short* wt_i[8]      = {wt0, wt1, wt2, wt3, wt4, wt5, wt6, wt7};
        const int Kp_i[8]   = {96, 256, 128, 256, 128, 96, 256, 256};
        const int N_i[8]    = {256, 128, 256, 128, 128, 256, 256, 128};
        for (int e = 0; e < 8; ++e) {
            wa.W[e] = d_in[din_i[e]]; wa.midx[e] = midx_i[e]; wa.KW[e] = KW_i[e];
            wa.ldw[e] = ldw_i[e]; wa.wt[e] = wt_i[e]; wa.Kpad[e] = Kp_i[e]; wa.N[e] = N_i[e];
        }
        wt_build_all<<<dim3(256, 8), 256, 0, stream>>>(wa, modes);
    }

    // ---------------- degrees (before CSR fill so adjw can fold dinv) ----------------
    hipMemsetAsync(dinv, 0, nS * sizeof(float), stream);
    deg_scatter<<<(nES + 255) / 256, 256, 0, stream>>>(d_in[6], modes, 2, eis + nES, dinv, nES);
    dinv_fin<<<(nS + 255) / 256, 256, 0, stream>>>(dinv, nS);

    // ---------------- CSR builds (hierarchical scan) ----------------
    const int nbN = (nN + 1023) / 1024, nbS = (nS + 1023) / 1024;
    hipMemsetAsync(cur_n, 0, nN * sizeof(int), stream);
    csr_count<<<(nE + 255) / 256, 256, 0, stream>>>(ei + nE, nE, cur_n);
    scan_part<<<nbN, 256, 0, stream>>>(cur_n, nN, bsum_n);
    scan_mid<<<1, 128, 0, stream>>>(bsum_n, nbN, rp_n, nN);
    scan_fin<<<nbN, 256, 0, stream>>>(cur_n, nN, bsum_n, rp_n, cur_n);
    csr_fill<<<(nE + 255) / 256, 256, 0, stream>>>(ei, ei + nE, nullptr, modes, 2, nullptr,
                                                   nE, cur_n, adj_n, nullptr);

    hipMemsetAsync(cur_s, 0, nS * sizeof(int), stream);
    csr_count<<<(nES + 255) / 256, 256, 0, stream>>>(eis + nES, nES, cur_s);
    scan_part<<<nbS, 256, 0, stream>>>(cur_s, nS, bsum_s);
    scan_mid<<<1, 128, 0, stream>>>(bsum_s, nbS, rp_s, nS);
    scan_fin<<<nbS, 256, 0, stream>>>(cur_s, nS, bsum_s, rp_s, cur_s);
    csr_fill<<<(nES + 255) / 256, 256, 0, stream>>>(eis, eis + nES, d_in[6], modes, 2, dinv,
                                                    nES, cur_s, adj_s, adw_s);

    auto gemm = [&](const short* Ah, const short* Al, int ldk, const short* Wt,
                    const void* bias, int bidx, float* outF, short* oH, short* oL,
                    int M, int N, int pair) {
        if (pair) hipMemsetAsync(stats, 0, 2 * N * sizeof(float), stream);
        dim3 grid(N / 128, (M + 127) / 128);
        gemm_mfma<<<grid, 256, 0, stream>>>(Ah, Al, ldk, Wt, bias, modes, bidx,
                                            outF, oH, oL, stats, M, N, ldk / 32, pair);
    };
    auto bnfin = [&](int gidx, int bidx, const void* g, const void* b, int C, int M) {
        bn_finalize<<<1, C, 0, stream>>>(stats, g, b, modes, gidx, bidx, C, 1.0f / M);
    };
    auto bninp = [&](short* H, short* L, int M, int C) {
        size_t t4 = (size_t)M * C / 4;
        bn_pair_inplace<<<(t4 + 255) / 256, 256, 0, stream>>>(H, L, stats, t4, C - 1, C);
    };

    // ---------------- node branch ----------------
    build_feat_pair<<<nN, 128, 0, stream>>>(d_in[10], node_ids, d_in[1], modes, 3, 0,
                                            C13H, C13L, 6, 96);
    gin_gather_pair<<<nN, 128, 0, stream>>>(C13H, C13L, rp_n, adj_n, d_in[18], modes, 11,
                                            B13H, B13L, 96);
    gemm(B13H, B13L, 96, wt0, d_in[13], 6, nullptr, A25H, A25L, nN, 256, 1);
    bnfin(7, 8, d_in[14], d_in[15], 256, nN);
    bninp(A25H, A25L, nN, 256);
    gemm(A25H, A25L, 256, wt1, d_in[17], 10, nullptr, C13H, C13L, nN, 128, 1);
    bnfin(12, 13, d_in[19], d_in[20], 128, nN);
    bninp(C13H, C13L, nN, 128);

    gin_gather_pair<<<nN, 128, 0, stream>>>(C13H, C13L, rp_n, adj_n, d_in[27], modes, 20,
                                            B13H, B13L, 128);
    gemm(B13H, B13L, 128, wt2, d_in[22], 15, nullptr, A25H, A25L, nN, 256, 1);
    bnfin(16, 17, d_in[23], d_in[24], 256, nN);
    bninp(A25H, A25L, nN, 256);
    gemm(A25H, A25L, 256, wt3, d_in[26], 19, nullptr, C13H, C13L, nN, 128, 1);
    bnfin(21, 22, d_in[28], d_in[29], 128, nN);
    bninp(C13H, C13L, nN, 128);

    gemm(C13H, C13L, 128, wt4, d_in[31], 24, B13F, nullptr, nullptr, nN, 128, 0);
    pool_sorted<<<Bg, 128, 0, stream>>>(B13F, batch, xg, nN);

    // ---------------- service branch ----------------
    build_feat_pair<<<nS, 128, 0, stream>>>(d_in[11], svc_ids, d_in[4], modes, 4, 1,
                                            C13H, C13L, 4, 96);
    gemm(C13H, C13L, 96, wt5, nullptr, 0, B13F, nullptr, nullptr, nS, 256, 0);
    gcn_gather<<<nS, 256, 0, stream>>>(B13F, rp_s, adj_s, adw_s, dinv, d_in[33], modes, 26, A25F);
    hipMemsetAsync(stats, 0, 2 * 256 * sizeof(float), stream);
    bn_stats_f32<<<(nS + 511) / 512, 256, 0, stream>>>(A25F, stats, nS, 256, 512);
    bnfin(27, 28, d_in[34], d_in[35], 256, nS);
    { size_t t = (size_t)nS * 256;
      bn_f32_to_pair<<<(t + 255) / 256, 256, 0, stream>>>(A25F, stats, C13H, C13L, t, 255, 256); }

    gemm(C13H, C13L, 256, wt6, nullptr, 0, B13F, nullptr, nullptr, nS, 256, 0);
    gcn_gather<<<nS, 256, 0, stream>>>(B13F, rp_s, adj_s, adw_s, dinv, d_in[37], modes, 30, A25F);
    hipMemsetAsync(stats, 0, 2 * 256 * sizeof(float), stream);
    bn_stats_f32<<<(nS + 511) / 512, 256, 0, stream>>>(A25F, stats, nS, 256, 512);
    bnfin(31, 32, d_in[38], d_in[39], 256, nS);
    { size_t t = (size_t)nS * 256;
      bn_f32_to_pair<<<(t + 255) / 256, 256, 0, stream>>>(A25F, stats, C13H, C13L, t, 255, 256); }

    gemm(C13H, C13L, 256, wt7, d_in[41], 34, B13F, nullptr, nullptr, nS, 128, 0);
    svc_pool1<<<dim3(50, 8), 128, 0, stream>>>(B13F, part);
    svc_pool2<<<50, 128, 0, stream>>>(part, xsg);

    // ---------------- output ----------------
    final_out<<<Bg, 64, 0, stream>>>(xg, xsg, modes, d_out);
}

// Round 6
// 1582.715 us; speedup vs baseline: 2.4050x; 1.1132x over previous
//
#include <hip/hip_runtime.h>
#include <hip/hip_bf16.h>
#include <cstddef>
#include <cstdint>

typedef __hip_bfloat16 bf16;
typedef __attribute__((ext_vector_type(8))) short short8;      // 8 bf16 (4 VGPRs)
typedef __attribute__((ext_vector_type(4))) float floatx4;     // MFMA acc
typedef __attribute__((ext_vector_type(8))) unsigned uintx8;   // 8 packed pairs

static __device__ __forceinline__ float b2f(bf16 v) { return __bfloat162float(v); }

static __device__ __forceinline__ short f2bf(float f) {
    unsigned u = __float_as_uint(f);
    unsigned r = u + 0x7FFF + ((u >> 16) & 1);
    return (short)(r >> 16);
}
static __device__ __forceinline__ float bf2f(short h) {
    return __uint_as_float(((unsigned)(unsigned short)h) << 16);
}
// packed pair: hi bf16 in top 16 bits, lo bf16 in low 16 bits
static __device__ __forceinline__ unsigned packf(float f) {
    unsigned u = __float_as_uint(f);
    unsigned hi = (u + 0x7FFF + ((u >> 16) & 1)) & 0xFFFF0000u;
    float l = f - __uint_as_float(hi);
    unsigned ul = __float_as_uint(l);
    unsigned lo = ((ul + 0x7FFF + ((ul >> 16) & 1)) >> 16) & 0xFFFFu;
    return hi | lo;
}
static __device__ __forceinline__ float unpackf(unsigned p) {
    return __uint_as_float(p & 0xFFFF0000u) + __uint_as_float(p << 16);
}
union S8u { unsigned u[4]; short8 s; };
static __device__ __forceinline__ void unpack8(uintx8 a, short8& hi, short8& lo) {
    S8u h, l;
    #pragma unroll
    for (int j = 0; j < 4; ++j) {
        unsigned u0 = a[2 * j], u1 = a[2 * j + 1];
        h.u[j] = (u0 >> 16) | (u1 & 0xFFFF0000u);
        l.u[j] = (u0 & 0xFFFFu) | (u1 << 16);
    }
    hi = h.s; lo = l.s;
}
// mode: 0=zero, 1=bf16-stored, 2=fp32-stored
static __device__ __forceinline__ float loadf(const void* p, int mode, size_t i) {
    if (mode == 1) return b2f(((const bf16*)p)[i]);
    if (mode == 2) return ((const float*)p)[i];
    return 0.f;
}

#define NCONV 35
struct DetArgs { const void* src[NCONV]; int n[NCONV]; };

// ---------------- dtype detection (one block per buffer) ----------------
__global__ void detect_all(DetArgs a, int* __restrict__ modes) {
    int b = blockIdx.x;
    int n = a.n[b];
    const unsigned short* w = (const unsigned short*)a.src[b];
    __shared__ int cz, cbad, cevz, codz;
    if (threadIdx.x == 0) { cz = 0; cbad = 0; cevz = 0; codz = 0; }
    __syncthreads();
    int K = n < 2048 ? n : 2048;
    int z = 0, bad = 0, evz = 0, odz = 0;
    for (int i = threadIdx.x; i < K; i += blockDim.x) {
        unsigned short v = w[i];
        int e = (v >> 7) & 0xFF;
        bool isz = (v & 0x7FFF) == 0;
        if (isz) { z++; if (i & 1) odz++; else evz++; }
        else if (e < 91 || e > 140) bad++;
    }
    atomicAdd(&cz, z); atomicAdd(&cbad, bad);
    atomicAdd(&cevz, evz); atomicAdd(&codz, odz);
    __syncthreads();
    if (threadIdx.x == 0) {
        int mode;
        if (cz >= K) mode = 0;
        else if (cbad * 16 > K) mode = 2;
        else if (cevz * 4 > K && codz * 16 < K) mode = 2;
        else mode = 1;
        modes[b] = mode;
    }
}

// ---------------- batched weight transpose -> bf16 Wt[n][Kpad] ----------------
struct WtArgs {
    const void* W[8]; short* wt[8];
    int midx[8]; int KW[8]; int ldw[8]; int Kpad[8]; int N[8];
};
__global__ void wt_build_all(WtArgs a, const int* __restrict__ modes) {
    int e = blockIdx.y;
    int n = blockIdx.x; if (n >= a.N[e]) return;
    int k = threadIdx.x; if (k >= a.Kpad[e]) return;
    float v = (k < a.KW[e]) ? loadf(a.W[e], modes[a.midx[e]], (size_t)k * a.ldw[e] + n) : 0.f;
    a.wt[e][(size_t)n * a.Kpad[e] + k] = f2bf(v);
}

// ---------------- feature build -> packed plane ----------------
__global__ void build_feat_pack(const void* __restrict__ emb, const int* __restrict__ ids,
                                const void* __restrict__ feats, const int* __restrict__ modes,
                                int eidx, int fidx, unsigned* __restrict__ P, int nf, int Ws) {
    int i = blockIdx.x;
    int d = threadIdx.x;          // 128
    if (d >= Ws) return;
    float v;
    if (d < 64)           v = loadf(emb, modes[eidx], (size_t)ids[i] * 64 + d);
    else if (d < 64 + nf) v = loadf(feats, modes[fidx], (size_t)i * nf + (d - 64));
    else                  v = 0.f;
    P[(size_t)i * Ws + d] = packf(v);
}

// ---------------- CSR build ----------------
__global__ void csr_count(const int* __restrict__ dst, int nE, int* __restrict__ cnt) {
    int e = blockIdx.x * blockDim.x + threadIdx.x;
    if (e < nE) atomicAdd(&cnt[dst[e]], 1);
}

__global__ __launch_bounds__(256) void scan_part(const int* __restrict__ cnt, int n,
                                                 int* __restrict__ bsum) {
    __shared__ int red[256];
    int blk = blockIdx.x, t = threadIdx.x;
    int base = blk * 1024 + t * 4;
    int s = 0;
    #pragma unroll
    for (int k = 0; k < 4; ++k) { int i = base + k; if (i < n) s += cnt[i]; }
    red[t] = s;
    __syncthreads();
    for (int off = 128; off > 0; off >>= 1) {
        if (t < off) red[t] += red[t + off];
        __syncthreads();
    }
    if (t == 0) bsum[blk] = red[0];
}

__global__ __launch_bounds__(128) void scan_mid(int* __restrict__ bsum, int nb,
                                                int* __restrict__ rowptr, int n) {
    __shared__ int sh[128];
    int t = threadIdx.x;
    int v = (t < nb) ? bsum[t] : 0;
    sh[t] = v;
    __syncthreads();
    for (int off = 1; off < 128; off <<= 1) {
        int u = (t >= off) ? sh[t - off] : 0;
        __syncthreads();
        sh[t] += u;
        __syncthreads();
    }
    if (t < nb) bsum[t] = sh[t] - v;        // exclusive
    if (t == 127) rowptr[n] = sh[127];      // total
}

__global__ __launch_bounds__(256) void scan_fin(const int* __restrict__ cnt, int n,
                                                const int* __restrict__ bsum,
                                                int* __restrict__ rowptr, int* __restrict__ cursor) {
    __shared__ int sh[256];
    int blk = blockIdx.x, t = threadIdx.x;
    int base = blk * 1024 + t * 4;
    int v[4], s = 0;
    #pragma unroll
    for (int k = 0; k < 4; ++k) { int i = base + k; v[k] = (i < n) ? cnt[i] : 0; s += v[k]; }
    sh[t] = s;
    __syncthreads();
    for (int off = 1; off < 256; off <<= 1) {
        int u = (t >= off) ? sh[t - off] : 0;
        __syncthreads();
        sh[t] += u;
        __syncthreads();
    }
    int run = sh[t] - s + bsum[blk];
    #pragma unroll
    for (int k = 0; k < 4; ++k) {
        int i = base + k;
        if (i < n) { rowptr[i] = run; cursor[i] = run; run += v[k]; }
    }
}

__global__ void csr_fill(const int* __restrict__ src, const int* __restrict__ dst,
                         const void* __restrict__ w, const int* __restrict__ modes, int widx,
                         const float* __restrict__ dinv, int nE, int* __restrict__ cursor,
                         int* __restrict__ adj, short* __restrict__ adjw) {
    int e = blockIdx.x * blockDim.x + threadIdx.x;
    if (e < nE) {
        int s = src[e];
        int pos = atomicAdd(&cursor[dst[e]], 1);
        adj[pos] = s;
        if (adjw) adjw[pos] = f2bf(dinv[s] * loadf(w, modes[widx], e));
    }
}

// ---------------- GIN gather on packed (fused (1+eps)x) ----------------
__global__ void gin_gather_pack(const unsigned* __restrict__ P, const int* __restrict__ rowptr,
                                const int* __restrict__ adj, const void* __restrict__ eps,
                                const int* __restrict__ modes, int eidx,
                                unsigned* __restrict__ Po, int Ws) {
    int i = blockIdx.x;
    int d = threadIdx.x;          // 128
    if (d >= Ws) return;
    float epsv = 1.0f + loadf(eps, modes[eidx], 0);
    int lo = rowptr[i], hi = rowptr[i + 1];
    float acc = 0.f;
    for (int p = lo; p < hi; ++p)
        acc += unpackf(P[(size_t)adj[p] * Ws + d]);
    size_t o = (size_t)i * Ws + d;
    acc += epsv * unpackf(P[o]);
    Po[o] = packf(acc);
}

// ---------------- GCN gather (fused self-loop + bias), C=256, fp32 in/out ----------------
__global__ void gcn_gather(const float* __restrict__ xw, const int* __restrict__ rowptr,
                           const int* __restrict__ adj, const short* __restrict__ adjw,
                           const float* __restrict__ dinv, const void* __restrict__ bias,
                           const int* __restrict__ modes, int bidx, float* __restrict__ out) {
    int i = blockIdx.x;
    int d = threadIdx.x;          // 256
    float di = dinv[i];
    float acc = xw[(size_t)i * 256 + d] * di * di + loadf(bias, modes[bidx], d);
    int lo = rowptr[i], hi = rowptr[i + 1];
    for (int p = lo; p < hi; ++p) {
        int s = adj[p];
        acc += di * bf2f(adjw[p]) * xw[(size_t)s * 256 + d];
    }
    out[(size_t)i * 256 + d] = acc;
}

// ---------------- MFMA GEMM: out[M,N] = A(hi+lo packed)[M,ldk] @ Wt^T ----------------
__global__ __launch_bounds__(256) void gemm_mfma(
        const unsigned* __restrict__ Ap, int ldk,
        const short* __restrict__ Wt,
        const void* __restrict__ bias, const int* __restrict__ modes, int bias_midx,
        float* __restrict__ outF, unsigned* __restrict__ oP,
        float* __restrict__ stats, int M, int N, int ksteps, int pair_out) {
    int tid  = threadIdx.x;
    int wv   = tid >> 6, lane = tid & 63;
    int m16  = lane & 15, q = lane >> 4;
    int bm   = blockIdx.y * 128 + wv * 32;
    int n0   = blockIdx.x * 128;
    int r0 = min(bm + m16, M - 1);
    int r1 = min(bm + 16 + m16, M - 1);
    const uintx8* pa0 = (const uintx8*)(Ap + (size_t)r0 * ldk + q * 8);
    const uintx8* pa1 = (const uintx8*)(Ap + (size_t)r1 * ldk + q * 8);
    const short8* pb[8];
    #pragma unroll
    for (int nt = 0; nt < 8; ++nt)
        pb[nt] = (const short8*)(Wt + (size_t)(n0 + nt * 16 + m16) * ldk + q * 8);

    floatx4 acc[2][8];
    #pragma unroll
    for (int mt = 0; mt < 2; ++mt)
        #pragma unroll
        for (int nt = 0; nt < 8; ++nt)
            acc[mt][nt] = (floatx4){0.f, 0.f, 0.f, 0.f};

    for (int ks = 0; ks < ksteps; ++ks) {
        int idx = ks * 4;                 // uintx8 units (32 packed / k-step)
        short8 a0h, a0l, a1h, a1l;
        unpack8(pa0[idx], a0h, a0l);
        unpack8(pa1[idx], a1h, a1l);
        #pragma unroll
        for (int nt = 0; nt < 8; ++nt) {
            short8 b = pb[nt][idx];
            acc[0][nt] = __builtin_amdgcn_mfma_f32_16x16x32_bf16(a0h, b, acc[0][nt], 0, 0, 0);
            acc[0][nt] = __builtin_amdgcn_mfma_f32_16x16x32_bf16(a0l, b, acc[0][nt], 0, 0, 0);
            acc[1][nt] = __builtin_amdgcn_mfma_f32_16x16x32_bf16(a1h, b, acc[1][nt], 0, 0, 0);
            acc[1][nt] = __builtin_amdgcn_mfma_f32_16x16x32_bf16(a1l, b, acc[1][nt], 0, 0, 0);
        }
    }

    float bv[8];
    int bmode = bias ? modes[bias_midx] : 0;
    #pragma unroll
    for (int nt = 0; nt < 8; ++nt)
        bv[nt] = bias ? loadf(bias, bmode, n0 + nt * 16 + m16) : 0.f;

    if (pair_out) {
        float sA[8], qA[8];
        #pragma unroll
        for (int nt = 0; nt < 8; ++nt) { sA[nt] = 0.f; qA[nt] = 0.f; }
        #pragma unroll
        for (int mt = 0; mt < 2; ++mt)
            #pragma unroll
            for (int r = 0; r < 4; ++r) {
                int row = bm + mt * 16 + q * 4 + r;
                bool ok = row < M;
                #pragma unroll
                for (int nt = 0; nt < 8; ++nt) {
                    float v = acc[mt][nt][r] + bv[nt];
                    if (ok) {
                        oP[(size_t)row * N + n0 + nt * 16 + m16] = packf(v);
                        sA[nt] += v; qA[nt] += v * v;
                    }
                }
            }
        #pragma unroll
        for (int nt = 0; nt < 8; ++nt) {
            sA[nt] += __shfl_xor(sA[nt], 16); sA[nt] += __shfl_xor(sA[nt], 32);
            qA[nt] += __shfl_xor(qA[nt], 16); qA[nt] += __shfl_xor(qA[nt], 32);
        }
        __shared__ float redS[4][128], redQ[4][128];
        if (q == 0) {
            #pragma unroll
            for (int nt = 0; nt < 8; ++nt) {
                redS[wv][nt * 16 + m16] = sA[nt];
                redQ[wv][nt * 16 + m16] = qA[nt];
            }
        }
        __syncthreads();
        if (tid < 128) {
            float s = 0.f, qq = 0.f;
            #pragma unroll
            for (int w = 0; w < 4; ++w) { s += redS[w][tid]; qq += redQ[w][tid]; }
            atomicAdd(&stats[n0 + tid], s);
            atomicAdd(&stats[N + n0 + tid], qq);
        }
    } else {
        #pragma unroll
        for (int mt = 0; mt < 2; ++mt)
            #pragma unroll
            for (int r = 0; r < 4; ++r) {
                int row = bm + mt * 16 + q * 4 + r;
                if (row >= M) continue;
                #pragma unroll
                for (int nt = 0; nt < 8; ++nt)
                    outF[(size_t)row * N + n0 + nt * 16 + m16] = acc[mt][nt][r] + bv[nt];
            }
    }
}

// ---------------- BatchNorm ----------------
__global__ void bn_finalize(float* __restrict__ stats, const void* __restrict__ g,
                            const void* __restrict__ b, const int* __restrict__ modes,
                            int gidx, int bidx, int C, float invM) {
    int c = threadIdx.x;
    if (c < C) {
        float mean = stats[c] * invM;
        float var  = fmaxf(stats[C + c] * invM - mean * mean, 0.f);
        float sc   = loadf(g, modes[gidx], c) * rsqrtf(var + 1e-5f);
        stats[2 * C + c] = sc;
        stats[3 * C + c] = loadf(b, modes[bidx], c) - mean * sc;
    }
}

__global__ void bn_pack_inplace(unsigned* __restrict__ P, const float* __restrict__ stats,
                                size_t total4, int cmask, int C) {
    size_t i = (size_t)blockIdx.x * blockDim.x + threadIdx.x;
    if (i >= total4) return;
    size_t e = i * 4;
    int c = (int)(e & (size_t)cmask);
    uint4 p = *(uint4*)(P + e);
    const float* sc = stats + 2 * C;
    const float* sh = stats + 3 * C;
    p.x = packf(fmaxf(unpackf(p.x) * sc[c + 0] + sh[c + 0], 0.f));
    p.y = packf(fmaxf(unpackf(p.y) * sc[c + 1] + sh[c + 1], 0.f));
    p.z = packf(fmaxf(unpackf(p.z) * sc[c + 2] + sh[c + 2], 0.f));
    p.w = packf(fmaxf(unpackf(p.w) * sc[c + 3] + sh[c + 3], 0.f));
    *(uint4*)(P + e) = p;
}

__global__ void bn_stats_f32(const float* __restrict__ X, float* __restrict__ stats,
                             int M, int C, int rows) {
    int c = threadIdx.x;          // blockDim == C
    int r0 = blockIdx.x * rows;
    int r1 = min(r0 + rows, M);
    float s = 0.f, s2 = 0.f;
    for (int r = r0; r < r1; ++r) {
        float v = X[(size_t)r * C + c];
        s += v; s2 += v * v;
    }
    atomicAdd(&stats[c], s);
    atomicAdd(&stats[C + c], s2);
}

__global__ void bn_f32_to_pack(const float* __restrict__ X, const float* __restrict__ stats,
                               unsigned* __restrict__ P, size_t total, int cmask, int C) {
    size_t i = (size_t)blockIdx.x * blockDim.x + threadIdx.x;
    if (i >= total) return;
    int c = (int)(i & (size_t)cmask);
    float v = fmaxf(X[i] * stats[2 * C + c] + stats[3 * C + c], 0.f);
    P[i] = packf(v);
}

// ---------------- GCN degree ----------------
__global__ void deg_scatter(const void* __restrict__ ew, const int* __restrict__ modes, int eidx,
                            const int* __restrict__ col, float* __restrict__ deg, int nE) {
    int e = blockIdx.x * blockDim.x + threadIdx.x;
    if (e < nE) atomicAdd(&deg[col[e]], loadf(ew, modes[eidx], e));
}

__global__ void dinv_fin(float* __restrict__ deg, int n) {
    int i = blockIdx.x * blockDim.x + threadIdx.x;
    if (i < n) {
        float d = deg[i] + 1.0f;
        deg[i] = d > 0.f ? rsqrtf(d) : 0.f;
    }
}

// ---------------- pooling ----------------
__global__ void pool_sorted(const float* __restrict__ xn, const int* __restrict__ batch,
                            float* __restrict__ xg, int nN) {
    int g = blockIdx.x;
    int lo = 0, hi = nN;
    while (lo < hi) { int mid = (lo + hi) >> 1; if (batch[mid] < g) lo = mid + 1; else hi = mid; }
    int lo2 = lo, hi2 = nN;
    while (lo2 < hi2) { int mid = (lo2 + hi2) >> 1; if (batch[mid] < g + 1) lo2 = mid + 1; else hi2 = mid; }
    int d = threadIdx.x;          // 128
    float s = 0.f;
    for (int r = lo; r < lo2; ++r) s += xn[(size_t)r * 128 + d];
    xg[(size_t)g * 128 + d] = s / fmaxf((float)(lo2 - lo), 1.0f);
}

__global__ void svc_pool1(const float* __restrict__ xsl, float* __restrict__ partial) {
    int o = blockIdx.x;           // 50
    int c = blockIdx.y;           // 8
    int d = threadIdx.x;          // 128
    float s = 0.f;
    int r0 = c * 128;
    for (int r = r0; r < r0 + 128; ++r)
        s += xsl[((size_t)(r * 50 + o)) * 128 + d];
    partial[((size_t)(o * 8 + c)) * 128 + d] = s;
}

__global__ void svc_pool2(const float* __restrict__ partial, float* __restrict__ xsg) {
    int o = blockIdx.x;           // 50
    int d = threadIdx.x;          // 128
    float s = 0.f;
    #pragma unroll
    for (int c = 0; c < 8; ++c)
        s += partial[((size_t)(o * 8 + c)) * 128 + d];
    xsg[o * 128 + d] = s * (1.0f / 1024.0f);
}

// ---------------- final ----------------
__global__ void final_out(const float* __restrict__ xg, const float* __restrict__ xsg,
                          const int* __restrict__ modes, void* __restrict__ out) {
    __shared__ float xrow[128];
    int g = blockIdx.x;
    for (int d = threadIdx.x; d < 128; d += 64) xrow[d] = xg[(size_t)g * 128 + d];
    __syncthreads();
    int o = threadIdx.x;
    if (o < 50) {
        const float* xs = xsg + o * 128;
        float s = 0.f;
        #pragma unroll 4
        for (int d = 0; d < 128; ++d) s += xrow[d] * xs[d];
        float sg = 1.0f / (1.0f + __expf(-s));
        if (modes[0] == 1) ((bf16*)out)[(size_t)g * 50 + o] = __float2bfloat16(sg);
        else               ((float*)out)[(size_t)g * 50 + o] = sg;
    }
}

extern "C" void kernel_launch(void* const* d_in, const int* in_sizes, int n_in,
                              void* d_out, int out_size, void* d_ws, size_t ws_size,
                              hipStream_t stream) {
    const int nN = 100000, nE = 800000, nS = 51200, nES = 409600;
    const int Bg = 1024;

    const int* node_ids = (const int*)d_in[0];
    const int* ei       = (const int*)d_in[2];
    const int* svc_ids  = (const int*)d_in[3];
    const int* eis      = (const int*)d_in[5];
    const int* batch    = (const int*)d_in[7];

    // ---------------- workspace layout (float words, 16B-aligned blocks) ----------------
    float* ws    = (float*)d_ws;
    int*   modes = (int*)ws;                        // 64
    float* stats = ws + 64;                         // 1024
    float* dinv  = ws + 1088;                       // 51200
    float* xsg   = ws + 52288;                      // 6400
    int*   bsum  = (int*)(ws + 58688);              // 256
    int*   rp_n  = (int*)(ws + 58944);              // 100001
    int*   adj_n = (int*)(ws + 158948);             // 800000
    int*   rp_s  = (int*)(ws + 958948);             // 51201
    int*   adj_s = (int*)(ws + 1010152);            // 409600
    short* adw_s = (short*)(ws + 1419752);          // 409600 shorts
    short* wtb   = (short*)(ws + 1624552);          // 262144 shorts
    float* xg    = ws + 1755624;                    // 131072 (also cur_n early)
    float* part  = ws + 1886696;                    // 51200  (also cur_s early)
    float* A25   = ws + 1937896;                    // 25,600,000
    float* B13   = ws + 27537896;                   // 13,107,200
    float* C13   = ws + 40645096;                   // 13,107,200
    size_t need  = (size_t)53752296 * 4;
    if (ws_size < need) return;
    int* cur_n = (int*)xg;
    int* cur_s = (int*)part;
    int* bsum_n = bsum;
    int* bsum_s = bsum + 128;

    unsigned* A25P = (unsigned*)A25;
    unsigned* B13P = (unsigned*)B13;
    unsigned* C13P = (unsigned*)C13;
    float* B13F = B13;  float* A25F = A25;

    short* wt0 = wtb;               // g0_W1  256 x 96
    short* wt1 = wt0 + 24576;       // g0_W2  128 x 256
    short* wt2 = wt1 + 32768;       // g1_W1  256 x 128
    short* wt3 = wt2 + 32768;       // g1_W2  128 x 256
    short* wt4 = wt3 + 32768;       // nl_W   128 x 128
    short* wt5 = wt4 + 16384;       // c0_W   256 x 96
    short* wt6 = wt5 + 24576;       // c1_W   256 x 256
    short* wt7 = wt6 + 65536;       // sl_W   128 x 256

    // ---------------- detect dtypes (once, 35 blocks) ----------------
    static const int conv_idx[NCONV] = {1, 4, 6, 10, 11,
        12, 13, 14, 15, 16, 17, 18, 19, 20,
        21, 22, 23, 24, 25, 26, 27, 28, 29,
        30, 31, 32, 33, 34, 35, 36, 37, 38, 39, 40, 41};
    DetArgs da;
    for (int b = 0; b < NCONV; ++b) { da.src[b] = d_in[conv_idx[b]]; da.n[b] = in_sizes[conv_idx[b]]; }
    detect_all<<<NCONV, 256, 0, stream>>>(da, modes);

    // ---------------- weight transposes (batched) ----------------
    {
        WtArgs wa;
        const int din_i[8]  = {12, 16, 21, 25, 30, 32, 36, 40};
        const int midx_i[8] = {5, 9, 14, 18, 23, 25, 29, 33};
        const int KW_i[8]   = {70, 256, 128, 256, 128, 68, 256, 256};
        const int ldw_i[8]  = {256, 128, 256, 128, 128, 256, 256, 128};
        short* wt_i[8]      = {wt0, wt1, wt2, wt3, wt4, wt5, wt6, wt7};
        const int Kp_i[8]   = {96, 256, 128, 256, 128, 96, 256, 256};
        const int N_i[8]    = {256, 128, 256, 128, 128, 256, 256, 128};
        for (int e = 0; e < 8; ++e) {
            wa.W[e] = d_in[din_i[e]]; wa.midx[e] = midx_i[e]; wa.KW[e] = KW_i[e];
            wa.ldw[e] = ldw_i[e]; wa.wt[e] = wt_i[e]; wa.Kpad[e] = Kp_i[e]; wa.N[e] = N_i[e];
        }
        wt_build_all<<<dim3(256, 8), 256, 0, stream>>>(wa, modes);
    }

    // ---------------- degrees (before CSR fill so adjw can fold dinv) ----------------
    hipMemsetAsync(dinv, 0, nS * sizeof(float), stream);
    deg_scatter<<<(nES + 255) / 256, 256, 0, stream>>>(d_in[6], modes, 2, eis + nES, dinv, nES);
    dinv_fin<<<(nS + 255) / 256, 256, 0, stream>>>(dinv, nS);

    // ---------------- CSR builds (hierarchical scan) ----------------
    const int nbN = (nN + 1023) / 1024, nbS = (nS + 1023) / 1024;
    hipMemsetAsync(cur_n, 0, nN * sizeof(int), stream);
    csr_count<<<(nE + 255) / 256, 256, 0, stream>>>(ei + nE, nE, cur_n);
    scan_part<<<nbN, 256, 0, stream>>>(cur_n, nN, bsum_n);
    scan_mid<<<1, 128, 0, stream>>>(bsum_n, nbN, rp_n, nN);
    scan_fin<<<nbN, 256, 0, stream>>>(cur_n, nN, bsum_n, rp_n, cur_n);
    csr_fill<<<(nE + 255) / 256, 256, 0, stream>>>(ei, ei + nE, nullptr, modes, 2, nullptr,
                                                   nE, cur_n, adj_n, nullptr);

    hipMemsetAsync(cur_s, 0, nS * sizeof(int), stream);
    csr_count<<<(nES + 255) / 256, 256, 0, stream>>>(eis + nES, nES, cur_s);
    scan_part<<<nbS, 256, 0, stream>>>(cur_s, nS, bsum_s);
    scan_mid<<<1, 128, 0, stream>>>(bsum_s, nbS, rp_s, nS);
    scan_fin<<<nbS, 256, 0, stream>>>(cur_s, nS, bsum_s, rp_s, cur_s);
    csr_fill<<<(nES + 255) / 256, 256, 0, stream>>>(eis, eis + nES, d_in[6], modes, 2, dinv,
                                                    nES, cur_s, adj_s, adw_s);

    auto gemm = [&](const unsigned* Ap, int ldk, const short* Wt,
                    const void* bias, int bidx, float* outF, unsigned* oP,
                    int M, int N, int pair) {
        if (pair) hipMemsetAsync(stats, 0, 2 * N * sizeof(float), stream);
        dim3 grid(N / 128, (M + 127) / 128);
        gemm_mfma<<<grid, 256, 0, stream>>>(Ap, ldk, Wt, bias, modes, bidx,
                                            outF, oP, stats, M, N, ldk / 32, pair);
    };
    auto bnfin = [&](int gidx, int bidx, const void* g, const void* b, int C, int M) {
        bn_finalize<<<1, C, 0, stream>>>(stats, g, b, modes, gidx, bidx, C, 1.0f / M);
    };
    auto bninp = [&](unsigned* P, int M, int C) {
        size_t t4 = (size_t)M * C / 4;
        bn_pack_inplace<<<(t4 + 255) / 256, 256, 0, stream>>>(P, stats, t4, C - 1, C);
    };

    // ---------------- node branch ----------------
    build_feat_pack<<<nN, 128, 0, stream>>>(d_in[10], node_ids, d_in[1], modes, 3, 0,
                                            C13P, 6, 96);
    gin_gather_pack<<<nN, 128, 0, stream>>>(C13P, rp_n, adj_n, d_in[18], modes, 11, B13P, 96);
    gemm(B13P, 96, wt0, d_in[13], 6, nullptr, A25P, nN, 256, 1);
    bnfin(7, 8, d_in[14], d_in[15], 256, nN);
    bninp(A25P, nN, 256);
    gemm(A25P, 256, wt1, d_in[17], 10, nullptr, C13P, nN, 128, 1);
    bnfin(12, 13, d_in[19], d_in[20], 128, nN);
    bninp(C13P, nN, 128);

    gin_gather_pack<<<nN, 128, 0, stream>>>(C13P, rp_n, adj_n, d_in[27], modes, 20, B13P, 128);
    gemm(B13P, 128, wt2, d_in[22], 15, nullptr, A25P, nN, 256, 1);
    bnfin(16, 17, d_in[23], d_in[24], 256, nN);
    bninp(A25P, nN, 256);
    gemm(A25P, 256, wt3, d_in[26], 19, nullptr, C13P, nN, 128, 1);
    bnfin(21, 22, d_in[28], d_in[29], 128, nN);
    bninp(C13P, nN, 128);

    gemm(C13P, 128, wt4, d_in[31], 24, B13F, nullptr, nN, 128, 0);
    pool_sorted<<<Bg, 128, 0, stream>>>(B13F, batch, xg, nN);

    // ---------------- service branch ----------------
    build_feat_pack<<<nS, 128, 0, stream>>>(d_in[11], svc_ids, d_in[4], modes, 4, 1,
                                            C13P, 4, 96);
    gemm(C13P, 96, wt5, nullptr, 0, B13F, nullptr, nS, 256, 0);
    gcn_gather<<<nS, 256, 0, stream>>>(B13F, rp_s, adj_s, adw_s, dinv, d_in[33], modes, 26, A25F);
    hipMemsetAsync(stats, 0, 2 * 256 * sizeof(float), stream);
    bn_stats_f32<<<(nS + 31) / 32, 256, 0, stream>>>(A25F, stats, nS, 256, 32);
    bnfin(27, 28, d_in[34], d_in[35], 256, nS);
    { size_t t = (size_t)nS * 256;
      bn_f32_to_pack<<<(t + 255) / 256, 256, 0, stream>>>(A25F, stats, C13P, t, 255, 256); }

    gemm(C13P, 256, wt6, nullptr, 0, B13F, nullptr, nS, 256, 0);
    gcn_gather<<<nS, 256, 0, stream>>>(B13F, rp_s, adj_s, adw_s, dinv, d_in[37], modes, 30, A25F);
    hipMemsetAsync(stats, 0, 2 * 256 * sizeof(float), stream);
    bn_stats_f32<<<(nS + 31) / 32, 256, 0, stream>>>(A25F, stats, nS, 256, 32);
    bnfin(31, 32, d_in[38], d_in[39], 256, nS);
    { size_t t = (size_t)nS * 256;
      bn_f32_to_pack<<<(t + 255) / 256, 256, 0, stream>>>(A25F, stats, C13P, t, 255, 256); }

    gemm(C13P, 256, wt7, d_in[41], 34, B13F, nullptr, nS, 128, 0);
    svc_pool1<<<dim3(50, 8), 128, 0, stream>>>(B13F, part);
    svc_pool2<<<50, 128, 0, stream>>>(part, xsg);

    // ---------------- output ----------------
    final_out<<<Bg, 64, 0, stream>>>(xg, xsg, modes, d_out);
}

// Round 7
// 1430.645 us; speedup vs baseline: 2.6607x; 1.1063x over previous
//
#include <hip/hip_runtime.h>
#include <hip/hip_bf16.h>
#include <cstddef>
#include <cstdint>

typedef __hip_bfloat16 bf16;
typedef __attribute__((ext_vector_type(8))) short short8;      // 8 bf16 (4 VGPRs)
typedef __attribute__((ext_vector_type(4))) float floatx4;     // MFMA acc
typedef __attribute__((ext_vector_type(8))) unsigned uintx8;   // 8 packed pairs

static __device__ __forceinline__ float b2f(bf16 v) { return __bfloat162float(v); }

static __device__ __forceinline__ short f2bf(float f) {
    unsigned u = __float_as_uint(f);
    unsigned r = u + 0x7FFF + ((u >> 16) & 1);
    return (short)(r >> 16);
}
static __device__ __forceinline__ float bf2f(short h) {
    return __uint_as_float(((unsigned)(unsigned short)h) << 16);
}
// packed pair: hi bf16 in top 16 bits, lo bf16 in low 16 bits
static __device__ __forceinline__ unsigned packf(float f) {
    unsigned u = __float_as_uint(f);
    unsigned hi = (u + 0x7FFF + ((u >> 16) & 1)) & 0xFFFF0000u;
    float l = f - __uint_as_float(hi);
    unsigned ul = __float_as_uint(l);
    unsigned lo = ((ul + 0x7FFF + ((ul >> 16) & 1)) >> 16) & 0xFFFFu;
    return hi | lo;
}
static __device__ __forceinline__ float unpackf(unsigned p) {
    return __uint_as_float(p & 0xFFFF0000u) + __uint_as_float(p << 16);
}
union S8u { unsigned u[4]; short8 s; };
static __device__ __forceinline__ void unpack8(uintx8 a, short8& hi, short8& lo) {
    S8u h, l;
    #pragma unroll
    for (int j = 0; j < 4; ++j) {
        unsigned u0 = a[2 * j], u1 = a[2 * j + 1];
        h.u[j] = (u0 >> 16) | (u1 & 0xFFFF0000u);
        l.u[j] = (u0 & 0xFFFFu) | (u1 << 16);
    }
    hi = h.s; lo = l.s;
}
// mode: 0=zero, 1=bf16-stored, 2=fp32-stored
static __device__ __forceinline__ float loadf(const void* p, int mode, size_t i) {
    if (mode == 1) return b2f(((const bf16*)p)[i]);
    if (mode == 2) return ((const float*)p)[i];
    return 0.f;
}

#define NCONV 35
struct DetArgs { const void* src[NCONV]; int n[NCONV]; };

// ---------------- dtype detection (one block per buffer) ----------------
__global__ void detect_all(DetArgs a, int* __restrict__ modes) {
    int b = blockIdx.x;
    int n = a.n[b];
    const unsigned short* w = (const unsigned short*)a.src[b];
    __shared__ int cz, cbad, cevz, codz;
    if (threadIdx.x == 0) { cz = 0; cbad = 0; cevz = 0; codz = 0; }
    __syncthreads();
    int K = n < 2048 ? n : 2048;
    int z = 0, bad = 0, evz = 0, odz = 0;
    for (int i = threadIdx.x; i < K; i += blockDim.x) {
        unsigned short v = w[i];
        int e = (v >> 7) & 0xFF;
        bool isz = (v & 0x7FFF) == 0;
        if (isz) { z++; if (i & 1) odz++; else evz++; }
        else if (e < 91 || e > 140) bad++;
    }
    atomicAdd(&cz, z); atomicAdd(&cbad, bad);
    atomicAdd(&cevz, evz); atomicAdd(&codz, odz);
    __syncthreads();
    if (threadIdx.x == 0) {
        int mode;
        if (cz >= K) mode = 0;
        else if (cbad * 16 > K) mode = 2;
        else if (cevz * 4 > K && codz * 16 < K) mode = 2;
        else mode = 1;
        modes[b] = mode;
    }
}

// ---------------- batched weight transpose -> bf16 Wt[n][Kpad] ----------------
struct WtArgs {
    const void* W[8]; short* wt[8];
    int midx[8]; int KW[8]; int ldw[8]; int Kpad[8]; int N[8];
};
__global__ void wt_build_all(WtArgs a, const int* __restrict__ modes) {
    int e = blockIdx.y;
    int n = blockIdx.x; if (n >= a.N[e]) return;
    int k = threadIdx.x; if (k >= a.Kpad[e]) return;
    float v = (k < a.KW[e]) ? loadf(a.W[e], modes[a.midx[e]], (size_t)k * a.ldw[e] + n) : 0.f;
    a.wt[e][(size_t)n * a.Kpad[e] + k] = f2bf(v);
}

// ---------------- feature build -> packed plane ----------------
__global__ void build_feat_pack(const void* __restrict__ emb, const int* __restrict__ ids,
                                const void* __restrict__ feats, const int* __restrict__ modes,
                                int eidx, int fidx, unsigned* __restrict__ P, int nf, int Ws) {
    int i = blockIdx.x;
    int d = threadIdx.x;          // 128
    if (d >= Ws) return;
    float v;
    if (d < 64)           v = loadf(emb, modes[eidx], (size_t)ids[i] * 64 + d);
    else if (d < 64 + nf) v = loadf(feats, modes[fidx], (size_t)i * nf + (d - 64));
    else                  v = 0.f;
    P[(size_t)i * Ws + d] = packf(v);
}

// ---------------- CSR build ----------------
__global__ void csr_count(const int* __restrict__ dst, int nE, int* __restrict__ cnt) {
    int e = blockIdx.x * blockDim.x + threadIdx.x;
    if (e < nE) atomicAdd(&cnt[dst[e]], 1);
}

__global__ __launch_bounds__(256) void scan_part(const int* __restrict__ cnt, int n,
                                                 int* __restrict__ bsum) {
    __shared__ int red[256];
    int blk = blockIdx.x, t = threadIdx.x;
    int base = blk * 1024 + t * 4;
    int s = 0;
    #pragma unroll
    for (int k = 0; k < 4; ++k) { int i = base + k; if (i < n) s += cnt[i]; }
    red[t] = s;
    __syncthreads();
    for (int off = 128; off > 0; off >>= 1) {
        if (t < off) red[t] += red[t + off];
        __syncthreads();
    }
    if (t == 0) bsum[blk] = red[0];
}

__global__ __launch_bounds__(128) void scan_mid(int* __restrict__ bsum, int nb,
                                                int* __restrict__ rowptr, int n) {
    __shared__ int sh[128];
    int t = threadIdx.x;
    int v = (t < nb) ? bsum[t] : 0;
    sh[t] = v;
    __syncthreads();
    for (int off = 1; off < 128; off <<= 1) {
        int u = (t >= off) ? sh[t - off] : 0;
        __syncthreads();
        sh[t] += u;
        __syncthreads();
    }
    if (t < nb) bsum[t] = sh[t] - v;        // exclusive
    if (t == 127) rowptr[n] = sh[127];      // total
}

__global__ __launch_bounds__(256) void scan_fin(const int* __restrict__ cnt, int n,
                                                const int* __restrict__ bsum,
                                                int* __restrict__ rowptr, int* __restrict__ cursor) {
    __shared__ int sh[256];
    int blk = blockIdx.x, t = threadIdx.x;
    int base = blk * 1024 + t * 4;
    int v[4], s = 0;
    #pragma unroll
    for (int k = 0; k < 4; ++k) { int i = base + k; v[k] = (i < n) ? cnt[i] : 0; s += v[k]; }
    sh[t] = s;
    __syncthreads();
    for (int off = 1; off < 256; off <<= 1) {
        int u = (t >= off) ? sh[t - off] : 0;
        __syncthreads();
        sh[t] += u;
        __syncthreads();
    }
    int run = sh[t] - s + bsum[blk];
    #pragma unroll
    for (int k = 0; k < 4; ++k) {
        int i = base + k;
        if (i < n) { rowptr[i] = run; cursor[i] = run; run += v[k]; }
    }
}

__global__ void csr_fill(const int* __restrict__ src, const int* __restrict__ dst,
                         const void* __restrict__ w, const int* __restrict__ modes, int widx,
                         const float* __restrict__ dinv, int nE, int* __restrict__ cursor,
                         int* __restrict__ adj, short* __restrict__ adjw) {
    int e = blockIdx.x * blockDim.x + threadIdx.x;
    if (e < nE) {
        int s = src[e];
        int pos = atomicAdd(&cursor[dst[e]], 1);
        adj[pos] = s;
        if (adjw) adjw[pos] = f2bf(dinv[s] * loadf(w, modes[widx], e));
    }
}

// ---------------- GIN gather, vectorized: uint4/lane, 32-lane group per row ----------------
__global__ __launch_bounds__(256) void gin_gather_pack(
        const unsigned* __restrict__ P, const int* __restrict__ rowptr,
        const int* __restrict__ adj, const void* __restrict__ eps,
        const int* __restrict__ modes, int eidx,
        unsigned* __restrict__ Po, int Ws, int nN) {
    int W4 = Ws >> 2;
    int g = threadIdx.x >> 5;                 // row group 0..7
    int l = threadIdx.x & 31;                 // lane in group
    int i = blockIdx.x * 8 + g;
    if (i >= nN || l >= W4) return;
    float epsv = 1.0f + loadf(eps, modes[eidx], 0);
    int lo = rowptr[i], hi = rowptr[i + 1];
    float4 acc = {0.f, 0.f, 0.f, 0.f};
    int p = lo;
    for (; p + 1 < hi; p += 2) {
        int s0 = adj[p], s1 = adj[p + 1];
        uint4 v0 = *(const uint4*)(P + (size_t)s0 * Ws + (l << 2));
        uint4 v1 = *(const uint4*)(P + (size_t)s1 * Ws + (l << 2));
        acc.x += unpackf(v0.x) + unpackf(v1.x);
        acc.y += unpackf(v0.y) + unpackf(v1.y);
        acc.z += unpackf(v0.z) + unpackf(v1.z);
        acc.w += unpackf(v0.w) + unpackf(v1.w);
    }
    if (p < hi) {
        uint4 v0 = *(const uint4*)(P + (size_t)adj[p] * Ws + (l << 2));
        acc.x += unpackf(v0.x); acc.y += unpackf(v0.y);
        acc.z += unpackf(v0.z); acc.w += unpackf(v0.w);
    }
    size_t o = (size_t)i * Ws + (l << 2);
    uint4 sv = *(const uint4*)(P + o);
    acc.x += epsv * unpackf(sv.x); acc.y += epsv * unpackf(sv.y);
    acc.z += epsv * unpackf(sv.z); acc.w += epsv * unpackf(sv.w);
    uint4 r;
    r.x = packf(acc.x); r.y = packf(acc.y); r.z = packf(acc.z); r.w = packf(acc.w);
    *(uint4*)(Po + o) = r;
}

// ---------------- GCN gather, vectorized: float4/lane, wave per 256-col row ----------------
__global__ __launch_bounds__(256) void gcn_gather(
        const float* __restrict__ xw, const int* __restrict__ rowptr,
        const int* __restrict__ adj, const short* __restrict__ adjw,
        const float* __restrict__ dinv, const void* __restrict__ bias,
        const int* __restrict__ modes, int bidx, float* __restrict__ out, int nS) {
    int g = threadIdx.x >> 6;                 // 0..3
    int l = threadIdx.x & 63;
    int i = blockIdx.x * 4 + g;
    if (i >= nS) return;
    float di = dinv[i];
    int bmode = modes[bidx];
    size_t o = (size_t)i * 256 + (l << 2);
    float4 self = *(const float4*)(xw + o);
    float4 acc;
    float dd = di * di;
    acc.x = self.x * dd + loadf(bias, bmode, (l << 2) + 0);
    acc.y = self.y * dd + loadf(bias, bmode, (l << 2) + 1);
    acc.z = self.z * dd + loadf(bias, bmode, (l << 2) + 2);
    acc.w = self.w * dd + loadf(bias, bmode, (l << 2) + 3);
    int lo = rowptr[i], hi = rowptr[i + 1];
    int p = lo;
    for (; p + 1 < hi; p += 2) {
        int s0 = adj[p], s1 = adj[p + 1];
        float w0 = di * bf2f(adjw[p]), w1 = di * bf2f(adjw[p + 1]);
        float4 v0 = *(const float4*)(xw + (size_t)s0 * 256 + (l << 2));
        float4 v1 = *(const float4*)(xw + (size_t)s1 * 256 + (l << 2));
        acc.x += w0 * v0.x + w1 * v1.x;
        acc.y += w0 * v0.y + w1 * v1.y;
        acc.z += w0 * v0.z + w1 * v1.z;
        acc.w += w0 * v0.w + w1 * v1.w;
    }
    if (p < hi) {
        float w0 = di * bf2f(adjw[p]);
        float4 v0 = *(const float4*)(xw + (size_t)adj[p] * 256 + (l << 2));
        acc.x += w0 * v0.x; acc.y += w0 * v0.y;
        acc.z += w0 * v0.z; acc.w += w0 * v0.w;
    }
    *(float4*)(out + o) = acc;
}

// ---------------- MFMA GEMM: out[M,N] = A(hi+lo packed)[M,ldk] @ Wt^T ----------------
__global__ __launch_bounds__(256) void gemm_mfma(
        const unsigned* __restrict__ Ap, int ldk,
        const short* __restrict__ Wt,
        const void* __restrict__ bias, const int* __restrict__ modes, int bias_midx,
        float* __restrict__ outF, unsigned* __restrict__ oP,
        float* __restrict__ stats, int M, int N, int ksteps, int pair_out) {
    int tid  = threadIdx.x;
    int wv   = tid >> 6, lane = tid & 63;
    int m16  = lane & 15, q = lane >> 4;
    int bm   = blockIdx.y * 128 + wv * 32;
    int n0   = blockIdx.x * 128;
    int r0 = min(bm + m16, M - 1);
    int r1 = min(bm + 16 + m16, M - 1);
    const uintx8* pa0 = (const uintx8*)(Ap + (size_t)r0 * ldk + q * 8);
    const uintx8* pa1 = (const uintx8*)(Ap + (size_t)r1 * ldk + q * 8);
    const short8* pb[8];
    #pragma unroll
    for (int nt = 0; nt < 8; ++nt)
        pb[nt] = (const short8*)(Wt + (size_t)(n0 + nt * 16 + m16) * ldk + q * 8);

    floatx4 acc[2][8];
    #pragma unroll
    for (int mt = 0; mt < 2; ++mt)
        #pragma unroll
        for (int nt = 0; nt < 8; ++nt)
            acc[mt][nt] = (floatx4){0.f, 0.f, 0.f, 0.f};

    for (int ks = 0; ks < ksteps; ++ks) {
        int idx = ks * 4;                 // uintx8 units (32 packed / k-step)
        short8 a0h, a0l, a1h, a1l;
        unpack8(pa0[idx], a0h, a0l);
        unpack8(pa1[idx], a1h, a1l);
        #pragma unroll
        for (int nt = 0; nt < 8; ++nt) {
            short8 b = pb[nt][idx];
            acc[0][nt] = __builtin_amdgcn_mfma_f32_16x16x32_bf16(a0h, b, acc[0][nt], 0, 0, 0);
            acc[0][nt] = __builtin_amdgcn_mfma_f32_16x16x32_bf16(a0l, b, acc[0][nt], 0, 0, 0);
            acc[1][nt] = __builtin_amdgcn_mfma_f32_16x16x32_bf16(a1h, b, acc[1][nt], 0, 0, 0);
            acc[1][nt] = __builtin_amdgcn_mfma_f32_16x16x32_bf16(a1l, b, acc[1][nt], 0, 0, 0);
        }
    }

    float bv[8];
    int bmode = bias ? modes[bias_midx] : 0;
    #pragma unroll
    for (int nt = 0; nt < 8; ++nt)
        bv[nt] = bias ? loadf(bias, bmode, n0 + nt * 16 + m16) : 0.f;

    if (pair_out) {
        float sA[8], qA[8];
        #pragma unroll
        for (int nt = 0; nt < 8; ++nt) { sA[nt] = 0.f; qA[nt] = 0.f; }
        #pragma unroll
        for (int mt = 0; mt < 2; ++mt)
            #pragma unroll
            for (int r = 0; r < 4; ++r) {
                int row = bm + mt * 16 + q * 4 + r;
                bool ok = row < M;
                #pragma unroll
                for (int nt = 0; nt < 8; ++nt) {
                    float v = acc[mt][nt][r] + bv[nt];
                    if (ok) {
                        oP[(size_t)row * N + n0 + nt * 16 + m16] = packf(v);
                        sA[nt] += v; qA[nt] += v * v;
                    }
                }
            }
        #pragma unroll
        for (int nt = 0; nt < 8; ++nt) {
            sA[nt] += __shfl_xor(sA[nt], 16); sA[nt] += __shfl_xor(sA[nt], 32);
            qA[nt] += __shfl_xor(qA[nt], 16); qA[nt] += __shfl_xor(qA[nt], 32);
        }
        __shared__ float redS[4][128], redQ[4][128];
        if (q == 0) {
            #pragma unroll
            for (int nt = 0; nt < 8; ++nt) {
                redS[wv][nt * 16 + m16] = sA[nt];
                redQ[wv][nt * 16 + m16] = qA[nt];
            }
        }
        __syncthreads();
        if (tid < 128) {
            float s = 0.f, qq = 0.f;
            #pragma unroll
            for (int w = 0; w < 4; ++w) { s += redS[w][tid]; qq += redQ[w][tid]; }
            atomicAdd(&stats[n0 + tid], s);
            atomicAdd(&stats[N + n0 + tid], qq);
        }
    } else {
        #pragma unroll
        for (int mt = 0; mt < 2; ++mt)
            #pragma unroll
            for (int r = 0; r < 4; ++r) {
                int row = bm + mt * 16 + q * 4 + r;
                if (row >= M) continue;
                #pragma unroll
                for (int nt = 0; nt < 8; ++nt)
                    outF[(size_t)row * N + n0 + nt * 16 + m16] = acc[mt][nt][r] + bv[nt];
            }
    }
}

// ---------------- BatchNorm ----------------
__global__ void bn_finalize(float* __restrict__ stats, const void* __restrict__ g,
                            const void* __restrict__ b, const int* __restrict__ modes,
                            int gidx, int bidx, int C, float invM) {
    int c = threadIdx.x;
    if (c < C) {
        float mean = stats[c] * invM;
        float var  = fmaxf(stats[C + c] * invM - mean * mean, 0.f);
        float sc   = loadf(g, modes[gidx], c) * rsqrtf(var + 1e-5f);
        stats[2 * C + c] = sc;
        stats[3 * C + c] = loadf(b, modes[bidx], c) - mean * sc;
    }
}

__global__ void bn_pack_inplace(unsigned* __restrict__ P, const float* __restrict__ stats,
                                size_t total4, int cmask, int C) {
    size_t i = (size_t)blockIdx.x * blockDim.x + threadIdx.x;
    if (i >= total4) return;
    size_t e = i * 4;
    int c = (int)(e & (size_t)cmask);
    uint4 p = *(uint4*)(P + e);
    const float* sc = stats + 2 * C;
    const float* sh = stats + 3 * C;
    p.x = packf(fmaxf(unpackf(p.x) * sc[c + 0] + sh[c + 0], 0.f));
    p.y = packf(fmaxf(unpackf(p.y) * sc[c + 1] + sh[c + 1], 0.f));
    p.z = packf(fmaxf(unpackf(p.z) * sc[c + 2] + sh[c + 2], 0.f));
    p.w = packf(fmaxf(unpackf(p.w) * sc[c + 3] + sh[c + 3], 0.f));
    *(uint4*)(P + e) = p;
}

__global__ void bn_stats_f32(const float* __restrict__ X, float* __restrict__ stats,
                             int M, int C, int rows) {
    int c = threadIdx.x;          // blockDim == C
    int r0 = blockIdx.x * rows;
    int r1 = min(r0 + rows, M);
    float s = 0.f, s2 = 0.f;
    for (int r = r0; r < r1; ++r) {
        float v = X[(size_t)r * C + c];
        s += v; s2 += v * v;
    }
    atomicAdd(&stats[c], s);
    atomicAdd(&stats[C + c], s2);
}

__global__ void bn_f32_to_pack(const float* __restrict__ X, const float* __restrict__ stats,
                               unsigned* __restrict__ P, size_t total4, int cmask, int C) {
    size_t i = (size_t)blockIdx.x * blockDim.x + threadIdx.x;
    if (i >= total4) return;
    size_t e = i * 4;
    int c = (int)(e & (size_t)cmask);
    float4 x = *(const float4*)(X + e);
    const float* sc = stats + 2 * C;
    const float* sh = stats + 3 * C;
    uint4 r;
    r.x = packf(fmaxf(x.x * sc[c + 0] + sh[c + 0], 0.f));
    r.y = packf(fmaxf(x.y * sc[c + 1] + sh[c + 1], 0.f));
    r.z = packf(fmaxf(x.z * sc[c + 2] + sh[c + 2], 0.f));
    r.w = packf(fmaxf(x.w * sc[c + 3] + sh[c + 3], 0.f));
    *(uint4*)(P + e) = r;
}

// ---------------- GCN degree ----------------
__global__ void deg_scatter(const void* __restrict__ ew, const int* __restrict__ modes, int eidx,
                            const int* __restrict__ col, float* __restrict__ deg, int nE) {
    int e = blockIdx.x * blockDim.x + threadIdx.x;
    if (e < nE) atomicAdd(&deg[col[e]], loadf(ew, modes[eidx], e));
}

__global__ void dinv_fin(float* __restrict__ deg, int n) {
    int i = blockIdx.x * blockDim.x + threadIdx.x;
    if (i < n) {
        float d = deg[i] + 1.0f;
        deg[i] = d > 0.f ? rsqrtf(d) : 0.f;
    }
}

// ---------------- pooling ----------------
__global__ void pool_sorted(const float* __restrict__ xn, const int* __restrict__ batch,
                            float* __restrict__ xg, int nN) {
    int g = blockIdx.x;
    int lo = 0, hi = nN;
    while (lo < hi) { int mid = (lo + hi) >> 1; if (batch[mid] < g) lo = mid + 1; else hi = mid; }
    int lo2 = lo, hi2 = nN;
    while (lo2 < hi2) { int mid = (lo2 + hi2) >> 1; if (batch[mid] < g + 1) lo2 = mid + 1; else hi2 = mid; }
    int d = threadIdx.x;          // 128
    float s = 0.f;
    for (int r = lo; r < lo2; ++r) s += xn[(size_t)r * 128 + d];
    xg[(size_t)g * 128 + d] = s / fmaxf((float)(lo2 - lo), 1.0f);
}

__global__ void svc_pool1(const float* __restrict__ xsl, float* __restrict__ partial) {
    int o = blockIdx.x;           // 50
    int c = blockIdx.y;           // 8
    int d = threadIdx.x;          // 128
    float s = 0.f;
    int r0 = c * 128;
    for (int r = r0; r < r0 + 128; ++r)
        s += xsl[((size_t)(r * 50 + o)) * 128 + d];
    partial[((size_t)(o * 8 + c)) * 128 + d] = s;
}

__global__ void svc_pool2(const float* __restrict__ partial, float* __restrict__ xsg) {
    int o = blockIdx.x;           // 50
    int d = threadIdx.x;          // 128
    float s = 0.f;
    #pragma unroll
    for (int c = 0; c < 8; ++c)
        s += partial[((size_t)(o * 8 + c)) * 128 + d];
    xsg[o * 128 + d] = s * (1.0f / 1024.0f);
}

// ---------------- final ----------------
__global__ void final_out(const float* __restrict__ xg, const float* __restrict__ xsg,
                          const int* __restrict__ modes, void* __restrict__ out) {
    __shared__ float xrow[128];
    int g = blockIdx.x;
    for (int d = threadIdx.x; d < 128; d += 64) xrow[d] = xg[(size_t)g * 128 + d];
    __syncthreads();
    int o = threadIdx.x;
    if (o < 50) {
        const float* xs = xsg + o * 128;
        float s = 0.f;
        #pragma unroll 4
        for (int d = 0; d < 128; ++d) s += xrow[d] * xs[d];
        float sg = 1.0f / (1.0f + __expf(-s));
        if (modes[0] == 1) ((bf16*)out)[(size_t)g * 50 + o] = __float2bfloat16(sg);
        else               ((float*)out)[(size_t)g * 50 + o] = sg;
    }
}

extern "C" void kernel_launch(void* const* d_in, const int* in_sizes, int n_in,
                              void* d_out, int out_size, void* d_ws, size_t ws_size,
                              hipStream_t stream) {
    const int nN = 100000, nE = 800000, nS = 51200, nES = 409600;
    const int Bg = 1024;

    const int* node_ids = (const int*)d_in[0];
    const int* ei       = (const int*)d_in[2];
    const int* svc_ids  = (const int*)d_in[3];
    const int* eis      = (const int*)d_in[5];
    const int* batch    = (const int*)d_in[7];

    // ---------------- workspace layout (float words, 16B-aligned blocks) ----------------
    float* ws    = (float*)d_ws;
    int*   modes = (int*)ws;                        // 64
    float* stats = ws + 64;                         // 1024
    float* dinv  = ws + 1088;                       // 51200
    float* xsg   = ws + 52288;                      // 6400
    int*   bsum  = (int*)(ws + 58688);              // 256
    int*   rp_n  = (int*)(ws + 58944);              // 100001
    int*   adj_n = (int*)(ws + 158948);             // 800000
    int*   rp_s  = (int*)(ws + 958948);             // 51201
    int*   adj_s = (int*)(ws + 1010152);            // 409600
    short* adw_s = (short*)(ws + 1419752);          // 409600 shorts
    short* wtb   = (short*)(ws + 1624552);          // 262144 shorts
    float* xg    = ws + 1755624;                    // 131072 (also cur_n early)
    float* part  = ws + 1886696;                    // 51200  (also cur_s early)
    float* A25   = ws + 1937896;                    // 25,600,000
    float* B13   = ws + 27537896;                   // 13,107,200
    float* C13   = ws + 40645096;                   // 13,107,200
    size_t need  = (size_t)53752296 * 4;
    if (ws_size < need) return;
    int* cur_n = (int*)xg;
    int* cur_s = (int*)part;
    int* bsum_n = bsum;
    int* bsum_s = bsum + 128;

    unsigned* A25P = (unsigned*)A25;
    unsigned* B13P = (unsigned*)B13;
    unsigned* C13P = (unsigned*)C13;
    float* B13F = B13;  float* A25F = A25;

    short* wt0 = wtb;               // g0_W1  256 x 96
    short* wt1 = wt0 + 24576;       // g0_W2  128 x 256
    short* wt2 = wt1 + 32768;       // g1_W1  256 x 128
    short* wt3 = wt2 + 32768;       // g1_W2  128 x 256
    short* wt4 = wt3 + 32768;       // nl_W   128 x 128
    short* wt5 = wt4 + 16384;       // c0_W   256 x 96
    short* wt6 = wt5 + 24576;       // c1_W   256 x 256
    short* wt7 = wt6 + 65536;       // sl_W   128 x 256

    // ---------------- detect dtypes (once, 35 blocks) ----------------
    static const int conv_idx[NCONV] = {1, 4, 6, 10, 11,
        12, 13, 14, 15, 16, 17, 18, 19, 20,
        21, 22, 23, 24, 25, 26, 27, 28, 29,
        30, 31, 32, 33, 34, 35, 36, 37, 38, 39, 40, 41};
    DetArgs da;
    for (int b = 0; b < NCONV; ++b) { da.src[b] = d_in[conv_idx[b]]; da.n[b] = in_sizes[conv_idx[b]]; }
    detect_all<<<NCONV, 256, 0, stream>>>(da, modes);

    // ---------------- weight transposes (batched) ----------------
    {
        WtArgs wa;
        const int din_i[8]  = {12, 16, 21, 25, 30, 32, 36, 40};
        const int midx_i[8] = {5, 9, 14, 18, 23, 25, 29, 33};
        const int KW_i[8]   = {70, 256, 128, 256, 128, 68, 256, 256};
        const int ldw_i[8]  = {256, 128, 256, 128, 128, 256, 256, 128};
        short* wt_i[8]      = {wt0, wt1, wt2, wt3, wt4, wt5, wt6, wt7};
        const int Kp_i[8]   = {96, 256, 128, 256, 128, 96, 256, 256};
        const int N_i[8]    = {256, 128, 256, 128, 128, 256, 256, 128};
        for (int e = 0; e < 8; ++e) {
            wa.W[e] = d_in[din_i[e]]; wa.midx[e] = midx_i[e]; wa.KW[e] = KW_i[e];
            wa.ldw[e] = ldw_i[e]; wa.wt[e] = wt_i[e]; wa.Kpad[e] = Kp_i[e]; wa.N[e] = N_i[e];
        }
        wt_build_all<<<dim3(256, 8), 256, 0, stream>>>(wa, modes);
    }

    // ---------------- degrees (before CSR fill so adjw can fold dinv) ----------------
    hipMemsetAsync(dinv, 0, nS * sizeof(float), stream);
    deg_scatter<<<(nES + 255) / 256, 256, 0, stream>>>(d_in[6], modes, 2, eis + nES, dinv, nES);
    dinv_fin<<<(nS + 255) / 256, 256, 0, stream>>>(dinv, nS);

    // ---------------- CSR builds (hierarchical scan) ----------------
    const int nbN = (nN + 1023) / 1024, nbS = (nS + 1023) / 1024;
    hipMemsetAsync(cur_n, 0, nN * sizeof(int), stream);
    csr_count<<<(nE + 255) / 256, 256, 0, stream>>>(ei + nE, nE, cur_n);
    scan_part<<<nbN, 256, 0, stream>>>(cur_n, nN, bsum_n);
    scan_mid<<<1, 128, 0, stream>>>(bsum_n, nbN, rp_n, nN);
    scan_fin<<<nbN, 256, 0, stream>>>(cur_n, nN, bsum_n, rp_n, cur_n);
    csr_fill<<<(nE + 255) / 256, 256, 0, stream>>>(ei, ei + nE, nullptr, modes, 2, nullptr,
                                                   nE, cur_n, adj_n, nullptr);

    hipMemsetAsync(cur_s, 0, nS * sizeof(int), stream);
    csr_count<<<(nES + 255) / 256, 256, 0, stream>>>(eis + nES, nES, cur_s);
    scan_part<<<nbS, 256, 0, stream>>>(cur_s, nS, bsum_s);
    scan_mid<<<1, 128, 0, stream>>>(bsum_s, nbS, rp_s, nS);
    scan_fin<<<nbS, 256, 0, stream>>>(cur_s, nS, bsum_s, rp_s, cur_s);
    csr_fill<<<(nES + 255) / 256, 256, 0, stream>>>(eis, eis + nES, d_in[6], modes, 2, dinv,
                                                    nES, cur_s, adj_s, adw_s);

    auto gemm = [&](const unsigned* Ap, int ldk, const short* Wt,
                    const void* bias, int bidx, float* outF, unsigned* oP,
                    int M, int N, int pair) {
        if (pair) hipMemsetAsync(stats, 0, 2 * N * sizeof(float), stream);
        dim3 grid(N / 128, (M + 127) / 128);
        gemm_mfma<<<grid, 256, 0, stream>>>(Ap, ldk, Wt, bias, modes, bidx,
                                            outF, oP, stats, M, N, ldk / 32, pair);
    };
    auto bnfin = [&](int gidx, int bidx, const void* g, const void* b, int C, int M) {
        bn_finalize<<<1, C, 0, stream>>>(stats, g, b, modes, gidx, bidx, C, 1.0f / M);
    };
    auto bninp = [&](unsigned* P, int M, int C) {
        size_t t4 = (size_t)M * C / 4;
        bn_pack_inplace<<<(t4 + 255) / 256, 256, 0, stream>>>(P, stats, t4, C - 1, C);
    };

    // ---------------- node branch ----------------
    build_feat_pack<<<nN, 128, 0, stream>>>(d_in[10], node_ids, d_in[1], modes, 3, 0,
                                            C13P, 6, 96);
    gin_gather_pack<<<(nN + 7) / 8, 256, 0, stream>>>(C13P, rp_n, adj_n, d_in[18], modes, 11,
                                                      B13P, 96, nN);
    gemm(B13P, 96, wt0, d_in[13], 6, nullptr, A25P, nN, 256, 1);
    bnfin(7, 8, d_in[14], d_in[15], 256, nN);
    bninp(A25P, nN, 256);
    gemm(A25P, 256, wt1, d_in[17], 10, nullptr, C13P, nN, 128, 1);
    bnfin(12, 13, d_in[19], d_in[20], 128, nN);
    bninp(C13P, nN, 128);

    gin_gather_pack<<<(nN + 7) / 8, 256, 0, stream>>>(C13P, rp_n, adj_n, d_in[27], modes, 20,
                                                      B13P, 128, nN);
    gemm(B13P, 128, wt2, d_in[22], 15, nullptr, A25P, nN, 256, 1);
    bnfin(16, 17, d_in[23], d_in[24], 256, nN);
    bninp(A25P, nN, 256);
    gemm(A25P, 256, wt3, d_in[26], 19, nullptr, C13P, nN, 128, 1);
    bnfin(21, 22, d_in[28], d_in[29], 128, nN);
    bninp(C13P, nN, 128);

    gemm(C13P, 128, wt4, d_in[31], 24, B13F, nullptr, nN, 128, 0);
    pool_sorted<<<Bg, 128, 0, stream>>>(B13F, batch, xg, nN);

    // ---------------- service branch ----------------
    build_feat_pack<<<nS, 128, 0, stream>>>(d_in[11], svc_ids, d_in[4], modes, 4, 1,
                                            C13P, 4, 96);
    gemm(C13P, 96, wt5, nullptr, 0, B13F, nullptr, nS, 256, 0);
    gcn_gather<<<(nS + 3) / 4, 256, 0, stream>>>(B13F, rp_s, adj_s, adw_s, dinv, d_in[33],
                                                 modes, 26, A25F, nS);
    hipMemsetAsync(stats, 0, 2 * 256 * sizeof(float), stream);
    bn_stats_f32<<<(nS + 31) / 32, 256, 0, stream>>>(A25F, stats, nS, 256, 32);
    bnfin(27, 28, d_in[34], d_in[35], 256, nS);
    { size_t t4 = (size_t)nS * 256 / 4;
      bn_f32_to_pack<<<(t4 + 255) / 256, 256, 0, stream>>>(A25F, stats, C13P, t4, 255, 256); }

    gemm(C13P, 256, wt6, nullptr, 0, B13F, nullptr, nS, 256, 0);
    gcn_gather<<<(nS + 3) / 4, 256, 0, stream>>>(B13F, rp_s, adj_s, adw_s, dinv, d_in[37],
                                                 modes, 30, A25F, nS);
    hipMemsetAsync(stats, 0, 2 * 256 * sizeof(float), stream);
    bn_stats_f32<<<(nS + 31) / 32, 256, 0, stream>>>(A25F, stats, nS, 256, 32);
    bnfin(31, 32, d_in[38], d_in[39], 256, nS);
    { size_t t4 = (size_t)nS * 256 / 4;
      bn_f32_to_pack<<<(t4 + 255) / 256, 256, 0, stream>>>(A25F, stats, C13P, t4, 255, 256); }

    gemm(C13P, 256, wt7, d_in[41], 34, B13F, nullptr, nS, 128, 0);
    svc_pool1<<<dim3(50, 8), 128, 0, stream>>>(B13F, part);
    svc_pool2<<<50, 128, 0, stream>>>(part, xsg);

    // ---------------- output ----------------
    final_out<<<Bg, 64, 0, stream>>>(xg, xsg, modes, d_out);
}

// Round 8
// 1368.225 us; speedup vs baseline: 2.7821x; 1.0456x over previous
//
#include <hip/hip_runtime.h>
#include <hip/hip_bf16.h>
#include <cstddef>
#include <cstdint>

typedef __hip_bfloat16 bf16;
typedef __attribute__((ext_vector_type(8))) short short8;      // 8 bf16 (4 VGPRs)
typedef __attribute__((ext_vector_type(4))) float floatx4;     // MFMA acc
typedef __attribute__((ext_vector_type(8))) unsigned uintx8;   // 8 packed pairs

static __device__ __forceinline__ float b2f(bf16 v) { return __bfloat162float(v); }

static __device__ __forceinline__ short f2bf(float f) {
    unsigned u = __float_as_uint(f);
    unsigned r = u + 0x7FFF + ((u >> 16) & 1);
    return (short)(r >> 16);
}
static __device__ __forceinline__ float bf2f(short h) {
    return __uint_as_float(((unsigned)(unsigned short)h) << 16);
}
// packed pair: hi bf16 in top 16 bits, lo bf16 in low 16 bits
static __device__ __forceinline__ unsigned packf(float f) {
    unsigned u = __float_as_uint(f);
    unsigned hi = (u + 0x7FFF + ((u >> 16) & 1)) & 0xFFFF0000u;
    float l = f - __uint_as_float(hi);
    unsigned ul = __float_as_uint(l);
    unsigned lo = ((ul + 0x7FFF + ((ul >> 16) & 1)) >> 16) & 0xFFFFu;
    return hi | lo;
}
static __device__ __forceinline__ float unpackf(unsigned p) {
    return __uint_as_float(p & 0xFFFF0000u) + __uint_as_float(p << 16);
}
union S8u { unsigned u[4]; short8 s; };
static __device__ __forceinline__ void unpack8(uintx8 a, short8& hi, short8& lo) {
    S8u h, l;
    #pragma unroll
    for (int j = 0; j < 4; ++j) {
        unsigned u0 = a[2 * j], u1 = a[2 * j + 1];
        h.u[j] = (u0 >> 16) | (u1 & 0xFFFF0000u);
        l.u[j] = (u0 & 0xFFFFu) | (u1 << 16);
    }
    hi = h.s; lo = l.s;
}
static __device__ __forceinline__ void pack8(const float* v, short8& hi, short8& lo) {
    S8u h, l;
    #pragma unroll
    for (int jj = 0; jj < 4; ++jj) {
        unsigned pA = packf(v[2 * jj]), pB = packf(v[2 * jj + 1]);
        h.u[jj] = (pA >> 16) | (pB & 0xFFFF0000u);
        l.u[jj] = (pA & 0xFFFFu) | (pB << 16);
    }
    hi = h.s; lo = l.s;
}
// mode: 0=zero, 1=bf16-stored, 2=fp32-stored
static __device__ __forceinline__ float loadf(const void* p, int mode, size_t i) {
    if (mode == 1) return b2f(((const bf16*)p)[i]);
    if (mode == 2) return ((const float*)p)[i];
    return 0.f;
}

#define NCONV 35
struct DetArgs { const void* src[NCONV]; int n[NCONV]; };

// ---------------- dtype detection (one block per buffer) ----------------
__global__ void detect_all(DetArgs a, int* __restrict__ modes) {
    int b = blockIdx.x;
    int n = a.n[b];
    const unsigned short* w = (const unsigned short*)a.src[b];
    __shared__ int cz, cbad, cevz, codz;
    if (threadIdx.x == 0) { cz = 0; cbad = 0; cevz = 0; codz = 0; }
    __syncthreads();
    int K = n < 2048 ? n : 2048;
    int z = 0, bad = 0, evz = 0, odz = 0;
    for (int i = threadIdx.x; i < K; i += blockDim.x) {
        unsigned short v = w[i];
        int e = (v >> 7) & 0xFF;
        bool isz = (v & 0x7FFF) == 0;
        if (isz) { z++; if (i & 1) odz++; else evz++; }
        else if (e < 91 || e > 140) bad++;
    }
    atomicAdd(&cz, z); atomicAdd(&cbad, bad);
    atomicAdd(&cevz, evz); atomicAdd(&codz, odz);
    __syncthreads();
    if (threadIdx.x == 0) {
        int mode;
        if (cz >= K) mode = 0;
        else if (cbad * 16 > K) mode = 2;
        else if (cevz * 4 > K && codz * 16 < K) mode = 2;
        else mode = 1;
        modes[b] = mode;
    }
}

// ---------------- batched weight transpose -> bf16 Wt[n][Kpad] ----------------
struct WtArgs {
    const void* W[8]; short* wt[8];
    int midx[8]; int KW[8]; int ldw[8]; int Kpad[8]; int N[8];
};
__global__ void wt_build_all(WtArgs a, const int* __restrict__ modes) {
    int e = blockIdx.y;
    int n = blockIdx.x; if (n >= a.N[e]) return;
    int k = threadIdx.x; if (k >= a.Kpad[e]) return;
    float v = (k < a.KW[e]) ? loadf(a.W[e], modes[a.midx[e]], (size_t)k * a.ldw[e] + n) : 0.f;
    a.wt[e][(size_t)n * a.Kpad[e] + k] = f2bf(v);
}

// ---------------- feature build -> packed plane ----------------
__global__ void build_feat_pack(const void* __restrict__ emb, const int* __restrict__ ids,
                                const void* __restrict__ feats, const int* __restrict__ modes,
                                int eidx, int fidx, unsigned* __restrict__ P, int nf, int Ws) {
    int i = blockIdx.x;
    int d = threadIdx.x;          // 128
    if (d >= Ws) return;
    float v;
    if (d < 64)           v = loadf(emb, modes[eidx], (size_t)ids[i] * 64 + d);
    else if (d < 64 + nf) v = loadf(feats, modes[fidx], (size_t)i * nf + (d - 64));
    else                  v = 0.f;
    P[(size_t)i * Ws + d] = packf(v);
}

// ---------------- CSR build ----------------
__global__ void csr_count(const int* __restrict__ dst, int nE, int* __restrict__ cnt) {
    int e = blockIdx.x * blockDim.x + threadIdx.x;
    if (e < nE) atomicAdd(&cnt[dst[e]], 1);
}

__global__ __launch_bounds__(256) void scan_part(const int* __restrict__ cnt, int n,
                                                 int* __restrict__ bsum) {
    __shared__ int red[256];
    int blk = blockIdx.x, t = threadIdx.x;
    int base = blk * 1024 + t * 4;
    int s = 0;
    #pragma unroll
    for (int k = 0; k < 4; ++k) { int i = base + k; if (i < n) s += cnt[i]; }
    red[t] = s;
    __syncthreads();
    for (int off = 128; off > 0; off >>= 1) {
        if (t < off) red[t] += red[t + off];
        __syncthreads();
    }
    if (t == 0) bsum[blk] = red[0];
}

__global__ __launch_bounds__(128) void scan_mid(int* __restrict__ bsum, int nb,
                                                int* __restrict__ rowptr, int n) {
    __shared__ int sh[128];
    int t = threadIdx.x;
    int v = (t < nb) ? bsum[t] : 0;
    sh[t] = v;
    __syncthreads();
    for (int off = 1; off < 128; off <<= 1) {
        int u = (t >= off) ? sh[t - off] : 0;
        __syncthreads();
        sh[t] += u;
        __syncthreads();
    }
    if (t < nb) bsum[t] = sh[t] - v;        // exclusive
    if (t == 127) rowptr[n] = sh[127];      // total
}

__global__ __launch_bounds__(256) void scan_fin(const int* __restrict__ cnt, int n,
                                                const int* __restrict__ bsum,
                                                int* __restrict__ rowptr, int* __restrict__ cursor) {
    __shared__ int sh[256];
    int blk = blockIdx.x, t = threadIdx.x;
    int base = blk * 1024 + t * 4;
    int v[4], s = 0;
    #pragma unroll
    for (int k = 0; k < 4; ++k) { int i = base + k; v[k] = (i < n) ? cnt[i] : 0; s += v[k]; }
    sh[t] = s;
    __syncthreads();
    for (int off = 1; off < 256; off <<= 1) {
        int u = (t >= off) ? sh[t - off] : 0;
        __syncthreads();
        sh[t] += u;
        __syncthreads();
    }
    int run = sh[t] - s + bsum[blk];
    #pragma unroll
    for (int k = 0; k < 4; ++k) {
        int i = base + k;
        if (i < n) { rowptr[i] = run; cursor[i] = run; run += v[k]; }
    }
}

__global__ void csr_fill(const int* __restrict__ src, const int* __restrict__ dst,
                         const void* __restrict__ w, const int* __restrict__ modes, int widx,
                         const float* __restrict__ dinv, int nE, int* __restrict__ cursor,
                         int* __restrict__ adj, short* __restrict__ adjw) {
    int e = blockIdx.x * blockDim.x + threadIdx.x;
    if (e < nE) {
        int s = src[e];
        int pos = atomicAdd(&cursor[dst[e]], 1);
        adj[pos] = s;
        if (adjw) adjw[pos] = f2bf(dinv[s] * loadf(w, modes[widx], e));
    }
}

// ---------------- GIN gather, vectorized, optional fused BN+ReLU on input ----------------
__global__ __launch_bounds__(256) void gin_gather_pack(
        const unsigned* __restrict__ P, const int* __restrict__ rowptr,
        const int* __restrict__ adj, const void* __restrict__ eps,
        const int* __restrict__ modes, int eidx,
        const float* __restrict__ bnsc, const float* __restrict__ bnsh,
        unsigned* __restrict__ Po, int Ws, int nN) {
    int W4 = Ws >> 2;
    int g = threadIdx.x >> 5;                 // row group 0..7
    int l = threadIdx.x & 31;                 // lane in group
    int i = blockIdx.x * 8 + g;
    if (i >= nN || l >= W4) return;
    float epsv = 1.0f + loadf(eps, modes[eidx], 0);
    float4 sc4 = {1.f, 1.f, 1.f, 1.f}, sh4 = {0.f, 0.f, 0.f, 0.f};
    bool bn = bnsc != nullptr;
    if (bn) { sc4 = *(const float4*)(bnsc + (l << 2)); sh4 = *(const float4*)(bnsh + (l << 2)); }
    int lo = rowptr[i], hi = rowptr[i + 1];
    float4 acc = {0.f, 0.f, 0.f, 0.f};
    for (int p = lo; p < hi; ++p) {
        uint4 v0 = *(const uint4*)(P + (size_t)adj[p] * Ws + (l << 2));
        float4 y;
        y.x = unpackf(v0.x); y.y = unpackf(v0.y); y.z = unpackf(v0.z); y.w = unpackf(v0.w);
        if (bn) {
            y.x = fmaxf(fmaf(y.x, sc4.x, sh4.x), 0.f);
            y.y = fmaxf(fmaf(y.y, sc4.y, sh4.y), 0.f);
            y.z = fmaxf(fmaf(y.z, sc4.z, sh4.z), 0.f);
            y.w = fmaxf(fmaf(y.w, sc4.w, sh4.w), 0.f);
        }
        acc.x += y.x; acc.y += y.y; acc.z += y.z; acc.w += y.w;
    }
    size_t o = (size_t)i * Ws + (l << 2);
    uint4 sv = *(const uint4*)(P + o);
    float4 ys;
    ys.x = unpackf(sv.x); ys.y = unpackf(sv.y); ys.z = unpackf(sv.z); ys.w = unpackf(sv.w);
    if (bn) {
        ys.x = fmaxf(fmaf(ys.x, sc4.x, sh4.x), 0.f);
        ys.y = fmaxf(fmaf(ys.y, sc4.y, sh4.y), 0.f);
        ys.z = fmaxf(fmaf(ys.z, sc4.z, sh4.z), 0.f);
        ys.w = fmaxf(fmaf(ys.w, sc4.w, sh4.w), 0.f);
    }
    acc.x += epsv * ys.x; acc.y += epsv * ys.y;
    acc.z += epsv * ys.z; acc.w += epsv * ys.w;
    uint4 r;
    r.x = packf(acc.x); r.y = packf(acc.y); r.z = packf(acc.z); r.w = packf(acc.w);
    *(uint4*)(Po + o) = r;
}

// ---------------- GCN gather, vectorized ----------------
__global__ __launch_bounds__(256) void gcn_gather(
        const float* __restrict__ xw, const int* __restrict__ rowptr,
        const int* __restrict__ adj, const short* __restrict__ adjw,
        const float* __restrict__ dinv, const void* __restrict__ bias,
        const int* __restrict__ modes, int bidx, float* __restrict__ out, int nS) {
    int g = threadIdx.x >> 6;                 // 0..3
    int l = threadIdx.x & 63;
    int i = blockIdx.x * 4 + g;
    if (i >= nS) return;
    float di = dinv[i];
    int bmode = modes[bidx];
    size_t o = (size_t)i * 256 + (l << 2);
    float4 self = *(const float4*)(xw + o);
    float4 acc;
    float dd = di * di;
    acc.x = self.x * dd + loadf(bias, bmode, (l << 2) + 0);
    acc.y = self.y * dd + loadf(bias, bmode, (l << 2) + 1);
    acc.z = self.z * dd + loadf(bias, bmode, (l << 2) + 2);
    acc.w = self.w * dd + loadf(bias, bmode, (l << 2) + 3);
    int lo = rowptr[i], hi = rowptr[i + 1];
    int p = lo;
    for (; p + 1 < hi; p += 2) {
        int s0 = adj[p], s1 = adj[p + 1];
        float w0 = di * bf2f(adjw[p]), w1 = di * bf2f(adjw[p + 1]);
        float4 v0 = *(const float4*)(xw + (size_t)s0 * 256 + (l << 2));
        float4 v1 = *(const float4*)(xw + (size_t)s1 * 256 + (l << 2));
        acc.x += w0 * v0.x + w1 * v1.x;
        acc.y += w0 * v0.y + w1 * v1.y;
        acc.z += w0 * v0.z + w1 * v1.z;
        acc.w += w0 * v0.w + w1 * v1.w;
    }
    if (p < hi) {
        float w0 = di * bf2f(adjw[p]);
        float4 v0 = *(const float4*)(xw + (size_t)adj[p] * 256 + (l << 2));
        acc.x += w0 * v0.x; acc.y += w0 * v0.y;
        acc.z += w0 * v0.z; acc.w += w0 * v0.w;
    }
    *(float4*)(out + o) = acc;
}

// ---------------- MFMA GEMM: out[M,N] = f(A)[M,ldk] @ Wt^T ----------------
// afmt: 0 = packed hi/lo uint, 1 = fp32.  bnsc/bnsh non-null: A' = relu(A*sc+sh).
__global__ __launch_bounds__(256) void gemm_mfma(
        const void* __restrict__ A, int afmt, int ldk,
        const float* __restrict__ bnsc, const float* __restrict__ bnsh,
        const short* __restrict__ Wt,
        const void* __restrict__ bias, const int* __restrict__ modes, int bias_midx,
        float* __restrict__ outF, unsigned* __restrict__ oP,
        float* __restrict__ stats, int M, int N, int ksteps, int pair_out) {
    int tid  = threadIdx.x;
    int wv   = tid >> 6, lane = tid & 63;
    int m16  = lane & 15, q = lane >> 4;
    int bm   = blockIdx.y * 128 + wv * 32;
    int n0   = blockIdx.x * 128;
    int r0 = min(bm + m16, M - 1);
    int r1 = min(bm + 16 + m16, M - 1);
    const uintx8* pa0 = (const uintx8*)((const unsigned*)A + (size_t)r0 * ldk + q * 8);
    const uintx8* pa1 = (const uintx8*)((const unsigned*)A + (size_t)r1 * ldk + q * 8);
    const float*  fa0 = (const float*)A + (size_t)r0 * ldk + q * 8;
    const float*  fa1 = (const float*)A + (size_t)r1 * ldk + q * 8;
    const short8* pb[8];
    #pragma unroll
    for (int nt = 0; nt < 8; ++nt)
        pb[nt] = (const short8*)(Wt + (size_t)(n0 + nt * 16 + m16) * ldk + q * 8);

    floatx4 acc[2][8];
    #pragma unroll
    for (int mt = 0; mt < 2; ++mt)
        #pragma unroll
        for (int nt = 0; nt < 8; ++nt)
            acc[mt][nt] = (floatx4){0.f, 0.f, 0.f, 0.f};

    bool bn = bnsc != nullptr;
    for (int ks = 0; ks < ksteps; ++ks) {
        int idx = ks * 4;                 // uintx8 units (32 elems / k-step)
        short8 a0h, a0l, a1h, a1l;
        if (!bn && afmt == 0) {
            unpack8(pa0[idx], a0h, a0l);
            unpack8(pa1[idx], a1h, a1l);
        } else {
            int c0 = ks * 32 + q * 8;
            float v0[8], v1[8];
            if (afmt == 0) {
                uintx8 u0 = pa0[idx], u1 = pa1[idx];
                #pragma unroll
                for (int j = 0; j < 8; ++j) { v0[j] = unpackf(u0[j]); v1[j] = unpackf(u1[j]); }
            } else {
                *(float4*)&v0[0] = *(const float4*)(fa0 + ks * 32);
                *(float4*)&v0[4] = *(const float4*)(fa0 + ks * 32 + 4);
                *(float4*)&v1[0] = *(const float4*)(fa1 + ks * 32);
                *(float4*)&v1[4] = *(const float4*)(fa1 + ks * 32 + 4);
            }
            if (bn) {
                float scv[8], shv[8];
                *(float4*)&scv[0] = *(const float4*)(bnsc + c0);
                *(float4*)&scv[4] = *(const float4*)(bnsc + c0 + 4);
                *(float4*)&shv[0] = *(const float4*)(bnsh + c0);
                *(float4*)&shv[4] = *(const float4*)(bnsh + c0 + 4);
                #pragma unroll
                for (int j = 0; j < 8; ++j) {
                    v0[j] = fmaxf(fmaf(v0[j], scv[j], shv[j]), 0.f);
                    v1[j] = fmaxf(fmaf(v1[j], scv[j], shv[j]), 0.f);
                }
            }
            pack8(v0, a0h, a0l);
            pack8(v1, a1h, a1l);
        }
        #pragma unroll
        for (int nt = 0; nt < 8; ++nt) {
            short8 b = pb[nt][idx];
            acc[0][nt] = __builtin_amdgcn_mfma_f32_16x16x32_bf16(a0h, b, acc[0][nt], 0, 0, 0);
            acc[0][nt] = __builtin_amdgcn_mfma_f32_16x16x32_bf16(a0l, b, acc[0][nt], 0, 0, 0);
            acc[1][nt] = __builtin_amdgcn_mfma_f32_16x16x32_bf16(a1h, b, acc[1][nt], 0, 0, 0);
            acc[1][nt] = __builtin_amdgcn_mfma_f32_16x16x32_bf16(a1l, b, acc[1][nt], 0, 0, 0);
        }
    }

    float bv[8];
    int bmode = bias ? modes[bias_midx] : 0;
    #pragma unroll
    for (int nt = 0; nt < 8; ++nt)
        bv[nt] = bias ? loadf(bias, bmode, n0 + nt * 16 + m16) : 0.f;

    if (pair_out) {
        float sA[8], qA[8];
        #pragma unroll
        for (int nt = 0; nt < 8; ++nt) { sA[nt] = 0.f; qA[nt] = 0.f; }
        #pragma unroll
        for (int mt = 0; mt < 2; ++mt)
            #pragma unroll
            for (int r = 0; r < 4; ++r) {
                int row = bm + mt * 16 + q * 4 + r;
                bool ok = row < M;
                #pragma unroll
                for (int nt = 0; nt < 8; ++nt) {
                    float v = acc[mt][nt][r] + bv[nt];
                    if (ok) {
                        oP[(size_t)row * N + n0 + nt * 16 + m16] = packf(v);
                        sA[nt] += v; qA[nt] += v * v;
                    }
                }
            }
        #pragma unroll
        for (int nt = 0; nt < 8; ++nt) {
            sA[nt] += __shfl_xor(sA[nt], 16); sA[nt] += __shfl_xor(sA[nt], 32);
            qA[nt] += __shfl_xor(qA[nt], 16); qA[nt] += __shfl_xor(qA[nt], 32);
        }
        __shared__ float redS[4][128], redQ[4][128];
        if (q == 0) {
            #pragma unroll
            for (int nt = 0; nt < 8; ++nt) {
                redS[wv][nt * 16 + m16] = sA[nt];
                redQ[wv][nt * 16 + m16] = qA[nt];
            }
        }
        __syncthreads();
        if (tid < 128) {
            float s = 0.f, qq = 0.f;
            #pragma unroll
            for (int w = 0; w < 4; ++w) { s += redS[w][tid]; qq += redQ[w][tid]; }
            atomicAdd(&stats[n0 + tid], s);
            atomicAdd(&stats[N + n0 + tid], qq);
        }
    } else {
        #pragma unroll
        for (int mt = 0; mt < 2; ++mt)
            #pragma unroll
            for (int r = 0; r < 4; ++r) {
                int row = bm + mt * 16 + q * 4 + r;
                if (row >= M) continue;
                #pragma unroll
                for (int nt = 0; nt < 8; ++nt)
                    outF[(size_t)row * N + n0 + nt * 16 + m16] = acc[mt][nt][r] + bv[nt];
            }
    }
}

// ---------------- BatchNorm ----------------
__global__ void bn_finalize(float* __restrict__ stats, const void* __restrict__ g,
                            const void* __restrict__ b, const int* __restrict__ modes,
                            int gidx, int bidx, int C, float invM) {
    int c = threadIdx.x;
    if (c < C) {
        float mean = stats[c] * invM;
        float var  = fmaxf(stats[C + c] * invM - mean * mean, 0.f);
        float sc   = loadf(g, modes[gidx], c) * rsqrtf(var + 1e-5f);
        stats[2 * C + c] = sc;
        stats[3 * C + c] = loadf(b, modes[bidx], c) - mean * sc;
    }
}

__global__ void bn_stats_f32(const float* __restrict__ X, float* __restrict__ stats,
                             int M, int C, int rows) {
    int c = threadIdx.x;          // blockDim == C
    int r0 = blockIdx.x * rows;
    int r1 = min(r0 + rows, M);
    float s = 0.f, s2 = 0.f;
    for (int r = r0; r < r1; ++r) {
        float v = X[(size_t)r * C + c];
        s += v; s2 += v * v;
    }
    atomicAdd(&stats[c], s);
    atomicAdd(&stats[C + c], s2);
}

// ---------------- GCN degree ----------------
__global__ void deg_scatter(const void* __restrict__ ew, const int* __restrict__ modes, int eidx,
                            const int* __restrict__ col, float* __restrict__ deg, int nE) {
    int e = blockIdx.x * blockDim.x + threadIdx.x;
    if (e < nE) atomicAdd(&deg[col[e]], loadf(ew, modes[eidx], e));
}

__global__ void dinv_fin(float* __restrict__ deg, int n) {
    int i = blockIdx.x * blockDim.x + threadIdx.x;
    if (i < n) {
        float d = deg[i] + 1.0f;
        deg[i] = d > 0.f ? rsqrtf(d) : 0.f;
    }
}

// ---------------- pooling ----------------
__global__ void pool_sorted(const float* __restrict__ xn, const int* __restrict__ batch,
                            float* __restrict__ xg, int nN) {
    int g = blockIdx.x;
    int lo = 0, hi = nN;
    while (lo < hi) { int mid = (lo + hi) >> 1; if (batch[mid] < g) lo = mid + 1; else hi = mid; }
    int lo2 = lo, hi2 = nN;
    while (lo2 < hi2) { int mid = (lo2 + hi2) >> 1; if (batch[mid] < g + 1) lo2 = mid + 1; else hi2 = mid; }
    int d = threadIdx.x;          // 128
    float s = 0.f;
    for (int r = lo; r < lo2; ++r) s += xn[(size_t)r * 128 + d];
    xg[(size_t)g * 128 + d] = s / fmaxf((float)(lo2 - lo), 1.0f);
}

__global__ void svc_pool1(const float* __restrict__ xsl, float* __restrict__ partial) {
    int o = blockIdx.x;           // 50
    int c = blockIdx.y;           // 8
    int d = threadIdx.x;          // 128
    float s = 0.f;
    int r0 = c * 128;
    for (int r = r0; r < r0 + 128; ++r)
        s += xsl[((size_t)(r * 50 + o)) * 128 + d];
    partial[((size_t)(o * 8 + c)) * 128 + d] = s;
}

__global__ void svc_pool2(const float* __restrict__ partial, float* __restrict__ xsg) {
    int o = blockIdx.x;           // 50
    int d = threadIdx.x;          // 128
    float s = 0.f;
    #pragma unroll
    for (int c = 0; c < 8; ++c)
        s += partial[((size_t)(o * 8 + c)) * 128 + d];
    xsg[o * 128 + d] = s * (1.0f / 1024.0f);
}

// ---------------- final ----------------
__global__ void final_out(const float* __restrict__ xg, const float* __restrict__ xsg,
                          const int* __restrict__ modes, void* __restrict__ out) {
    __shared__ float xrow[128];
    int g = blockIdx.x;
    for (int d = threadIdx.x; d < 128; d += 64) xrow[d] = xg[(size_t)g * 128 + d];
    __syncthreads();
    int o = threadIdx.x;
    if (o < 50) {
        const float* xs = xsg + o * 128;
        float s = 0.f;
        #pragma unroll 4
        for (int d = 0; d < 128; ++d) s += xrow[d] * xs[d];
        float sg = 1.0f / (1.0f + __expf(-s));
        if (modes[0] == 1) ((bf16*)out)[(size_t)g * 50 + o] = __float2bfloat16(sg);
        else               ((float*)out)[(size_t)g * 50 + o] = sg;
    }
}

extern "C" void kernel_launch(void* const* d_in, const int* in_sizes, int n_in,
                              void* d_out, int out_size, void* d_ws, size_t ws_size,
                              hipStream_t stream) {
    const int nN = 100000, nE = 800000, nS = 51200, nES = 409600;
    const int Bg = 1024;

    const int* node_ids = (const int*)d_in[0];
    const int* ei       = (const int*)d_in[2];
    const int* svc_ids  = (const int*)d_in[3];
    const int* eis      = (const int*)d_in[5];
    const int* batch    = (const int*)d_in[7];

    // ---------------- workspace layout (float words, 16B-aligned blocks) ----------------
    float* ws    = (float*)d_ws;
    int*   modes = (int*)ws;                        // 64
    float* stats = ws + 64;                         // 1024
    float* dinv  = ws + 1088;                       // 51200
    float* xsg   = ws + 52288;                      // 6400
    int*   bsum  = (int*)(ws + 58688);              // 256
    int*   rp_n  = (int*)(ws + 58944);              // 100001
    int*   adj_n = (int*)(ws + 158948);             // 800000
    int*   rp_s  = (int*)(ws + 958948);             // 51201
    int*   adj_s = (int*)(ws + 1010152);            // 409600
    short* adw_s = (short*)(ws + 1419752);          // 409600 shorts
    short* wtb   = (short*)(ws + 1624552);          // 262144 shorts
    float* xg    = ws + 1755624;                    // 131072 (also cur_n early)
    float* part  = ws + 1886696;                    // 51200  (also cur_s early)
    float* A25   = ws + 1937896;                    // 25,600,000
    float* B13   = ws + 27537896;                   // 13,107,200
    float* C13   = ws + 40645096;                   // 13,107,200
    size_t need  = (size_t)53752296 * 4;
    if (ws_size < need) return;
    int* cur_n = (int*)xg;
    int* cur_s = (int*)part;
    int* bsum_n = bsum;
    int* bsum_s = bsum + 128;

    unsigned* A25P = (unsigned*)A25;
    unsigned* B13P = (unsigned*)B13;
    unsigned* C13P = (unsigned*)C13;
    float* B13F = B13;  float* A25F = A25;

    // BN sc/sh locations inside stats: C=256 -> sc@512, sh@768 ; C=128 -> sc@256, sh@384
    float* sc256 = stats + 512; float* sh256 = stats + 768;
    float* sc128 = stats + 256; float* sh128 = stats + 384;

    short* wt0 = wtb;               // g0_W1  256 x 96
    short* wt1 = wt0 + 24576;       // g0_W2  128 x 256
    short* wt2 = wt1 + 32768;       // g1_W1  256 x 128
    short* wt3 = wt2 + 32768;       // g1_W2  128 x 256
    short* wt4 = wt3 + 32768;       // nl_W   128 x 128
    short* wt5 = wt4 + 16384;       // c0_W   256 x 96
    short* wt6 = wt5 + 24576;       // c1_W   256 x 256
    short* wt7 = wt6 + 65536;       // sl_W   128 x 256

    // ---------------- detect dtypes (once, 35 blocks) ----------------
    static const int conv_idx[NCONV] = {1, 4, 6, 10, 11,
        12, 13, 14, 15, 16, 17, 18, 19, 20,
        21, 22, 23, 24, 25, 26, 27, 28, 29,
        30, 31, 32, 33, 34, 35, 36, 37, 38, 39, 40, 41};
    DetArgs da;
    for (int b = 0; b < NCONV; ++b) { da.src[b] = d_in[conv_idx[b]]; da.n[b] = in_sizes[conv_idx[b]]; }
    detect_all<<<NCONV, 256, 0, stream>>>(da, modes);

    // ---------------- weight transposes (batched) ----------------
    {
        WtArgs wa;
        const int din_i[8]  = {12, 16, 21, 25, 30, 32, 36, 40};
        const int midx_i[8] = {5, 9, 14, 18, 23, 25, 29, 33};
        const int KW_i[8]   = {70, 256, 128, 256, 128, 68, 256, 256};
        const int ldw_i[8]  = {256, 128, 256, 128, 128, 256, 256, 128};
        short* wt_i[8]      = {wt0, wt1, wt2, wt3, wt4, wt5, wt6, wt7};
        const int Kp_i[8]   = {96, 256, 128, 256, 128, 96, 256, 256};
        const int N_i[8]    = {256, 128, 256, 128, 128, 256, 256, 128};
        for (int e = 0; e < 8; ++e) {
            wa.W[e] = d_in[din_i[e]]; wa.midx[e] = midx_i[e]; wa.KW[e] = KW_i[e];
            wa.ldw[e] = ldw_i[e]; wa.wt[e] = wt_i[e]; wa.Kpad[e] = Kp_i[e]; wa.N[e] = N_i[e];
        }
        wt_build_all<<<dim3(256, 8), 256, 0, stream>>>(wa, modes);
    }

    // ---------------- degrees (before CSR fill so adjw can fold dinv) ----------------
    hipMemsetAsync(dinv, 0, nS * sizeof(float), stream);
    deg_scatter<<<(nES + 255) / 256, 256, 0, stream>>>(d_in[6], modes, 2, eis + nES, dinv, nES);
    dinv_fin<<<(nS + 255) / 256, 256, 0, stream>>>(dinv, nS);

    // ---------------- CSR builds (hierarchical scan) ----------------
    const int nbN = (nN + 1023) / 1024, nbS = (nS + 1023) / 1024;
    hipMemsetAsync(cur_n, 0, nN * sizeof(int), stream);
    csr_count<<<(nE + 255) / 256, 256, 0, stream>>>(ei + nE, nE, cur_n);
    scan_part<<<nbN, 256, 0, stream>>>(cur_n, nN, bsum_n);
    scan_mid<<<1, 128, 0, stream>>>(bsum_n, nbN, rp_n, nN);
    scan_fin<<<nbN, 256, 0, stream>>>(cur_n, nN, bsum_n, rp_n, cur_n);
    csr_fill<<<(nE + 255) / 256, 256, 0, stream>>>(ei, ei + nE, nullptr, modes, 2, nullptr,
                                                   nE, cur_n, adj_n, nullptr);

    hipMemsetAsync(cur_s, 0, nS * sizeof(int), stream);
    csr_count<<<(nES + 255) / 256, 256, 0, stream>>>(eis + nES, nES, cur_s);
    scan_part<<<nbS, 256, 0, stream>>>(cur_s, nS, bsum_s);
    scan_mid<<<1, 128, 0, stream>>>(bsum_s, nbS, rp_s, nS);
    scan_fin<<<nbS, 256, 0, stream>>>(cur_s, nS, bsum_s, rp_s, cur_s);
    csr_fill<<<(nES + 255) / 256, 256, 0, stream>>>(eis, eis + nES, d_in[6], modes, 2, dinv,
                                                    nES, cur_s, adj_s, adw_s);

    auto gemm = [&](const void* A, int afmt, int ldk, const float* bsc, const float* bsh,
                    const short* Wt, const void* bias, int bidx,
                    float* outF, unsigned* oP, int M, int N, int pair) {
        if (pair) hipMemsetAsync(stats, 0, 2 * N * sizeof(float), stream);
        dim3 grid(N / 128, (M + 127) / 128);
        gemm_mfma<<<grid, 256, 0, stream>>>(A, afmt, ldk, bsc, bsh, Wt, bias, modes, bidx,
                                            outF, oP, stats, M, N, ldk / 32, pair);
    };
    auto bnfin = [&](int gidx, int bidx, const void* g, const void* b, int C, int M) {
        bn_finalize<<<1, C, 0, stream>>>(stats, g, b, modes, gidx, bidx, C, 1.0f / M);
    };

    // ---------------- node branch ----------------
    build_feat_pack<<<nN, 128, 0, stream>>>(d_in[10], node_ids, d_in[1], modes, 3, 0,
                                            C13P, 6, 96);
    gin_gather_pack<<<(nN + 7) / 8, 256, 0, stream>>>(C13P, rp_n, adj_n, d_in[18], modes, 11,
                                                      nullptr, nullptr, B13P, 96, nN);
    gemm(B13P, 0, 96, nullptr, nullptr, wt0, d_in[13], 6, nullptr, A25P, nN, 256, 1);
    bnfin(7, 8, d_in[14], d_in[15], 256, nN);                       // BN1 -> sc256/sh256
    gemm(A25P, 0, 256, sc256, sh256, wt1, d_in[17], 10, nullptr, C13P, nN, 128, 1);
    bnfin(12, 13, d_in[19], d_in[20], 128, nN);                     // BN2 -> sc128/sh128
    gin_gather_pack<<<(nN + 7) / 8, 256, 0, stream>>>(C13P, rp_n, adj_n, d_in[27], modes, 20,
                                                      sc128, sh128, B13P, 128, nN);
    gemm(B13P, 0, 128, nullptr, nullptr, wt2, d_in[22], 15, nullptr, A25P, nN, 256, 1);
    bnfin(16, 17, d_in[23], d_in[24], 256, nN);                     // BN3
    gemm(A25P, 0, 256, sc256, sh256, wt3, d_in[26], 19, nullptr, C13P, nN, 128, 1);
    bnfin(21, 22, d_in[28], d_in[29], 128, nN);                     // BN4
    gemm(C13P, 0, 128, sc128, sh128, wt4, d_in[31], 24, B13F, nullptr, nN, 128, 0);
    pool_sorted<<<Bg, 128, 0, stream>>>(B13F, batch, xg, nN);

    // ---------------- service branch ----------------
    build_feat_pack<<<nS, 128, 0, stream>>>(d_in[11], svc_ids, d_in[4], modes, 4, 1,
                                            C13P, 4, 96);
    gemm(C13P, 0, 96, nullptr, nullptr, wt5, nullptr, 0, B13F, nullptr, nS, 256, 0);
    gcn_gather<<<(nS + 3) / 4, 256, 0, stream>>>(B13F, rp_s, adj_s, adw_s, dinv, d_in[33],
                                                 modes, 26, A25F, nS);
    hipMemsetAsync(stats, 0, 2 * 256 * sizeof(float), stream);
    bn_stats_f32<<<(nS + 31) / 32, 256, 0, stream>>>(A25F, stats, nS, 256, 32);
    bnfin(27, 28, d_in[34], d_in[35], 256, nS);
    gemm(A25F, 1, 256, sc256, sh256, wt6, nullptr, 0, B13F, nullptr, nS, 256, 0);
    gcn_gather<<<(nS + 3) / 4, 256, 0, stream>>>(B13F, rp_s, adj_s, adw_s, dinv, d_in[37],
                                                 modes, 30, A25F, nS);
    hipMemsetAsync(stats, 0, 2 * 256 * sizeof(float), stream);
    bn_stats_f32<<<(nS + 31) / 32, 256, 0, stream>>>(A25F, stats, nS, 256, 32);
    bnfin(31, 32, d_in[38], d_in[39], 256, nS);
    gemm(A25F, 1, 256, sc256, sh256, wt7, d_in[41], 34, B13F, nullptr, nS, 128, 0);
    svc_pool1<<<dim3(50, 8), 128, 0, stream>>>(B13F, part);
    svc_pool2<<<50, 128, 0, stream>>>(part, xsg);

    // ---------------- output ----------------
    final_out<<<Bg, 64, 0, stream>>>(xg, xsg, modes, d_out);
}

// Round 9
// 1235.726 us; speedup vs baseline: 3.0804x; 1.1072x over previous
//
#include <hip/hip_runtime.h>
#include <hip/hip_bf16.h>
#include <cstddef>
#include <cstdint>

typedef __hip_bfloat16 bf16;
typedef __attribute__((ext_vector_type(8))) short short8;      // 8 bf16 (4 VGPRs)
typedef __attribute__((ext_vector_type(4))) float floatx4;     // MFMA acc

static __device__ __forceinline__ float b2f(bf16 v) { return __bfloat162float(v); }

static __device__ __forceinline__ short f2bf(float f) {
    unsigned u = __float_as_uint(f);
    unsigned r = u + 0x7FFF + ((u >> 16) & 1);
    return (short)(r >> 16);
}
static __device__ __forceinline__ float bf2f(short h) {
    return __uint_as_float(((unsigned)(unsigned short)h) << 16);
}
// mode: 0=zero, 1=bf16-stored, 2=fp32-stored
static __device__ __forceinline__ float loadf(const void* p, int mode, size_t i) {
    if (mode == 1) return b2f(((const bf16*)p)[i]);
    if (mode == 2) return ((const float*)p)[i];
    return 0.f;
}

#define NCONV 35
struct DetArgs { const void* src[NCONV]; int n[NCONV]; };

// ---------------- dtype detection (one block per buffer) ----------------
__global__ void detect_all(DetArgs a, int* __restrict__ modes) {
    int b = blockIdx.x;
    int n = a.n[b];
    const unsigned short* w = (const unsigned short*)a.src[b];
    __shared__ int cz, cbad, cevz, codz;
    if (threadIdx.x == 0) { cz = 0; cbad = 0; cevz = 0; codz = 0; }
    __syncthreads();
    int K = n < 2048 ? n : 2048;
    int z = 0, bad = 0, evz = 0, odz = 0;
    for (int i = threadIdx.x; i < K; i += blockDim.x) {
        unsigned short v = w[i];
        int e = (v >> 7) & 0xFF;
        bool isz = (v & 0x7FFF) == 0;
        if (isz) { z++; if (i & 1) odz++; else evz++; }
        else if (e < 91 || e > 140) bad++;
    }
    atomicAdd(&cz, z); atomicAdd(&cbad, bad);
    atomicAdd(&cevz, evz); atomicAdd(&codz, odz);
    __syncthreads();
    if (threadIdx.x == 0) {
        int mode;
        if (cz >= K) mode = 0;
        else if (cbad * 16 > K) mode = 2;
        else if (cevz * 4 > K && codz * 16 < K) mode = 2;
        else mode = 1;
        modes[b] = mode;
    }
}

// ---------------- batched weight transpose -> bf16 Wt[n][Kpad] ----------------
struct WtArgs {
    const void* W[8]; short* wt[8];
    int midx[8]; int KW[8]; int ldw[8]; int Kpad[8]; int N[8];
};
__global__ void wt_build_all(WtArgs a, const int* __restrict__ modes) {
    int e = blockIdx.y;
    int n = blockIdx.x; if (n >= a.N[e]) return;
    int k = threadIdx.x; if (k >= a.Kpad[e]) return;
    float v = (k < a.KW[e]) ? loadf(a.W[e], modes[a.midx[e]], (size_t)k * a.ldw[e] + n) : 0.f;
    a.wt[e][(size_t)n * a.Kpad[e] + k] = f2bf(v);
}

// ---------------- feature build -> bf16 plane ----------------
__global__ void build_feat_bf16(const void* __restrict__ emb, const int* __restrict__ ids,
                                const void* __restrict__ feats, const int* __restrict__ modes,
                                int eidx, int fidx, unsigned short* __restrict__ P,
                                int nf, int Ws) {
    int i = blockIdx.x;
    int d = threadIdx.x;          // 128
    if (d >= Ws) return;
    float v;
    if (d < 64)           v = loadf(emb, modes[eidx], (size_t)ids[i] * 64 + d);
    else if (d < 64 + nf) v = loadf(feats, modes[fidx], (size_t)i * nf + (d - 64));
    else                  v = 0.f;
    P[(size_t)i * Ws + d] = (unsigned short)f2bf(v);
}

// ---------------- CSR build ----------------
__global__ void csr_count(const int* __restrict__ dst, int nE, int* __restrict__ cnt) {
    int e = blockIdx.x * blockDim.x + threadIdx.x;
    if (e < nE) atomicAdd(&cnt[dst[e]], 1);
}

__global__ __launch_bounds__(256) void scan_part(const int* __restrict__ cnt, int n,
                                                 int* __restrict__ bsum) {
    __shared__ int red[256];
    int blk = blockIdx.x, t = threadIdx.x;
    int base = blk * 1024 + t * 4;
    int s = 0;
    #pragma unroll
    for (int k = 0; k < 4; ++k) { int i = base + k; if (i < n) s += cnt[i]; }
    red[t] = s;
    __syncthreads();
    for (int off = 128; off > 0; off >>= 1) {
        if (t < off) red[t] += red[t + off];
        __syncthreads();
    }
    if (t == 0) bsum[blk] = red[0];
}

__global__ __launch_bounds__(128) void scan_mid(int* __restrict__ bsum, int nb,
                                                int* __restrict__ rowptr, int n) {
    __shared__ int sh[128];
    int t = threadIdx.x;
    int v = (t < nb) ? bsum[t] : 0;
    sh[t] = v;
    __syncthreads();
    for (int off = 1; off < 128; off <<= 1) {
        int u = (t >= off) ? sh[t - off] : 0;
        __syncthreads();
        sh[t] += u;
        __syncthreads();
    }
    if (t < nb) bsum[t] = sh[t] - v;        // exclusive
    if (t == 127) rowptr[n] = sh[127];      // total
}

__global__ __launch_bounds__(256) void scan_fin(const int* __restrict__ cnt, int n,
                                                const int* __restrict__ bsum,
                                                int* __restrict__ rowptr, int* __restrict__ cursor) {
    __shared__ int sh[256];
    int blk = blockIdx.x, t = threadIdx.x;
    int base = blk * 1024 + t * 4;
    int v[4], s = 0;
    #pragma unroll
    for (int k = 0; k < 4; ++k) { int i = base + k; v[k] = (i < n) ? cnt[i] : 0; s += v[k]; }
    sh[t] = s;
    __syncthreads();
    for (int off = 1; off < 256; off <<= 1) {
        int u = (t >= off) ? sh[t - off] : 0;
        __syncthreads();
        sh[t] += u;
        __syncthreads();
    }
    int run = sh[t] - s + bsum[blk];
    #pragma unroll
    for (int k = 0; k < 4; ++k) {
        int i = base + k;
        if (i < n) { rowptr[i] = run; cursor[i] = run; run += v[k]; }
    }
}

__global__ void csr_fill(const int* __restrict__ src, const int* __restrict__ dst,
                         const void* __restrict__ w, const int* __restrict__ modes, int widx,
                         const float* __restrict__ dinv, int nE, int* __restrict__ cursor,
                         int* __restrict__ adj, short* __restrict__ adjw) {
    int e = blockIdx.x * blockDim.x + threadIdx.x;
    if (e < nE) {
        int s = src[e];
        int pos = atomicAdd(&cursor[dst[e]], 1);
        adj[pos] = s;
        if (adjw) adjw[pos] = f2bf(dinv[s] * loadf(w, modes[widx], e));
    }
}

// ---------------- GIN gather, bf16, 16-lane groups, optional fused BN+ReLU ----------------
__global__ __launch_bounds__(256) void gin_gather_bf16(
        const unsigned short* __restrict__ P, const int* __restrict__ rowptr,
        const int* __restrict__ adj, const void* __restrict__ eps,
        const int* __restrict__ modes, int eidx,
        const float* __restrict__ bnsc, const float* __restrict__ bnsh,
        unsigned short* __restrict__ Po, int Ws, int nN) {
    int W8 = Ws >> 3;
    int g = threadIdx.x >> 4;                 // 16 row-groups per block
    int l = threadIdx.x & 15;                 // lane in group
    int i = blockIdx.x * 16 + g;
    if (i >= nN || l >= W8) return;
    float epsv = 1.0f + loadf(eps, modes[eidx], 0);
    float sc[8], sh[8];
    bool bn = bnsc != nullptr;
    if (bn) {
        *(float4*)&sc[0] = *(const float4*)(bnsc + l * 8);
        *(float4*)&sc[4] = *(const float4*)(bnsc + l * 8 + 4);
        *(float4*)&sh[0] = *(const float4*)(bnsh + l * 8);
        *(float4*)&sh[4] = *(const float4*)(bnsh + l * 8 + 4);
    }
    int lo = rowptr[i], hi = rowptr[i + 1];
    float acc[8] = {};
    for (int p = lo; p < hi; ++p) {
        short8 v = *(const short8*)(P + (size_t)adj[p] * Ws + l * 8);
        #pragma unroll
        for (int j = 0; j < 8; ++j) {
            float y = bf2f(v[j]);
            if (bn) y = fmaxf(fmaf(y, sc[j], sh[j]), 0.f);
            acc[j] += y;
        }
    }
    size_t o = (size_t)i * Ws + l * 8;
    short8 sv = *(const short8*)(P + o);
    short8 r;
    #pragma unroll
    for (int j = 0; j < 8; ++j) {
        float y = bf2f(sv[j]);
        if (bn) y = fmaxf(fmaf(y, sc[j], sh[j]), 0.f);
        r[j] = f2bf(acc[j] + epsv * y);
    }
    *(short8*)(Po + o) = r;
}

// ---------------- GCN gather, vectorized ----------------
__global__ __launch_bounds__(256) void gcn_gather(
        const float* __restrict__ xw, const int* __restrict__ rowptr,
        const int* __restrict__ adj, const short* __restrict__ adjw,
        const float* __restrict__ dinv, const void* __restrict__ bias,
        const int* __restrict__ modes, int bidx, float* __restrict__ out, int nS) {
    int g = threadIdx.x >> 6;                 // 0..3
    int l = threadIdx.x & 63;
    int i = blockIdx.x * 4 + g;
    if (i >= nS) return;
    float di = dinv[i];
    int bmode = modes[bidx];
    size_t o = (size_t)i * 256 + (l << 2);
    float4 self = *(const float4*)(xw + o);
    float4 acc;
    float dd = di * di;
    acc.x = self.x * dd + loadf(bias, bmode, (l << 2) + 0);
    acc.y = self.y * dd + loadf(bias, bmode, (l << 2) + 1);
    acc.z = self.z * dd + loadf(bias, bmode, (l << 2) + 2);
    acc.w = self.w * dd + loadf(bias, bmode, (l << 2) + 3);
    int lo = rowptr[i], hi = rowptr[i + 1];
    int p = lo;
    for (; p + 1 < hi; p += 2) {
        int s0 = adj[p], s1 = adj[p + 1];
        float w0 = di * bf2f(adjw[p]), w1 = di * bf2f(adjw[p + 1]);
        float4 v0 = *(const float4*)(xw + (size_t)s0 * 256 + (l << 2));
        float4 v1 = *(const float4*)(xw + (size_t)s1 * 256 + (l << 2));
        acc.x += w0 * v0.x + w1 * v1.x;
        acc.y += w0 * v0.y + w1 * v1.y;
        acc.z += w0 * v0.z + w1 * v1.z;
        acc.w += w0 * v0.w + w1 * v1.w;
    }
    if (p < hi) {
        float w0 = di * bf2f(adjw[p]);
        float4 v0 = *(const float4*)(xw + (size_t)adj[p] * 256 + (l << 2));
        acc.x += w0 * v0.x; acc.y += w0 * v0.y;
        acc.z += w0 * v0.z; acc.w += w0 * v0.w;
    }
    *(float4*)(out + o) = acc;
}

// ---------------- MFMA GEMM: out[M,N] = f(A)[M,ldk] @ Wt^T ----------------
// afmt: 0 = bf16, 1 = fp32.  bnsc/bnsh non-null: A' = relu(A*sc+sh).
// bf_out=1: write bf16 + column (sum,sumsq) atomics into stats; else fp32 (+bias)
__global__ __launch_bounds__(256) void gemm_mfma(
        const void* __restrict__ A, int afmt, int ldk,
        const float* __restrict__ bnsc, const float* __restrict__ bnsh,
        const short* __restrict__ Wt,
        const void* __restrict__ bias, const int* __restrict__ modes, int bias_midx,
        float* __restrict__ outF, unsigned short* __restrict__ oB,
        float* __restrict__ stats, int M, int N, int ksteps, int bf_out) {
    int tid  = threadIdx.x;
    int wv   = tid >> 6, lane = tid & 63;
    int m16  = lane & 15, q = lane >> 4;
    int bm   = blockIdx.y * 128 + wv * 32;
    int n0   = blockIdx.x * 128;
    int r0 = min(bm + m16, M - 1);
    int r1 = min(bm + 16 + m16, M - 1);
    const short8* ba0 = (const short8*)((const short*)A + (size_t)r0 * ldk + q * 8);
    const short8* ba1 = (const short8*)((const short*)A + (size_t)r1 * ldk + q * 8);
    const float*  fa0 = (const float*)A + (size_t)r0 * ldk + q * 8;
    const float*  fa1 = (const float*)A + (size_t)r1 * ldk + q * 8;
    const short8* pb[8];
    #pragma unroll
    for (int nt = 0; nt < 8; ++nt)
        pb[nt] = (const short8*)(Wt + (size_t)(n0 + nt * 16 + m16) * ldk + q * 8);

    floatx4 acc[2][8];
    #pragma unroll
    for (int mt = 0; mt < 2; ++mt)
        #pragma unroll
        for (int nt = 0; nt < 8; ++nt)
            acc[mt][nt] = (floatx4){0.f, 0.f, 0.f, 0.f};

    bool bn = bnsc != nullptr;
    for (int ks = 0; ks < ksteps; ++ks) {
        int idx = ks * 4;                 // short8 units (32 bf16 / k-step)
        short8 a0, a1;
        if (afmt == 0 && !bn) {
            a0 = ba0[idx];
            a1 = ba1[idx];
        } else {
            float v0[8], v1[8];
            if (afmt == 0) {
                short8 u0 = ba0[idx], u1 = ba1[idx];
                #pragma unroll
                for (int j = 0; j < 8; ++j) { v0[j] = bf2f(u0[j]); v1[j] = bf2f(u1[j]); }
            } else {
                *(float4*)&v0[0] = *(const float4*)(fa0 + ks * 32);
                *(float4*)&v0[4] = *(const float4*)(fa0 + ks * 32 + 4);
                *(float4*)&v1[0] = *(const float4*)(fa1 + ks * 32);
                *(float4*)&v1[4] = *(const float4*)(fa1 + ks * 32 + 4);
            }
            if (bn) {
                int c0 = ks * 32 + q * 8;
                float scv[8], shv[8];
                *(float4*)&scv[0] = *(const float4*)(bnsc + c0);
                *(float4*)&scv[4] = *(const float4*)(bnsc + c0 + 4);
                *(float4*)&shv[0] = *(const float4*)(bnsh + c0);
                *(float4*)&shv[4] = *(const float4*)(bnsh + c0 + 4);
                #pragma unroll
                for (int j = 0; j < 8; ++j) {
                    v0[j] = fmaxf(fmaf(v0[j], scv[j], shv[j]), 0.f);
                    v1[j] = fmaxf(fmaf(v1[j], scv[j], shv[j]), 0.f);
                }
            }
            #pragma unroll
            for (int j = 0; j < 8; ++j) { a0[j] = f2bf(v0[j]); a1[j] = f2bf(v1[j]); }
        }
        #pragma unroll
        for (int nt = 0; nt < 8; ++nt) {
            short8 b = pb[nt][idx];
            acc[0][nt] = __builtin_amdgcn_mfma_f32_16x16x32_bf16(a0, b, acc[0][nt], 0, 0, 0);
            acc[1][nt] = __builtin_amdgcn_mfma_f32_16x16x32_bf16(a1, b, acc[1][nt], 0, 0, 0);
        }
    }

    float bv[8];
    int bmode = bias ? modes[bias_midx] : 0;
    #pragma unroll
    for (int nt = 0; nt < 8; ++nt)
        bv[nt] = bias ? loadf(bias, bmode, n0 + nt * 16 + m16) : 0.f;

    if (bf_out) {
        float sA[8], qA[8];
        #pragma unroll
        for (int nt = 0; nt < 8; ++nt) { sA[nt] = 0.f; qA[nt] = 0.f; }
        #pragma unroll
        for (int mt = 0; mt < 2; ++mt)
            #pragma unroll
            for (int r = 0; r < 4; ++r) {
                int row = bm + mt * 16 + q * 4 + r;
                bool ok = row < M;
                #pragma unroll
                for (int nt = 0; nt < 8; ++nt) {
                    float v = acc[mt][nt][r] + bv[nt];
                    if (ok) {
                        oB[(size_t)row * N + n0 + nt * 16 + m16] = (unsigned short)f2bf(v);
                        sA[nt] += v; qA[nt] += v * v;
                    }
                }
            }
        #pragma unroll
        for (int nt = 0; nt < 8; ++nt) {
            sA[nt] += __shfl_xor(sA[nt], 16); sA[nt] += __shfl_xor(sA[nt], 32);
            qA[nt] += __shfl_xor(qA[nt], 16); qA[nt] += __shfl_xor(qA[nt], 32);
        }
        __shared__ float redS[4][128], redQ[4][128];
        if (q == 0) {
            #pragma unroll
            for (int nt = 0; nt < 8; ++nt) {
                redS[wv][nt * 16 + m16] = sA[nt];
                redQ[wv][nt * 16 + m16] = qA[nt];
            }
        }
        __syncthreads();
        if (tid < 128) {
            float s = 0.f, qq = 0.f;
            #pragma unroll
            for (int w = 0; w < 4; ++w) { s += redS[w][tid]; qq += redQ[w][tid]; }
            atomicAdd(&stats[n0 + tid], s);
            atomicAdd(&stats[N + n0 + tid], qq);
        }
    } else {
        #pragma unroll
        for (int mt = 0; mt < 2; ++mt)
            #pragma unroll
            for (int r = 0; r < 4; ++r) {
                int row = bm + mt * 16 + q * 4 + r;
                if (row >= M) continue;
                #pragma unroll
                for (int nt = 0; nt < 8; ++nt)
                    outF[(size_t)row * N + n0 + nt * 16 + m16] = acc[mt][nt][r] + bv[nt];
            }
    }
}

// ---------------- BatchNorm ----------------
__global__ void bn_finalize(float* __restrict__ stats, const void* __restrict__ g,
                            const void* __restrict__ b, const int* __restrict__ modes,
                            int gidx, int bidx, int C, float invM) {
    int c = threadIdx.x;
    if (c < C) {
        float mean = stats[c] * invM;
        float var  = fmaxf(stats[C + c] * invM - mean * mean, 0.f);
        float sc   = loadf(g, modes[gidx], c) * rsqrtf(var + 1e-5f);
        stats[2 * C + c] = sc;
        stats[3 * C + c] = loadf(b, modes[bidx], c) - mean * sc;
    }
}

__global__ void bn_stats_f32(const float* __restrict__ X, float* __restrict__ stats,
                             int M, int C, int rows) {
    int c = threadIdx.x;          // blockDim == C
    int r0 = blockIdx.x * rows;
    int r1 = min(r0 + rows, M);
    float s = 0.f, s2 = 0.f;
    for (int r = r0; r < r1; ++r) {
        float v = X[(size_t)r * C + c];
        s += v; s2 += v * v;
    }
    atomicAdd(&stats[c], s);
    atomicAdd(&stats[C + c], s2);
}

// ---------------- GCN degree ----------------
__global__ void deg_scatter(const void* __restrict__ ew, const int* __restrict__ modes, int eidx,
                            const int* __restrict__ col, float* __restrict__ deg, int nE) {
    int e = blockIdx.x * blockDim.x + threadIdx.x;
    if (e < nE) atomicAdd(&deg[col[e]], loadf(ew, modes[eidx], e));
}

__global__ void dinv_fin(float* __restrict__ deg, int n) {
    int i = blockIdx.x * blockDim.x + threadIdx.x;
    if (i < n) {
        float d = deg[i] + 1.0f;
        deg[i] = d > 0.f ? rsqrtf(d) : 0.f;
    }
}

// ---------------- pooling ----------------
__global__ void pool_sorted(const float* __restrict__ xn, const int* __restrict__ batch,
                            float* __restrict__ xg, int nN) {
    int g = blockIdx.x;
    int lo = 0, hi = nN;
    while (lo < hi) { int mid = (lo + hi) >> 1; if (batch[mid] < g) lo = mid + 1; else hi = mid; }
    int lo2 = lo, hi2 = nN;
    while (lo2 < hi2) { int mid = (lo2 + hi2) >> 1; if (batch[mid] < g + 1) lo2 = mid + 1; else hi2 = mid; }
    int d = threadIdx.x;          // 128
    float s = 0.f;
    for (int r = lo; r < lo2; ++r) s += xn[(size_t)r * 128 + d];
    xg[(size_t)g * 128 + d] = s / fmaxf((float)(lo2 - lo), 1.0f);
}

__global__ void svc_pool1(const float* __restrict__ xsl, float* __restrict__ partial) {
    int o = blockIdx.x;           // 50
    int c = blockIdx.y;           // 8
    int d = threadIdx.x;          // 128
    float s = 0.f;
    int r0 = c * 128;
    for (int r = r0; r < r0 + 128; ++r)
        s += xsl[((size_t)(r * 50 + o)) * 128 + d];
    partial[((size_t)(o * 8 + c)) * 128 + d] = s;
}

__global__ void svc_pool2(const float* __restrict__ partial, float* __restrict__ xsg) {
    int o = blockIdx.x;           // 50
    int d = threadIdx.x;          // 128
    float s = 0.f;
    #pragma unroll
    for (int c = 0; c < 8; ++c)
        s += partial[((size_t)(o * 8 + c)) * 128 + d];
    xsg[o * 128 + d] = s * (1.0f / 1024.0f);
}

// ---------------- final ----------------
__global__ void final_out(const float* __restrict__ xg, const float* __restrict__ xsg,
                          const int* __restrict__ modes, void* __restrict__ out) {
    __shared__ float xrow[128];
    int g = blockIdx.x;
    for (int d = threadIdx.x; d < 128; d += 64) xrow[d] = xg[(size_t)g * 128 + d];
    __syncthreads();
    int o = threadIdx.x;
    if (o < 50) {
        const float* xs = xsg + o * 128;
        float s = 0.f;
        #pragma unroll 4
        for (int d = 0; d < 128; ++d) s += xrow[d] * xs[d];
        float sg = 1.0f / (1.0f + __expf(-s));
        if (modes[0] == 1) ((bf16*)out)[(size_t)g * 50 + o] = __float2bfloat16(sg);
        else               ((float*)out)[(size_t)g * 50 + o] = sg;
    }
}

extern "C" void kernel_launch(void* const* d_in, const int* in_sizes, int n_in,
                              void* d_out, int out_size, void* d_ws, size_t ws_size,
                              hipStream_t stream) {
    const int nN = 100000, nE = 800000, nS = 51200, nES = 409600;
    const int Bg = 1024;

    const int* node_ids = (const int*)d_in[0];
    const int* ei       = (const int*)d_in[2];
    const int* svc_ids  = (const int*)d_in[3];
    const int* eis      = (const int*)d_in[5];
    const int* batch    = (const int*)d_in[7];

    // ---------------- workspace layout (float words, 16B-aligned blocks) ----------------
    float* ws    = (float*)d_ws;
    int*   modes = (int*)ws;                        // 64
    float* stats = ws + 64;                         // 1024
    float* dinv  = ws + 1088;                       // 51200
    float* xsg   = ws + 52288;                      // 6400
    int*   bsum  = (int*)(ws + 58688);              // 256
    int*   rp_n  = (int*)(ws + 58944);              // 100001
    int*   adj_n = (int*)(ws + 158948);             // 800000
    int*   rp_s  = (int*)(ws + 958948);             // 51201
    int*   adj_s = (int*)(ws + 1010152);            // 409600
    short* adw_s = (short*)(ws + 1419752);          // 409600 shorts
    short* wtb   = (short*)(ws + 1624552);          // 262144 shorts
    float* xg    = ws + 1755624;                    // 131072 (also cur_n early)
    float* part  = ws + 1886696;                    // 51200  (also cur_s early)
    float* A25   = ws + 1937896;                    // 25,600,000
    float* B13   = ws + 27537896;                   // 13,107,200
    float* C13   = ws + 40645096;                   // 13,107,200
    size_t need  = (size_t)53752296 * 4;
    if (ws_size < need) return;
    int* cur_n = (int*)xg;
    int* cur_s = (int*)part;
    int* bsum_n = bsum;
    int* bsum_s = bsum + 128;

    unsigned short* A25B = (unsigned short*)A25;
    unsigned short* B13B = (unsigned short*)B13;
    unsigned short* C13B = (unsigned short*)C13;
    float* B13F = B13;  float* A25F = A25;

    // BN sc/sh locations inside stats: C=256 -> sc@512, sh@768 ; C=128 -> sc@256, sh@384
    float* sc256 = stats + 512; float* sh256 = stats + 768;
    float* sc128 = stats + 256; float* sh128 = stats + 384;

    short* wt0 = wtb;               // g0_W1  256 x 96
    short* wt1 = wt0 + 24576;       // g0_W2  128 x 256
    short* wt2 = wt1 + 32768;       // g1_W1  256 x 128
    short* wt3 = wt2 + 32768;       // g1_W2  128 x 256
    short* wt4 = wt3 + 32768;       // nl_W   128 x 128
    short* wt5 = wt4 + 16384;       // c0_W   256 x 96
    short* wt6 = wt5 + 24576;       // c1_W   256 x 256
    short* wt7 = wt6 + 65536;       // sl_W   128 x 256

    // ---------------- detect dtypes (once, 35 blocks) ----------------
    static const int conv_idx[NCONV] = {1, 4, 6, 10, 11,
        12, 13, 14, 15, 16, 17, 18, 19, 20,
        21, 22, 23, 24, 25, 26, 27, 28, 29,
        30, 31, 32, 33, 34, 35, 36, 37, 38, 39, 40, 41};
    DetArgs da;
    for (int b = 0; b < NCONV; ++b) { da.src[b] = d_in[conv_idx[b]]; da.n[b] = in_sizes[conv_idx[b]]; }
    detect_all<<<NCONV, 256, 0, stream>>>(da, modes);

    // ---------------- weight transposes (batched) ----------------
    {
        WtArgs wa;
        const int din_i[8]  = {12, 16, 21, 25, 30, 32, 36, 40};
        const int midx_i[8] = {5, 9, 14, 18, 23, 25, 29, 33};
        const int KW_i[8]   = {70, 256, 128, 256, 128, 68, 256, 256};
        const int ldw_i[8]  = {256, 128, 256, 128, 128, 256, 256, 128};
        short* wt_i[8]      = {wt0, wt1, wt2, wt3, wt4, wt5, wt6, wt7};
        const int Kp_i[8]   = {96, 256, 128, 256, 128, 96, 256, 256};
        const int N_i[8]    = {256, 128, 256, 128, 128, 256, 256, 128};
        for (int e = 0; e < 8; ++e) {
            wa.W[e] = d_in[din_i[e]]; wa.midx[e] = midx_i[e]; wa.KW[e] = KW_i[e];
            wa.ldw[e] = ldw_i[e]; wa.wt[e] = wt_i[e]; wa.Kpad[e] = Kp_i[e]; wa.N[e] = N_i[e];
        }
        wt_build_all<<<dim3(256, 8), 256, 0, stream>>>(wa, modes);
    }

    // ---------------- degrees (before CSR fill so adjw can fold dinv) ----------------
    hipMemsetAsync(dinv, 0, nS * sizeof(float), stream);
    deg_scatter<<<(nES + 255) / 256, 256, 0, stream>>>(d_in[6], modes, 2, eis + nES, dinv, nES);
    dinv_fin<<<(nS + 255) / 256, 256, 0, stream>>>(dinv, nS);

    // ---------------- CSR builds (hierarchical scan) ----------------
    const int nbN = (nN + 1023) / 1024, nbS = (nS + 1023) / 1024;
    hipMemsetAsync(cur_n, 0, nN * sizeof(int), stream);
    csr_count<<<(nE + 255) / 256, 256, 0, stream>>>(ei + nE, nE, cur_n);
    scan_part<<<nbN, 256, 0, stream>>>(cur_n, nN, bsum_n);
    scan_mid<<<1, 128, 0, stream>>>(bsum_n, nbN, rp_n, nN);
    scan_fin<<<nbN, 256, 0, stream>>>(cur_n, nN, bsum_n, rp_n, cur_n);
    csr_fill<<<(nE + 255) / 256, 256, 0, stream>>>(ei, ei + nE, nullptr, modes, 2, nullptr,
                                                   nE, cur_n, adj_n, nullptr);

    hipMemsetAsync(cur_s, 0, nS * sizeof(int), stream);
    csr_count<<<(nES + 255) / 256, 256, 0, stream>>>(eis + nES, nES, cur_s);
    scan_part<<<nbS, 256, 0, stream>>>(cur_s, nS, bsum_s);
    scan_mid<<<1, 128, 0, stream>>>(bsum_s, nbS, rp_s, nS);
    scan_fin<<<nbS, 256, 0, stream>>>(cur_s, nS, bsum_s, rp_s, cur_s);
    csr_fill<<<(nES + 255) / 256, 256, 0, stream>>>(eis, eis + nES, d_in[6], modes, 2, dinv,
                                                    nES, cur_s, adj_s, adw_s);

    auto gemm = [&](const void* A, int afmt, int ldk, const float* bsc, const float* bsh,
                    const short* Wt, const void* bias, int bidx,
                    float* outF, unsigned short* oB, int M, int N, int bfo) {
        if (bfo) hipMemsetAsync(stats, 0, 2 * N * sizeof(float), stream);
        dim3 grid(N / 128, (M + 127) / 128);
        gemm_mfma<<<grid, 256, 0, stream>>>(A, afmt, ldk, bsc, bsh, Wt, bias, modes, bidx,
                                            outF, oB, stats, M, N, ldk / 32, bfo);
    };
    auto bnfin = [&](int gidx, int bidx, const void* g, const void* b, int C, int M) {
        bn_finalize<<<1, C, 0, stream>>>(stats, g, b, modes, gidx, bidx, C, 1.0f / M);
    };

    // ---------------- node branch ----------------
    build_feat_bf16<<<nN, 128, 0, stream>>>(d_in[10], node_ids, d_in[1], modes, 3, 0,
                                            C13B, 6, 96);
    gin_gather_bf16<<<(nN + 15) / 16, 256, 0, stream>>>(C13B, rp_n, adj_n, d_in[18], modes, 11,
                                                        nullptr, nullptr, B13B, 96, nN);
    gemm(B13B, 0, 96, nullptr, nullptr, wt0, d_in[13], 6, nullptr, A25B, nN, 256, 1);
    bnfin(7, 8, d_in[14], d_in[15], 256, nN);                       // BN1 -> sc256/sh256
    gemm(A25B, 0, 256, sc256, sh256, wt1, d_in[17], 10, nullptr, C13B, nN, 128, 1);
    bnfin(12, 13, d_in[19], d_in[20], 128, nN);                     // BN2 -> sc128/sh128
    gin_gather_bf16<<<(nN + 15) / 16, 256, 0, stream>>>(C13B, rp_n, adj_n, d_in[27], modes, 20,
                                                        sc128, sh128, B13B, 128, nN);
    gemm(B13B, 0, 128, nullptr, nullptr, wt2, d_in[22], 15, nullptr, A25B, nN, 256, 1);
    bnfin(16, 17, d_in[23], d_in[24], 256, nN);                     // BN3
    gemm(A25B, 0, 256, sc256, sh256, wt3, d_in[26], 19, nullptr, C13B, nN, 128, 1);
    bnfin(21, 22, d_in[28], d_in[29], 128, nN);                     // BN4
    gemm(C13B, 0, 128, sc128, sh128, wt4, d_in[31], 24, B13F, nullptr, nN, 128, 0);
    pool_sorted<<<Bg, 128, 0, stream>>>(B13F, batch, xg, nN);

    // ---------------- service branch ----------------
    build_feat_bf16<<<nS, 128, 0, stream>>>(d_in[11], svc_ids, d_in[4], modes, 4, 1,
                                            C13B, 4, 96);
    gemm(C13B, 0, 96, nullptr, nullptr, wt5, nullptr, 0, B13F, nullptr, nS, 256, 0);
    gcn_gather<<<(nS + 3) / 4, 256, 0, stream>>>(B13F, rp_s, adj_s, adw_s, dinv, d_in[33],
                                                 modes, 26, A25F, nS);
    hipMemsetAsync(stats, 0, 2 * 256 * sizeof(float), stream);
    bn_stats_f32<<<(nS + 31) / 32, 256, 0, stream>>>(A25F, stats, nS, 256, 32);
    bnfin(27, 28, d_in[34], d_in[35], 256, nS);
    gemm(A25F, 1, 256, sc256, sh256, wt6, nullptr, 0, B13F, nullptr, nS, 256, 0);
    gcn_gather<<<(nS + 3) / 4, 256, 0, stream>>>(B13F, rp_s, adj_s, adw_s, dinv, d_in[37],
                                                 modes, 30, A25F, nS);
    hipMemsetAsync(stats, 0, 2 * 256 * sizeof(float), stream);
    bn_stats_f32<<<(nS + 31) / 32, 256, 0, stream>>>(A25F, stats, nS, 256, 32);
    bnfin(31, 32, d_in[38], d_in[39], 256, nS);
    gemm(A25F, 1, 256, sc256, sh256, wt7, d_in[41], 34, B13F, nullptr, nS, 128, 0);
    svc_pool1<<<dim3(50, 8), 128, 0, stream>>>(B13F, part);
    svc_pool2<<<50, 128, 0, stream>>>(part, xsg);

    // ---------------- output ----------------
    final_out<<<Bg, 64, 0, stream>>>(xg, xsg, modes, d_out);
}

// Round 10
// 1106.596 us; speedup vs baseline: 3.4398x; 1.1167x over previous
//
#include <hip/hip_runtime.h>
#include <hip/hip_bf16.h>
#include <cstddef>
#include <cstdint>

typedef __hip_bfloat16 bf16;
typedef __attribute__((ext_vector_type(8))) short short8;      // 8 bf16 (4 VGPRs)
typedef __attribute__((ext_vector_type(4))) float floatx4;     // MFMA acc

static __device__ __forceinline__ float b2f(bf16 v) { return __bfloat162float(v); }

static __device__ __forceinline__ short f2bf(float f) {
    unsigned u = __float_as_uint(f);
    unsigned r = u + 0x7FFF + ((u >> 16) & 1);
    return (short)(r >> 16);
}
static __device__ __forceinline__ float bf2f(short h) {
    return __uint_as_float(((unsigned)(unsigned short)h) << 16);
}
// mode: 0=zero, 1=bf16-stored, 2=fp32-stored
static __device__ __forceinline__ float loadf(const void* p, int mode, size_t i) {
    if (mode == 1) return b2f(((const bf16*)p)[i]);
    if (mode == 2) return ((const float*)p)[i];
    return 0.f;
}

#define NCONV 35
struct DetArgs { const void* src[NCONV]; int n[NCONV]; };

// ---------------- dtype detection (one block per buffer) ----------------
__global__ void detect_all(DetArgs a, int* __restrict__ modes) {
    int b = blockIdx.x;
    int n = a.n[b];
    const unsigned short* w = (const unsigned short*)a.src[b];
    __shared__ int cz, cbad, cevz, codz;
    if (threadIdx.x == 0) { cz = 0; cbad = 0; cevz = 0; codz = 0; }
    __syncthreads();
    int K = n < 2048 ? n : 2048;
    int z = 0, bad = 0, evz = 0, odz = 0;
    for (int i = threadIdx.x; i < K; i += blockDim.x) {
        unsigned short v = w[i];
        int e = (v >> 7) & 0xFF;
        bool isz = (v & 0x7FFF) == 0;
        if (isz) { z++; if (i & 1) odz++; else evz++; }
        else if (e < 91 || e > 140) bad++;
    }
    atomicAdd(&cz, z); atomicAdd(&cbad, bad);
    atomicAdd(&cevz, evz); atomicAdd(&codz, odz);
    __syncthreads();
    if (threadIdx.x == 0) {
        int mode;
        if (cz >= K) mode = 0;
        else if (cbad * 16 > K) mode = 2;
        else if (cevz * 4 > K && codz * 16 < K) mode = 2;
        else mode = 1;
        modes[b] = mode;
    }
}

// ---------------- batched weight transpose -> bf16 Wt[n][Kpad] ----------------
struct WtArgs {
    const void* W[8]; short* wt[8];
    int midx[8]; int KW[8]; int ldw[8]; int Kpad[8]; int N[8];
};
__global__ void wt_build_all(WtArgs a, const int* __restrict__ modes) {
    int e = blockIdx.y;
    int n = blockIdx.x; if (n >= a.N[e]) return;
    int k = threadIdx.x; if (k >= a.Kpad[e]) return;
    float v = (k < a.KW[e]) ? loadf(a.W[e], modes[a.midx[e]], (size_t)k * a.ldw[e] + n) : 0.f;
    a.wt[e][(size_t)n * a.Kpad[e] + k] = f2bf(v);
}

// ---------------- feature build -> bf16 plane ----------------
__global__ void build_feat_bf16(const void* __restrict__ emb, const int* __restrict__ ids,
                                const void* __restrict__ feats, const int* __restrict__ modes,
                                int eidx, int fidx, unsigned short* __restrict__ P,
                                int nf, int Ws) {
    int i = blockIdx.x;
    int d = threadIdx.x;          // 128
    if (d >= Ws) return;
    float v;
    if (d < 64)           v = loadf(emb, modes[eidx], (size_t)ids[i] * 64 + d);
    else if (d < 64 + nf) v = loadf(feats, modes[fidx], (size_t)i * nf + (d - 64));
    else                  v = 0.f;
    P[(size_t)i * Ws + d] = (unsigned short)f2bf(v);
}

// ---------------- CSR build ----------------
__global__ void csr_count(const int* __restrict__ dst, int nE, int* __restrict__ cnt) {
    int e = blockIdx.x * blockDim.x + threadIdx.x;
    if (e < nE) atomicAdd(&cnt[dst[e]], 1);
}

__global__ __launch_bounds__(256) void scan_part(const int* __restrict__ cnt, int n,
                                                 int* __restrict__ bsum) {
    __shared__ int red[256];
    int blk = blockIdx.x, t = threadIdx.x;
    int base = blk * 1024 + t * 4;
    int s = 0;
    #pragma unroll
    for (int k = 0; k < 4; ++k) { int i = base + k; if (i < n) s += cnt[i]; }
    red[t] = s;
    __syncthreads();
    for (int off = 128; off > 0; off >>= 1) {
        if (t < off) red[t] += red[t + off];
        __syncthreads();
    }
    if (t == 0) bsum[blk] = red[0];
}

__global__ __launch_bounds__(128) void scan_mid(int* __restrict__ bsum, int nb,
                                                int* __restrict__ rowptr, int n) {
    __shared__ int sh[128];
    int t = threadIdx.x;
    int v = (t < nb) ? bsum[t] : 0;
    sh[t] = v;
    __syncthreads();
    for (int off = 1; off < 128; off <<= 1) {
        int u = (t >= off) ? sh[t - off] : 0;
        __syncthreads();
        sh[t] += u;
        __syncthreads();
    }
    if (t < nb) bsum[t] = sh[t] - v;        // exclusive
    if (t == 127) rowptr[n] = sh[127];      // total
}

__global__ __launch_bounds__(256) void scan_fin(const int* __restrict__ cnt, int n,
                                                const int* __restrict__ bsum,
                                                int* __restrict__ rowptr, int* __restrict__ cursor) {
    __shared__ int sh[256];
    int blk = blockIdx.x, t = threadIdx.x;
    int base = blk * 1024 + t * 4;
    int v[4], s = 0;
    #pragma unroll
    for (int k = 0; k < 4; ++k) { int i = base + k; v[k] = (i < n) ? cnt[i] : 0; s += v[k]; }
    sh[t] = s;
    __syncthreads();
    for (int off = 1; off < 256; off <<= 1) {
        int u = (t >= off) ? sh[t - off] : 0;
        __syncthreads();
        sh[t] += u;
        __syncthreads();
    }
    int run = sh[t] - s + bsum[blk];
    #pragma unroll
    for (int k = 0; k < 4; ++k) {
        int i = base + k;
        if (i < n) { rowptr[i] = run; cursor[i] = run; run += v[k]; }
    }
}

__global__ void csr_fill(const int* __restrict__ src, const int* __restrict__ dst,
                         const void* __restrict__ w, const int* __restrict__ modes, int widx,
                         const float* __restrict__ dinv, int nE, int* __restrict__ cursor,
                         int* __restrict__ adj, short* __restrict__ adjw) {
    int e = blockIdx.x * blockDim.x + threadIdx.x;
    if (e < nE) {
        int s = src[e];
        int pos = atomicAdd(&cursor[dst[e]], 1);
        adj[pos] = s;
        if (adjw) adjw[pos] = f2bf(dinv[s] * loadf(w, modes[widx], e));
    }
}

// ---------------- GIN gather, bf16, 16-lane groups, optional fused BN+ReLU ----------------
__global__ __launch_bounds__(256) void gin_gather_bf16(
        const unsigned short* __restrict__ P, const int* __restrict__ rowptr,
        const int* __restrict__ adj, const void* __restrict__ eps,
        const int* __restrict__ modes, int eidx,
        const float* __restrict__ bnsc, const float* __restrict__ bnsh,
        unsigned short* __restrict__ Po, int Ws, int nN) {
    int W8 = Ws >> 3;
    int g = threadIdx.x >> 4;                 // 16 row-groups per block
    int l = threadIdx.x & 15;                 // lane in group
    int i = blockIdx.x * 16 + g;
    if (i >= nN || l >= W8) return;
    float epsv = 1.0f + loadf(eps, modes[eidx], 0);
    float sc[8], sh[8];
    bool bn = bnsc != nullptr;
    if (bn) {
        *(float4*)&sc[0] = *(const float4*)(bnsc + l * 8);
        *(float4*)&sc[4] = *(const float4*)(bnsc + l * 8 + 4);
        *(float4*)&sh[0] = *(const float4*)(bnsh + l * 8);
        *(float4*)&sh[4] = *(const float4*)(bnsh + l * 8 + 4);
    }
    int lo = rowptr[i], hi = rowptr[i + 1];
    float acc[8] = {};
    for (int p = lo; p < hi; ++p) {
        short8 v = *(const short8*)(P + (size_t)adj[p] * Ws + l * 8);
        #pragma unroll
        for (int j = 0; j < 8; ++j) {
            float y = bf2f(v[j]);
            if (bn) y = fmaxf(fmaf(y, sc[j], sh[j]), 0.f);
            acc[j] += y;
        }
    }
    size_t o = (size_t)i * Ws + l * 8;
    short8 sv = *(const short8*)(P + o);
    short8 r;
    #pragma unroll
    for (int j = 0; j < 8; ++j) {
        float y = bf2f(sv[j]);
        if (bn) y = fmaxf(fmaf(y, sc[j], sh[j]), 0.f);
        r[j] = f2bf(acc[j] + epsv * y);
    }
    *(short8*)(Po + o) = r;
}

// ---------------- GCN gather, bf16 input xw, fp32 output ----------------
__global__ __launch_bounds__(256) void gcn_gather_bf16(
        const unsigned short* __restrict__ xw, const int* __restrict__ rowptr,
        const int* __restrict__ adj, const short* __restrict__ adjw,
        const float* __restrict__ dinv, const void* __restrict__ bias,
        const int* __restrict__ modes, int bidx, float* __restrict__ out, int nS) {
    int g = threadIdx.x >> 5;                 // 8 groups
    int l = threadIdx.x & 31;                 // 32 lanes x 8 cols = 256
    int i = blockIdx.x * 8 + g;
    if (i >= nS) return;
    float di = dinv[i];
    int bmode = modes[bidx];
    size_t o = (size_t)i * 256 + l * 8;
    short8 sv = *(const short8*)(xw + o);
    float dd = di * di;
    float acc[8];
    #pragma unroll
    for (int j = 0; j < 8; ++j)
        acc[j] = bf2f(sv[j]) * dd + loadf(bias, bmode, l * 8 + j);
    int lo = rowptr[i], hi = rowptr[i + 1];
    for (int p = lo; p < hi; ++p) {
        float w = di * bf2f(adjw[p]);
        short8 v = *(const short8*)(xw + (size_t)adj[p] * 256 + l * 8);
        #pragma unroll
        for (int j = 0; j < 8; ++j)
            acc[j] += w * bf2f(v[j]);
    }
    *(float4*)(out + o) = *(float4*)&acc[0];
    *(float4*)(out + o + 4) = *(float4*)&acc[4];
}

// ---------------- MFMA GEMM: out[M,N] = f(A)[M,ldk] @ Wt^T ----------------
// afmt: 0 = bf16, 1 = fp32.  bnsc/bnsh non-null: A' = relu(A*sc+sh).
// omode: 0 = fp32 out (+bias); 1 = bf16 out + column stats; 2 = bf16 out
__global__ __launch_bounds__(256) void gemm_mfma(
        const void* __restrict__ A, int afmt, int ldk,
        const float* __restrict__ bnsc, const float* __restrict__ bnsh,
        const short* __restrict__ Wt,
        const void* __restrict__ bias, const int* __restrict__ modes, int bias_midx,
        float* __restrict__ outF, unsigned short* __restrict__ oB,
        float* __restrict__ stats, int M, int N, int ksteps, int omode) {
    int tid  = threadIdx.x;
    int wv   = tid >> 6, lane = tid & 63;
    int m16  = lane & 15, q = lane >> 4;
    int bm   = blockIdx.y * 128 + wv * 32;
    int n0   = blockIdx.x * 128;
    int r0 = min(bm + m16, M - 1);
    int r1 = min(bm + 16 + m16, M - 1);
    const short8* ba0 = (const short8*)((const short*)A + (size_t)r0 * ldk + q * 8);
    const short8* ba1 = (const short8*)((const short*)A + (size_t)r1 * ldk + q * 8);
    const float*  fa0 = (const float*)A + (size_t)r0 * ldk + q * 8;
    const float*  fa1 = (const float*)A + (size_t)r1 * ldk + q * 8;
    const short8* pb[8];
    #pragma unroll
    for (int nt = 0; nt < 8; ++nt)
        pb[nt] = (const short8*)(Wt + (size_t)(n0 + nt * 16 + m16) * ldk + q * 8);

    floatx4 acc[2][8];
    #pragma unroll
    for (int mt = 0; mt < 2; ++mt)
        #pragma unroll
        for (int nt = 0; nt < 8; ++nt)
            acc[mt][nt] = (floatx4){0.f, 0.f, 0.f, 0.f};

    bool bn = bnsc != nullptr;
    for (int ks = 0; ks < ksteps; ++ks) {
        int idx = ks * 4;                 // short8 units (32 bf16 / k-step)
        short8 a0, a1;
        if (afmt == 0 && !bn) {
            a0 = ba0[idx];
            a1 = ba1[idx];
        } else {
            float v0[8], v1[8];
            if (afmt == 0) {
                short8 u0 = ba0[idx], u1 = ba1[idx];
                #pragma unroll
                for (int j = 0; j < 8; ++j) { v0[j] = bf2f(u0[j]); v1[j] = bf2f(u1[j]); }
            } else {
                *(float4*)&v0[0] = *(const float4*)(fa0 + ks * 32);
                *(float4*)&v0[4] = *(const float4*)(fa0 + ks * 32 + 4);
                *(float4*)&v1[0] = *(const float4*)(fa1 + ks * 32);
                *(float4*)&v1[4] = *(const float4*)(fa1 + ks * 32 + 4);
            }
            if (bn) {
                int c0 = ks * 32 + q * 8;
                float scv[8], shv[8];
                *(float4*)&scv[0] = *(const float4*)(bnsc + c0);
                *(float4*)&scv[4] = *(const float4*)(bnsc + c0 + 4);
                *(float4*)&shv[0] = *(const float4*)(bnsh + c0);
                *(float4*)&shv[4] = *(const float4*)(bnsh + c0 + 4);
                #pragma unroll
                for (int j = 0; j < 8; ++j) {
                    v0[j] = fmaxf(fmaf(v0[j], scv[j], shv[j]), 0.f);
                    v1[j] = fmaxf(fmaf(v1[j], scv[j], shv[j]), 0.f);
                }
            }
            #pragma unroll
            for (int j = 0; j < 8; ++j) { a0[j] = f2bf(v0[j]); a1[j] = f2bf(v1[j]); }
        }
        #pragma unroll
        for (int nt = 0; nt < 8; ++nt) {
            short8 b = pb[nt][idx];
            acc[0][nt] = __builtin_amdgcn_mfma_f32_16x16x32_bf16(a0, b, acc[0][nt], 0, 0, 0);
            acc[1][nt] = __builtin_amdgcn_mfma_f32_16x16x32_bf16(a1, b, acc[1][nt], 0, 0, 0);
        }
    }

    float bv[8];
    int bmode = bias ? modes[bias_midx] : 0;
    #pragma unroll
    for (int nt = 0; nt < 8; ++nt)
        bv[nt] = bias ? loadf(bias, bmode, n0 + nt * 16 + m16) : 0.f;

    if (omode) {
        __shared__ unsigned short tile[128][136];   // padded: quad rows 8 banks apart
        __shared__ float redS[4][128], redQ[4][128];
        float sA[8], qA[8];
        #pragma unroll
        for (int nt = 0; nt < 8; ++nt) { sA[nt] = 0.f; qA[nt] = 0.f; }
        #pragma unroll
        for (int mt = 0; mt < 2; ++mt)
            #pragma unroll
            for (int r = 0; r < 4; ++r) {
                int rl = wv * 32 + mt * 16 + q * 4 + r;
                bool ok = (bm + mt * 16 + q * 4 + r) < M;
                #pragma unroll
                for (int nt = 0; nt < 8; ++nt) {
                    float v = acc[mt][nt][r] + bv[nt];
                    tile[rl][nt * 16 + m16] = (unsigned short)f2bf(v);
                    if (ok && omode == 1) { sA[nt] += v; qA[nt] += v * v; }
                }
            }
        if (omode == 1) {
            #pragma unroll
            for (int nt = 0; nt < 8; ++nt) {
                sA[nt] += __shfl_xor(sA[nt], 16); sA[nt] += __shfl_xor(sA[nt], 32);
                qA[nt] += __shfl_xor(qA[nt], 16); qA[nt] += __shfl_xor(qA[nt], 32);
            }
            if (q == 0) {
                #pragma unroll
                for (int nt = 0; nt < 8; ++nt) {
                    redS[wv][nt * 16 + m16] = sA[nt];
                    redQ[wv][nt * 16 + m16] = qA[nt];
                }
            }
        }
        __syncthreads();
        int rb = blockIdx.y * 128;
        #pragma unroll
        for (int c = 0; c < 8; ++c) {
            int lin = c * 256 + tid;      // 16-byte unit index
            int row = lin >> 4;
            int cu  = lin & 15;
            int grow = rb + row;
            if (grow < M)
                *(short8*)(oB + (size_t)grow * N + n0 + cu * 8) = *(short8*)&tile[row][cu * 8];
        }
        if (omode == 1 && tid < 128) {
            float s = 0.f, qq = 0.f;
            #pragma unroll
            for (int w = 0; w < 4; ++w) { s += redS[w][tid]; qq += redQ[w][tid]; }
            atomicAdd(&stats[n0 + tid], s);
            atomicAdd(&stats[N + n0 + tid], qq);
        }
    } else {
        #pragma unroll
        for (int mt = 0; mt < 2; ++mt)
            #pragma unroll
            for (int r = 0; r < 4; ++r) {
                int row = bm + mt * 16 + q * 4 + r;
                if (row >= M) continue;
                #pragma unroll
                for (int nt = 0; nt < 8; ++nt)
                    outF[(size_t)row * N + n0 + nt * 16 + m16] = acc[mt][nt][r] + bv[nt];
            }
    }
}

// ---------------- BatchNorm ----------------
__global__ void bn_finalize(float* __restrict__ stats, const void* __restrict__ g,
                            const void* __restrict__ b, const int* __restrict__ modes,
                            int gidx, int bidx, int C, float invM) {
    int c = threadIdx.x;
    if (c < C) {
        float mean = stats[c] * invM;
        float var  = fmaxf(stats[C + c] * invM - mean * mean, 0.f);
        float sc   = loadf(g, modes[gidx], c) * rsqrtf(var + 1e-5f);
        stats[2 * C + c] = sc;
        stats[3 * C + c] = loadf(b, modes[bidx], c) - mean * sc;
    }
}

__global__ void bn_stats_f32(const float* __restrict__ X, float* __restrict__ stats,
                             int M, int C, int rows) {
    int c = threadIdx.x;          // blockDim == C
    int r0 = blockIdx.x * rows;
    int r1 = min(r0 + rows, M);
    float s = 0.f, s2 = 0.f;
    for (int r = r0; r < r1; ++r) {
        float v = X[(size_t)r * C + c];
        s += v; s2 += v * v;
    }
    atomicAdd(&stats[c], s);
    atomicAdd(&stats[C + c], s2);
}

// ---------------- GCN degree ----------------
__global__ void deg_scatter(const void* __restrict__ ew, const int* __restrict__ modes, int eidx,
                            const int* __restrict__ col, float* __restrict__ deg, int nE) {
    int e = blockIdx.x * blockDim.x + threadIdx.x;
    if (e < nE) atomicAdd(&deg[col[e]], loadf(ew, modes[eidx], e));
}

__global__ void dinv_fin(float* __restrict__ deg, int n) {
    int i = blockIdx.x * blockDim.x + threadIdx.x;
    if (i < n) {
        float d = deg[i] + 1.0f;
        deg[i] = d > 0.f ? rsqrtf(d) : 0.f;
    }
}

// ---------------- pooling ----------------
__global__ void pool_sorted_bf16(const unsigned short* __restrict__ xn,
                                 const int* __restrict__ batch,
                                 float* __restrict__ xg, int nN) {
    int g = blockIdx.x;
    int lo = 0, hi = nN;
    while (lo < hi) { int mid = (lo + hi) >> 1; if (batch[mid] < g) lo = mid + 1; else hi = mid; }
    int lo2 = lo, hi2 = nN;
    while (lo2 < hi2) { int mid = (lo2 + hi2) >> 1; if (batch[mid] < g + 1) lo2 = mid + 1; else hi2 = mid; }
    int d = threadIdx.x;          // 128
    float s = 0.f;
    for (int r = lo; r < lo2; ++r) s += bf2f((short)xn[(size_t)r * 128 + d]);
    xg[(size_t)g * 128 + d] = s / fmaxf((float)(lo2 - lo), 1.0f);
}

__global__ void svc_pool1(const float* __restrict__ xsl, float* __restrict__ partial) {
    int o = blockIdx.x;           // 50
    int c = blockIdx.y;           // 8
    int d = threadIdx.x;          // 128
    float s = 0.f;
    int r0 = c * 128;
    for (int r = r0; r < r0 + 128; ++r)
        s += xsl[((size_t)(r * 50 + o)) * 128 + d];
    partial[((size_t)(o * 8 + c)) * 128 + d] = s;
}

__global__ void svc_pool2(const float* __restrict__ partial, float* __restrict__ xsg) {
    int o = blockIdx.x;           // 50
    int d = threadIdx.x;          // 128
    float s = 0.f;
    #pragma unroll
    for (int c = 0; c < 8; ++c)
        s += partial[((size_t)(o * 8 + c)) * 128 + d];
    xsg[o * 128 + d] = s * (1.0f / 1024.0f);
}

// ---------------- final ----------------
__global__ void final_out(const float* __restrict__ xg, const float* __restrict__ xsg,
                          const int* __restrict__ modes, void* __restrict__ out) {
    __shared__ float xrow[128];
    int g = blockIdx.x;
    for (int d = threadIdx.x; d < 128; d += 64) xrow[d] = xg[(size_t)g * 128 + d];
    __syncthreads();
    int o = threadIdx.x;
    if (o < 50) {
        const float* xs = xsg + o * 128;
        float s = 0.f;
        #pragma unroll 4
        for (int d = 0; d < 128; ++d) s += xrow[d] * xs[d];
        float sg = 1.0f / (1.0f + __expf(-s));
        if (modes[0] == 1) ((bf16*)out)[(size_t)g * 50 + o] = __float2bfloat16(sg);
        else               ((float*)out)[(size_t)g * 50 + o] = sg;
    }
}

extern "C" void kernel_launch(void* const* d_in, const int* in_sizes, int n_in,
                              void* d_out, int out_size, void* d_ws, size_t ws_size,
                              hipStream_t stream) {
    const int nN = 100000, nE = 800000, nS = 51200, nES = 409600;
    const int Bg = 1024;

    const int* node_ids = (const int*)d_in[0];
    const int* ei       = (const int*)d_in[2];
    const int* svc_ids  = (const int*)d_in[3];
    const int* eis      = (const int*)d_in[5];
    const int* batch    = (const int*)d_in[7];

    // ---------------- workspace layout (float words, 16B-aligned blocks) ----------------
    float* ws    = (float*)d_ws;
    int*   modes = (int*)ws;                        // 64
    float* stats = ws + 64;                         // 1024
    float* dinv  = ws + 1088;                       // 51200
    float* xsg   = ws + 52288;                      // 6400
    int*   bsum  = (int*)(ws + 58688);              // 256
    int*   rp_n  = (int*)(ws + 58944);              // 100001
    int*   adj_n = (int*)(ws + 158948);             // 800000
    int*   rp_s  = (int*)(ws + 958948);             // 51201
    int*   adj_s = (int*)(ws + 1010152);            // 409600
    short* adw_s = (short*)(ws + 1419752);          // 409600 shorts
    short* wtb   = (short*)(ws + 1624552);          // 262144 shorts
    float* xg    = ws + 1755624;                    // 131072 (also cur_n early)
    float* part  = ws + 1886696;                    // 51200  (also cur_s early)
    float* A25   = ws + 1937896;                    // 25,600,000
    float* B13   = ws + 27537896;                   // 13,107,200
    float* C13   = ws + 40645096;                   // 13,107,200
    size_t need  = (size_t)53752296 * 4;
    if (ws_size < need) return;
    int* cur_n = (int*)xg;
    int* cur_s = (int*)part;
    int* bsum_n = bsum;
    int* bsum_s = bsum + 128;

    unsigned short* A25B = (unsigned short*)A25;
    unsigned short* B13B = (unsigned short*)B13;
    unsigned short* C13B = (unsigned short*)C13;
    float* B13F = B13;  float* A25F = A25;

    // BN sc/sh locations inside stats: C=256 -> sc@512, sh@768 ; C=128 -> sc@256, sh@384
    float* sc256 = stats + 512; float* sh256 = stats + 768;
    float* sc128 = stats + 256; float* sh128 = stats + 384;

    short* wt0 = wtb;               // g0_W1  256 x 96
    short* wt1 = wt0 + 24576;       // g0_W2  128 x 256
    short* wt2 = wt1 + 32768;       // g1_W1  256 x 128
    short* wt3 = wt2 + 32768;       // g1_W2  128 x 256
    short* wt4 = wt3 + 32768;       // nl_W   128 x 128
    short* wt5 = wt4 + 16384;       // c0_W   256 x 96
    short* wt6 = wt5 + 24576;       // c1_W   256 x 256
    short* wt7 = wt6 + 65536;       // sl_W   128 x 256

    // ---------------- detect dtypes (once, 35 blocks) ----------------
    static const int conv_idx[NCONV] = {1, 4, 6, 10, 11,
        12, 13, 14, 15, 16, 17, 18, 19, 20,
        21, 22, 23, 24, 25, 26, 27, 28, 29,
        30, 31, 32, 33, 34, 35, 36, 37, 38, 39, 40, 41};
    DetArgs da;
    for (int b = 0; b < NCONV; ++b) { da.src[b] = d_in[conv_idx[b]]; da.n[b] = in_sizes[conv_idx[b]]; }
    detect_all<<<NCONV, 256, 0, stream>>>(da, modes);

    // ---------------- weight transposes (batched) ----------------
    {
        WtArgs wa;
        const int din_i[8]  = {12, 16, 21, 25, 30, 32, 36, 40};
        const int midx_i[8] = {5, 9, 14, 18, 23, 25, 29, 33};
        const int KW_i[8]   = {70, 256, 128, 256, 128, 68, 256, 256};
        const int ldw_i[8]  = {256, 128, 256, 128, 128, 256, 256, 128};
        short* wt_i[8]      = {wt0, wt1, wt2, wt3, wt4, wt5, wt6, wt7};
        const int Kp_i[8]   = {96, 256, 128, 256, 128, 96, 256, 256};
        const int N_i[8]    = {256, 128, 256, 128, 128, 256, 256, 128};
        for (int e = 0; e < 8; ++e) {
            wa.W[e] = d_in[din_i[e]]; wa.midx[e] = midx_i[e]; wa.KW[e] = KW_i[e];
            wa.ldw[e] = ldw_i[e]; wa.wt[e] = wt_i[e]; wa.Kpad[e] = Kp_i[e]; wa.N[e] = N_i[e];
        }
        wt_build_all<<<dim3(256, 8), 256, 0, stream>>>(wa, modes);
    }

    // ---------------- degrees (before CSR fill so adjw can fold dinv) ----------------
    hipMemsetAsync(dinv, 0, nS * sizeof(float), stream);
    deg_scatter<<<(nES + 255) / 256, 256, 0, stream>>>(d_in[6], modes, 2, eis + nES, dinv, nES);
    dinv_fin<<<(nS + 255) / 256, 256, 0, stream>>>(dinv, nS);

    // ---------------- CSR builds (hierarchical scan) ----------------
    const int nbN = (nN + 1023) / 1024, nbS = (nS + 1023) / 1024;
    hipMemsetAsync(cur_n, 0, nN * sizeof(int), stream);
    csr_count<<<(nE + 255) / 256, 256, 0, stream>>>(ei + nE, nE, cur_n);
    scan_part<<<nbN, 256, 0, stream>>>(cur_n, nN, bsum_n);
    scan_mid<<<1, 128, 0, stream>>>(bsum_n, nbN, rp_n, nN);
    scan_fin<<<nbN, 256, 0, stream>>>(cur_n, nN, bsum_n, rp_n, cur_n);
    csr_fill<<<(nE + 255) / 256, 256, 0, stream>>>(ei, ei + nE, nullptr, modes, 2, nullptr,
                                                   nE, cur_n, adj_n, nullptr);

    hipMemsetAsync(cur_s, 0, nS * sizeof(int), stream);
    csr_count<<<(nES + 255) / 256, 256, 0, stream>>>(eis + nES, nES, cur_s);
    scan_part<<<nbS, 256, 0, stream>>>(cur_s, nS, bsum_s);
    scan_mid<<<1, 128, 0, stream>>>(bsum_s, nbS, rp_s, nS);
    scan_fin<<<nbS, 256, 0, stream>>>(cur_s, nS, bsum_s, rp_s, cur_s);
    csr_fill<<<(nES + 255) / 256, 256, 0, stream>>>(eis, eis + nES, d_in[6], modes, 2, dinv,
                                                    nES, cur_s, adj_s, adw_s);

    auto gemm = [&](const void* A, int afmt, int ldk, const float* bsc, const float* bsh,
                    const short* Wt, const void* bias, int bidx,
                    float* outF, unsigned short* oB, int M, int N, int om) {
        if (om == 1) hipMemsetAsync(stats, 0, 2 * N * sizeof(float), stream);
        dim3 grid(N / 128, (M + 127) / 128);
        gemm_mfma<<<grid, 256, 0, stream>>>(A, afmt, ldk, bsc, bsh, Wt, bias, modes, bidx,
                                            outF, oB, stats, M, N, ldk / 32, om);
    };
    auto bnfin = [&](int gidx, int bidx, const void* g, const void* b, int C, int M) {
        bn_finalize<<<1, C, 0, stream>>>(stats, g, b, modes, gidx, bidx, C, 1.0f / M);
    };

    // ---------------- node branch ----------------
    build_feat_bf16<<<nN, 128, 0, stream>>>(d_in[10], node_ids, d_in[1], modes, 3, 0,
                                            C13B, 6, 96);
    gin_gather_bf16<<<(nN + 15) / 16, 256, 0, stream>>>(C13B, rp_n, adj_n, d_in[18], modes, 11,
                                                        nullptr, nullptr, B13B, 96, nN);
    gemm(B13B, 0, 96, nullptr, nullptr, wt0, d_in[13], 6, nullptr, A25B, nN, 256, 1);
    bnfin(7, 8, d_in[14], d_in[15], 256, nN);                       // BN1 -> sc256/sh256
    gemm(A25B, 0, 256, sc256, sh256, wt1, d_in[17], 10, nullptr, C13B, nN, 128, 1);
    bnfin(12, 13, d_in[19], d_in[20], 128, nN);                     // BN2 -> sc128/sh128
    gin_gather_bf16<<<(nN + 15) / 16, 256, 0, stream>>>(C13B, rp_n, adj_n, d_in[27], modes, 20,
                                                        sc128, sh128, B13B, 128, nN);
    gemm(B13B, 0, 128, nullptr, nullptr, wt2, d_in[22], 15, nullptr, A25B, nN, 256, 1);
    bnfin(16, 17, d_in[23], d_in[24], 256, nN);                     // BN3
    gemm(A25B, 0, 256, sc256, sh256, wt3, d_in[26], 19, nullptr, C13B, nN, 128, 1);
    bnfin(21, 22, d_in[28], d_in[29], 128, nN);                     // BN4
    gemm(C13B, 0, 128, sc128, sh128, wt4, d_in[31], 24, nullptr, B13B, nN, 128, 2);
    pool_sorted_bf16<<<Bg, 128, 0, stream>>>(B13B, batch, xg, nN);

    // ---------------- service branch ----------------
    build_feat_bf16<<<nS, 128, 0, stream>>>(d_in[11], svc_ids, d_in[4], modes, 4, 1,
                                            C13B, 4, 96);
    gemm(C13B, 0, 96, nullptr, nullptr, wt5, nullptr, 0, nullptr, B13B, nS, 256, 2);
    gcn_gather_bf16<<<(nS + 7) / 8, 256, 0, stream>>>(B13B, rp_s, adj_s, adw_s, dinv, d_in[33],
                                                      modes, 26, A25F, nS);
    hipMemsetAsync(stats, 0, 2 * 256 * sizeof(float), stream);
    bn_stats_f32<<<(nS + 31) / 32, 256, 0, stream>>>(A25F, stats, nS, 256, 32);
    bnfin(27, 28, d_in[34], d_in[35], 256, nS);
    gemm(A25F, 1, 256, sc256, sh256, wt6, nullptr, 0, nullptr, B13B, nS, 256, 2);
    gcn_gather_bf16<<<(nS + 7) / 8, 256, 0, stream>>>(B13B, rp_s, adj_s, adw_s, dinv, d_in[37],
                                                      modes, 30, A25F, nS);
    hipMemsetAsync(stats, 0, 2 * 256 * sizeof(float), stream);
    bn_stats_f32<<<(nS + 31) / 32, 256, 0, stream>>>(A25F, stats, nS, 256, 32);
    bnfin(31, 32, d_in[38], d_in[39], 256, nS);
    gemm(A25F, 1, 256, sc256, sh256, wt7, d_in[41], 34, B13F, nullptr, nS, 128, 0);
    svc_pool1<<<dim3(50, 8), 128, 0, stream>>>(B13F, part);
    svc_pool2<<<50, 128, 0, stream>>>(part, xsg);

    // ---------------- output ----------------
    final_out<<<Bg, 64, 0, stream>>>(xg, xsg, modes, d_out);
}